// Round 1
// baseline (2035.784 us; speedup 1.0000x reference)
//
#include <hip/hip_runtime.h>
#include <hip/hip_bf16.h>
#include <math.h>

#define N_TOK 8192
#define D_DIM 512
#define F_DIM 256
#define E_NUM 64
#define SH_NUM 2
#define K_TOP 6
#define CAP   1536
#define M_ENT (N_TOK * K_TOP)   // 49152
#define NCHUNK (M_ENT / 256)    // 192

// ---------------- Router + softmax + top-6 (one wave per token) ----------------
__global__ void router_topk(const float* __restrict__ x, const float* __restrict__ rw,
                            const float* __restrict__ bias, int* __restrict__ topk_i,
                            float* __restrict__ topk_p) {
  const int wave = threadIdx.x >> 6;
  const int lane = threadIdx.x & 63;      // lane == expert id (E=64)
  const int n = blockIdx.x * 4 + wave;
  if (n >= N_TOK) return;

  const float4* xr = (const float4*)(x + (size_t)n * D_DIM);
  const float4* wr = (const float4*)(rw + (size_t)lane * D_DIM);
  float acc = 0.f;
  #pragma unroll 4
  for (int d4 = 0; d4 < D_DIM / 4; ++d4) {
    float4 xv = xr[d4]; float4 wv = wr[d4];
    acc += xv.x * wv.x + xv.y * wv.y + xv.z * wv.z + xv.w * wv.w;
  }
  float logit = acc + bias[lane];

  // softmax across the 64-lane wave
  float m = logit;
  for (int off = 32; off > 0; off >>= 1) m = fmaxf(m, __shfl_xor(m, off));
  float p = expf(logit - m);
  float s = p;
  for (int off = 32; off > 0; off >>= 1) s += __shfl_xor(s, off);
  float prob = p / s;

  // iterative top-6, tie -> smallest index (matches jax.lax.top_k)
  float myp = prob;
  float gsum = 0.f;
  float myg = 0.f; int myi = -1;
  for (int k = 0; k < K_TOP; ++k) {
    float bp = myp; int bi = lane;
    for (int off = 32; off > 0; off >>= 1) {
      float op = __shfl_xor(bp, off); int oi = __shfl_xor(bi, off);
      if (op > bp || (op == bp && oi < bi)) { bp = op; bi = oi; }
    }
    gsum += bp;
    if (lane == k) { myg = bp; myi = bi; }
    if (lane == bi) myp = -1.f;
  }
  if (lane < K_TOP) {
    topk_i[n * K_TOP + lane] = myi;
    topk_p[n * K_TOP + lane] = myg / (gsum + 1e-9f);
  }
}

// ---------------- per-chunk expert histogram ----------------
__global__ void hist_kernel(const int* __restrict__ topk_i, int* __restrict__ chunk_hist) {
  __shared__ int h[E_NUM];
  const int tid = threadIdx.x;
  if (tid < E_NUM) h[tid] = 0;
  __syncthreads();
  int e = topk_i[blockIdx.x * 256 + tid];
  atomicAdd(&h[e], 1);
  __syncthreads();
  if (tid < E_NUM) chunk_hist[blockIdx.x * E_NUM + tid] = h[tid];
}

// ---------------- exclusive scan over chunks, per expert ----------------
__global__ void scan_kernel(const int* __restrict__ chunk_hist, int* __restrict__ chunk_base) {
  const int e = threadIdx.x;  // 64 threads
  int run = 0;
  for (int c = 0; c < NCHUNK; ++c) {
    chunk_base[c * E_NUM + e] = run;
    run += chunk_hist[c * E_NUM + e];
  }
}

// ---------------- dispatch: slot = global stable rank within expert ----------------
__global__ void dispatch_kernel(const int* __restrict__ topk_i, const float* __restrict__ topk_p,
                                const int* __restrict__ chunk_base,
                                int* __restrict__ expert_tok, float* __restrict__ expert_gate) {
  __shared__ int eid[256];
  const int tid = threadIdx.x;
  const int m = blockIdx.x * 256 + tid;
  const int e = topk_i[m];
  eid[tid] = e;
  __syncthreads();
  int rank = 0;
  for (int t = 0; t < tid; ++t) rank += (eid[t] == e);
  int slot = chunk_base[blockIdx.x * E_NUM + e] + rank;
  if (slot < CAP) {
    expert_tok[e * CAP + slot] = m / K_TOP;
    expert_gate[e * CAP + slot] = topk_p[m];
  }
}

__device__ __forceinline__ float silu_f(float g) { return g / (1.f + expf(-g)); }

// ---------------- shared experts: out = (silu(xWg^T)*xWu^T)Wd^T / SH ----------------
__global__ void __launch_bounds__(256) shared_ffn(const float* __restrict__ x,
                          const float* __restrict__ swg, const float* __restrict__ swu,
                          const float* __restrict__ swd, float* __restrict__ out) {
  __shared__ float4 xs[16][D_DIM / 4];                 // 32 KB
  __shared__ float4 act[16][(SH_NUM * F_DIM) / 4];     // 32 KB
  const int tid = threadIdx.x;
  const int row0 = blockIdx.x * 16;

  const float4* xg = (const float4*)(x + (size_t)row0 * D_DIM);
  for (int i = tid; i < 16 * D_DIM / 4; i += 256) ((float4*)xs)[i] = xg[i];
  __syncthreads();

  for (int half = 0; half < 2; ++half) {
    const int col = tid + half * 256;  // col = e*F + f, SH*F = 512
    const float4* wg = (const float4*)(swg + (size_t)col * D_DIM);
    const float4* wu = (const float4*)(swu + (size_t)col * D_DIM);
    float hg[16], hu[16];
    #pragma unroll
    for (int c = 0; c < 16; ++c) { hg[c] = 0.f; hu[c] = 0.f; }
    for (int d4 = 0; d4 < D_DIM / 4; ++d4) {
      float4 g4 = wg[d4], u4 = wu[d4];
      #pragma unroll
      for (int c = 0; c < 16; ++c) {
        float4 xv = xs[c][d4];
        hg[c] += xv.x * g4.x + xv.y * g4.y + xv.z * g4.z + xv.w * g4.w;
        hu[c] += xv.x * u4.x + xv.y * u4.y + xv.z * u4.z + xv.w * u4.w;
      }
    }
    #pragma unroll
    for (int c = 0; c < 16; ++c)
      ((float*)&act[c][0])[col] = silu_f(hg[c]) * hu[c];
  }
  __syncthreads();

  for (int half = 0; half < 2; ++half) {
    const int d = tid + half * 256;
    float acc[16];
    #pragma unroll
    for (int c = 0; c < 16; ++c) acc[c] = 0.f;
    for (int e = 0; e < SH_NUM; ++e) {
      const float4* wd = (const float4*)(swd + ((size_t)e * D_DIM + d) * F_DIM);
      for (int f4 = 0; f4 < F_DIM / 4; ++f4) {
        float4 w4 = wd[f4];
        #pragma unroll
        for (int c = 0; c < 16; ++c) {
          float4 av = act[c][e * (F_DIM / 4) + f4];
          acc[c] += av.x * w4.x + av.y * w4.y + av.z * w4.z + av.w * w4.w;
        }
      }
    }
    #pragma unroll
    for (int c = 0; c < 16; ++c)
      out[(size_t)(row0 + c) * D_DIM + d] = acc[c] * (1.f / SH_NUM);
  }
}

// ---------------- routed experts: gather x rows, FFN, atomic scatter-add ----------------
__global__ void __launch_bounds__(256) expert_ffn(const float* __restrict__ x,
                          const float* __restrict__ wg_, const float* __restrict__ wu_,
                          const float* __restrict__ wd_, const int* __restrict__ expert_tok,
                          const float* __restrict__ expert_gate, float* __restrict__ out) {
  const int e = blockIdx.y;
  const int s0 = blockIdx.x * 16;
  if (expert_tok[e * CAP + s0] < 0) return;  // slots filled contiguously

  __shared__ int toks[16];
  __shared__ float gts[16];
  __shared__ float4 xs[16][D_DIM / 4];   // 32 KB
  __shared__ float4 act[16][F_DIM / 4];  // 16 KB
  const int tid = threadIdx.x;

  if (tid < 16) {
    int s = s0 + tid;
    int t = expert_tok[e * CAP + s];
    toks[tid] = t;
    gts[tid] = (t >= 0) ? expert_gate[e * CAP + s] : 0.f;
  }
  __syncthreads();

  for (int i = tid; i < 16 * D_DIM / 4; i += 256) {
    int c = i / (D_DIM / 4), j = i % (D_DIM / 4);
    int t = toks[c];
    float4 v = make_float4(0.f, 0.f, 0.f, 0.f);
    if (t >= 0) v = ((const float4*)(x + (size_t)t * D_DIM))[j];
    xs[c][j] = v;
  }
  __syncthreads();

  {
    const int f = tid;  // F = 256 = blockDim
    const float4* wg = (const float4*)(wg_ + ((size_t)e * F_DIM + f) * D_DIM);
    const float4* wu = (const float4*)(wu_ + ((size_t)e * F_DIM + f) * D_DIM);
    float hg[16], hu[16];
    #pragma unroll
    for (int c = 0; c < 16; ++c) { hg[c] = 0.f; hu[c] = 0.f; }
    for (int d4 = 0; d4 < D_DIM / 4; ++d4) {
      float4 g4 = wg[d4], u4 = wu[d4];
      #pragma unroll
      for (int c = 0; c < 16; ++c) {
        float4 xv = xs[c][d4];
        hg[c] += xv.x * g4.x + xv.y * g4.y + xv.z * g4.z + xv.w * g4.w;
        hu[c] += xv.x * u4.x + xv.y * u4.y + xv.z * u4.z + xv.w * u4.w;
      }
    }
    #pragma unroll
    for (int c = 0; c < 16; ++c)
      ((float*)&act[c][0])[f] = silu_f(hg[c]) * hu[c];
  }
  __syncthreads();

  for (int half = 0; half < 2; ++half) {
    const int d = tid + half * 256;
    const float4* wd = (const float4*)(wd_ + ((size_t)e * D_DIM + d) * F_DIM);
    float acc[16];
    #pragma unroll
    for (int c = 0; c < 16; ++c) acc[c] = 0.f;
    for (int f4 = 0; f4 < F_DIM / 4; ++f4) {
      float4 w4 = wd[f4];
      #pragma unroll
      for (int c = 0; c < 16; ++c) {
        float4 av = act[c][f4];
        acc[c] += av.x * w4.x + av.y * w4.y + av.z * w4.z + av.w * w4.w;
      }
    }
    #pragma unroll
    for (int c = 0; c < 16; ++c) {
      int t = toks[c];
      if (t >= 0) atomicAdd(&out[(size_t)t * D_DIM + d], gts[c] * acc[c]);
    }
  }
}

extern "C" void kernel_launch(void* const* d_in, const int* in_sizes, int n_in,
                              void* d_out, int out_size, void* d_ws, size_t ws_size,
                              hipStream_t stream) {
  const float* x    = (const float*)d_in[0];
  const float* rw   = (const float*)d_in[1];
  const float* bias = (const float*)d_in[2];
  const float* swg  = (const float*)d_in[3];
  const float* swu  = (const float*)d_in[4];
  const float* swd  = (const float*)d_in[5];
  const float* wg   = (const float*)d_in[6];
  const float* wu   = (const float*)d_in[7];
  const float* wd   = (const float*)d_in[8];
  float* out = (float*)d_out;

  char* ws = (char*)d_ws;
  int*   topk_i      = (int*)ws;   ws += (size_t)M_ENT * 4;
  float* topk_p      = (float*)ws; ws += (size_t)M_ENT * 4;
  int*   chunk_hist  = (int*)ws;   ws += (size_t)NCHUNK * E_NUM * 4;
  int*   chunk_base  = (int*)ws;   ws += (size_t)NCHUNK * E_NUM * 4;
  int*   expert_tok  = (int*)ws;   ws += (size_t)E_NUM * CAP * 4;
  float* expert_gate = (float*)ws; ws += (size_t)E_NUM * CAP * 4;

  router_topk<<<N_TOK / 4, 256, 0, stream>>>(x, rw, bias, topk_i, topk_p);
  hipMemsetAsync(expert_tok, 0xFF, (size_t)E_NUM * CAP * 4, stream);
  hist_kernel<<<NCHUNK, 256, 0, stream>>>(topk_i, chunk_hist);
  scan_kernel<<<1, 64, 0, stream>>>(chunk_hist, chunk_base);
  dispatch_kernel<<<NCHUNK, 256, 0, stream>>>(topk_i, topk_p, chunk_base, expert_tok, expert_gate);
  shared_ffn<<<N_TOK / 16, 256, 0, stream>>>(x, swg, swu, swd, out);
  expert_ffn<<<dim3(CAP / 16, E_NUM), 256, 0, stream>>>(x, wg, wu, wd, expert_tok, expert_gate, out);
}

// Round 2
// 483.791 us; speedup vs baseline: 4.2080x; 4.2080x over previous
//
#include <hip/hip_runtime.h>
#include <hip/hip_bf16.h>
#include <math.h>

#define N_TOK 8192
#define D_DIM 512
#define F_DIM 256
#define E_NUM 64
#define SH_NUM 2
#define K_TOP 6
#define CAP   1536
#define M_ENT (N_TOK * K_TOP)   // 49152
#define NCHUNK (M_ENT / 256)    // 192

typedef __attribute__((ext_vector_type(8))) short bf16x8;
typedef __attribute__((ext_vector_type(4))) float f32x4;

__device__ __forceinline__ ushort f2bf(float f) {
  union { float f; unsigned u; } c; c.f = f;
  return (ushort)((c.u + 0x7FFFu + ((c.u >> 16) & 1u)) >> 16);
}
__device__ __forceinline__ float bf2f(ushort h) {
  union { unsigned u; float f; } c; c.u = ((unsigned)h) << 16;
  return c.f;
}

// ---------------- Router + softmax + top-6 (one wave per token) ----------------
__global__ void router_topk(const float* __restrict__ x, const float* __restrict__ rw,
                            const float* __restrict__ bias, int* __restrict__ topk_i,
                            float* __restrict__ topk_p) {
  const int wave = threadIdx.x >> 6;
  const int lane = threadIdx.x & 63;      // lane == expert id (E=64)
  const int n = blockIdx.x * 4 + wave;
  if (n >= N_TOK) return;

  const float4* xr = (const float4*)(x + (size_t)n * D_DIM);
  const float4* wr = (const float4*)(rw + (size_t)lane * D_DIM);
  float acc = 0.f;
  #pragma unroll 4
  for (int d4 = 0; d4 < D_DIM / 4; ++d4) {
    float4 xv = xr[d4]; float4 wv = wr[d4];
    acc += xv.x * wv.x + xv.y * wv.y + xv.z * wv.z + xv.w * wv.w;
  }
  float logit = acc + bias[lane];

  float m = logit;
  for (int off = 32; off > 0; off >>= 1) m = fmaxf(m, __shfl_xor(m, off));
  float p = expf(logit - m);
  float s = p;
  for (int off = 32; off > 0; off >>= 1) s += __shfl_xor(s, off);
  float prob = p / s;

  float myp = prob;
  float gsum = 0.f;
  float myg = 0.f; int myi = -1;
  for (int k = 0; k < K_TOP; ++k) {
    float bp = myp; int bi = lane;
    for (int off = 32; off > 0; off >>= 1) {
      float op = __shfl_xor(bp, off); int oi = __shfl_xor(bi, off);
      if (op > bp || (op == bp && oi < bi)) { bp = op; bi = oi; }
    }
    gsum += bp;
    if (lane == k) { myg = bp; myi = bi; }
    if (lane == bi) myp = -1.f;
  }
  if (lane < K_TOP) {
    topk_i[n * K_TOP + lane] = myi;
    topk_p[n * K_TOP + lane] = myg / (gsum + 1e-9f);
  }
}

// ---------------- per-chunk expert histogram ----------------
__global__ void hist_kernel(const int* __restrict__ topk_i, int* __restrict__ chunk_hist) {
  __shared__ int h[E_NUM];
  const int tid = threadIdx.x;
  if (tid < E_NUM) h[tid] = 0;
  __syncthreads();
  int e = topk_i[blockIdx.x * 256 + tid];
  atomicAdd(&h[e], 1);
  __syncthreads();
  if (tid < E_NUM) chunk_hist[blockIdx.x * E_NUM + tid] = h[tid];
}

// ---------------- exclusive scan over chunks, per expert ----------------
__global__ void scan_kernel(const int* __restrict__ chunk_hist, int* __restrict__ chunk_base) {
  const int e = threadIdx.x;  // 64 threads
  int run = 0;
  for (int c = 0; c < NCHUNK; ++c) {
    chunk_base[c * E_NUM + e] = run;
    run += chunk_hist[c * E_NUM + e];
  }
}

// ---------------- dispatch: slot = global stable rank within expert ----------------
__global__ void dispatch_kernel(const int* __restrict__ topk_i, const float* __restrict__ topk_p,
                                const int* __restrict__ chunk_base,
                                int* __restrict__ expert_tok, float* __restrict__ expert_gate) {
  __shared__ int eid[256];
  const int tid = threadIdx.x;
  const int m = blockIdx.x * 256 + tid;
  const int e = topk_i[m];
  eid[tid] = e;
  __syncthreads();
  int rank = 0;
  for (int t = 0; t < tid; ++t) rank += (eid[t] == e);
  int slot = chunk_base[blockIdx.x * E_NUM + e] + rank;
  if (slot < CAP) {
    expert_tok[e * CAP + slot] = m / K_TOP;
    expert_gate[e * CAP + slot] = topk_p[m];
  }
}

// ---------------- routed experts: bf16 MFMA fused FFN ----------------
// grid: (CAP/64)*E_NUM blocks; e = bid & 63 so same-expert tiles share an XCD L2.
__global__ void __launch_bounds__(256, 2) expert_ffn_mfma(
    const float* __restrict__ x, const float* __restrict__ wg_,
    const float* __restrict__ wu_, const float* __restrict__ wd_,
    const int* __restrict__ expert_tok, const float* __restrict__ expert_gate,
    float* __restrict__ out) {
  const int e = blockIdx.x & (E_NUM - 1);
  const int mt = blockIdx.x >> 6;
  const int s0 = mt * 64;
  if (expert_tok[e * CAP + s0] < 0) return;   // slots are filled contiguously

  __shared__ ushort Xs[64][72];    // 64x64 bf16 k-chunk, +8 pad (2-way banks)
  __shared__ ushort Ws[256][72];   // 256x64 bf16 k-chunk
  __shared__ ushort Act[64][264];  // 64x256 bf16 (hg, then act)
  __shared__ int   toks[64];
  __shared__ float gts[64];

  const int tid = threadIdx.x;
  const int lane = tid & 63;
  const int wid = tid >> 6;          // 4 waves: wave owns cols wid*64..wid*64+63
  const int rl = lane & 15;
  const int ko = (lane >> 4) * 8;    // k-offset within a 32-chunk (A/B frag layout)
  const int rquad = (lane >> 4) * 4; // C/D row group

  if (tid < 64) {
    int t = expert_tok[e * CAP + s0 + tid];
    toks[tid] = t;
    gts[tid] = (t >= 0) ? expert_gate[e * CAP + s0 + tid] : 0.f;
  }
  __syncthreads();

  float4 px[4], pw[16];

  auto loadX = [&](int kb) {
    #pragma unroll
    for (int it = 0; it < 4; ++it) {
      int idx = tid + it * 256;           // 1024 = 64 rows x 16 float4
      int row = idx >> 4, c4 = (idx & 15) << 2;
      int t = toks[row];
      px[it] = (t >= 0) ? *(const float4*)(x + (size_t)t * D_DIM + kb * 64 + c4)
                        : make_float4(0.f, 0.f, 0.f, 0.f);
    }
  };
  auto writeX = [&]() {
    #pragma unroll
    for (int it = 0; it < 4; ++it) {
      int idx = tid + it * 256;
      int row = idx >> 4, c4 = (idx & 15) << 2;
      ushort4 h; h.x = f2bf(px[it].x); h.y = f2bf(px[it].y);
      h.z = f2bf(px[it].z); h.w = f2bf(px[it].w);
      *(ushort4*)&Xs[row][c4] = h;
    }
  };
  auto loadW = [&](const float* src, int ldk, int kb) {
    #pragma unroll
    for (int it = 0; it < 16; ++it) {
      int idx = tid + it * 256;           // 4096 = 256 rows x 16 float4
      int row = idx >> 4, c4 = (idx & 15) << 2;
      pw[it] = *(const float4*)(src + (size_t)row * ldk + kb * 64 + c4);
    }
  };
  auto writeW = [&]() {
    #pragma unroll
    for (int it = 0; it < 16; ++it) {
      int idx = tid + it * 256;
      int row = idx >> 4, c4 = (idx & 15) << 2;
      ushort4 h; h.x = f2bf(pw[it].x); h.y = f2bf(pw[it].y);
      h.z = f2bf(pw[it].z); h.w = f2bf(pw[it].w);
      *(ushort4*)&Ws[row][c4] = h;
    }
  };
  auto compute = [&](const ushort* Ab, int lda, f32x4 (&acc)[4][4]) {
    #pragma unroll
    for (int kk = 0; kk < 2; ++kk) {
      bf16x8 a[4], b[4];
      #pragma unroll
      for (int ri = 0; ri < 4; ++ri)
        a[ri] = *(const bf16x8*)(Ab + (size_t)(ri * 16 + rl) * lda + kk * 32 + ko);
      #pragma unroll
      for (int bi = 0; bi < 4; ++bi)
        b[bi] = *(const bf16x8*)(&Ws[wid * 64 + bi * 16 + rl][kk * 32 + ko]);
      #pragma unroll
      for (int ri = 0; ri < 4; ++ri)
        #pragma unroll
        for (int bi = 0; bi < 4; ++bi)
          acc[ri][bi] = __builtin_amdgcn_mfma_f32_16x16x32_bf16(a[ri], b[bi], acc[ri][bi], 0, 0, 0);
    }
  };

  const f32x4 fzero = {0.f, 0.f, 0.f, 0.f};

  // ---- gate pass (which=0) then up pass (which=1), K = 512 ----
  #pragma unroll 1
  for (int which = 0; which < 2; ++which) {
    const float* wsrc = (which == 0 ? wg_ : wu_) + (size_t)e * F_DIM * D_DIM;
    f32x4 acc[4][4];
    #pragma unroll
    for (int ri = 0; ri < 4; ++ri)
      #pragma unroll
      for (int bi = 0; bi < 4; ++bi) acc[ri][bi] = fzero;

    loadX(0); loadW(wsrc, D_DIM, 0);
    writeX(); writeW();
    __syncthreads();
    for (int kb = 0; kb < 8; ++kb) {
      if (kb < 7) { loadX(kb + 1); loadW(wsrc, D_DIM, kb + 1); }
      compute(&Xs[0][0], 72, acc);
      __syncthreads();
      if (kb < 7) { writeX(); writeW(); __syncthreads(); }
    }
    #pragma unroll
    for (int ri = 0; ri < 4; ++ri)
      #pragma unroll
      for (int bi = 0; bi < 4; ++bi)
        #pragma unroll
        for (int j = 0; j < 4; ++j) {
          int r = ri * 16 + rquad + j;
          int c = wid * 64 + bi * 16 + rl;
          if (which == 0) {
            Act[r][c] = f2bf(acc[ri][bi][j]);              // hg
          } else {
            float hg = bf2f(Act[r][c]);
            float a = hg / (1.f + __expf(-hg)) * acc[ri][bi][j];
            Act[r][c] = f2bf(a);                           // silu(hg)*hu
          }
        }
    __syncthreads();
  }

  // ---- down passes: out[64 x 512] = Act[64 x 256] @ Wd^T, K = 256 ----
  #pragma unroll 1
  for (int np = 0; np < 2; ++np) {
    const float* wsrc = wd_ + ((size_t)e * D_DIM + np * 256) * F_DIM;
    f32x4 acc[4][4];
    #pragma unroll
    for (int ri = 0; ri < 4; ++ri)
      #pragma unroll
      for (int bi = 0; bi < 4; ++bi) acc[ri][bi] = fzero;

    loadW(wsrc, F_DIM, 0); writeW();
    __syncthreads();
    for (int kb = 0; kb < 4; ++kb) {
      if (kb < 3) loadW(wsrc, F_DIM, kb + 1);
      compute(&Act[0][kb * 64], 264, acc);
      __syncthreads();
      if (kb < 3) { writeW(); __syncthreads(); }
    }
    #pragma unroll
    for (int ri = 0; ri < 4; ++ri)
      #pragma unroll
      for (int bi = 0; bi < 4; ++bi)
        #pragma unroll
        for (int j = 0; j < 4; ++j) {
          int r = ri * 16 + rquad + j;
          int t = toks[r];
          if (t >= 0) {
            int c = np * 256 + wid * 64 + bi * 16 + rl;
            atomicAdd(out + (size_t)t * D_DIM + c, gts[r] * acc[ri][bi][j]);
          }
        }
  }
}

// ---------------- shared experts: bf16 MFMA fused FFN, 32-token tiles ----------------
__global__ void __launch_bounds__(256, 2) shared_ffn_mfma(
    const float* __restrict__ x, const float* __restrict__ swg,
    const float* __restrict__ swu, const float* __restrict__ swd,
    float* __restrict__ out) {
  const int row0 = blockIdx.x * 32;

  __shared__ ushort Xs[32][72];
  __shared__ ushort Ws[256][72];
  __shared__ ushort Act[32][264];

  const int tid = threadIdx.x;
  const int lane = tid & 63;
  const int wid = tid >> 6;
  const int rl = lane & 15;
  const int ko = (lane >> 4) * 8;
  const int rquad = (lane >> 4) * 4;

  float4 px[2], pw[16];

  auto loadX = [&](int kb) {
    #pragma unroll
    for (int it = 0; it < 2; ++it) {
      int idx = tid + it * 256;           // 512 = 32 rows x 16 float4
      int row = idx >> 4, c4 = (idx & 15) << 2;
      px[it] = *(const float4*)(x + (size_t)(row0 + row) * D_DIM + kb * 64 + c4);
    }
  };
  auto writeX = [&]() {
    #pragma unroll
    for (int it = 0; it < 2; ++it) {
      int idx = tid + it * 256;
      int row = idx >> 4, c4 = (idx & 15) << 2;
      ushort4 h; h.x = f2bf(px[it].x); h.y = f2bf(px[it].y);
      h.z = f2bf(px[it].z); h.w = f2bf(px[it].w);
      *(ushort4*)&Xs[row][c4] = h;
    }
  };
  auto loadW = [&](const float* src, int ldk, int kb) {
    #pragma unroll
    for (int it = 0; it < 16; ++it) {
      int idx = tid + it * 256;
      int row = idx >> 4, c4 = (idx & 15) << 2;
      pw[it] = *(const float4*)(src + (size_t)row * ldk + kb * 64 + c4);
    }
  };
  auto writeW = [&]() {
    #pragma unroll
    for (int it = 0; it < 16; ++it) {
      int idx = tid + it * 256;
      int row = idx >> 4, c4 = (idx & 15) << 2;
      ushort4 h; h.x = f2bf(pw[it].x); h.y = f2bf(pw[it].y);
      h.z = f2bf(pw[it].z); h.w = f2bf(pw[it].w);
      *(ushort4*)&Ws[row][c4] = h;
    }
  };
  auto compute = [&](const ushort* Ab, int lda, f32x4 (&acc)[2][4]) {
    #pragma unroll
    for (int kk = 0; kk < 2; ++kk) {
      bf16x8 a[2], b[4];
      #pragma unroll
      for (int ri = 0; ri < 2; ++ri)
        a[ri] = *(const bf16x8*)(Ab + (size_t)(ri * 16 + rl) * lda + kk * 32 + ko);
      #pragma unroll
      for (int bi = 0; bi < 4; ++bi)
        b[bi] = *(const bf16x8*)(&Ws[wid * 64 + bi * 16 + rl][kk * 32 + ko]);
      #pragma unroll
      for (int ri = 0; ri < 2; ++ri)
        #pragma unroll
        for (int bi = 0; bi < 4; ++bi)
          acc[ri][bi] = __builtin_amdgcn_mfma_f32_16x16x32_bf16(a[ri], b[bi], acc[ri][bi], 0, 0, 0);
    }
  };

  const f32x4 fzero = {0.f, 0.f, 0.f, 0.f};
  f32x4 accd[2][2][4];
  #pragma unroll
  for (int np = 0; np < 2; ++np)
    #pragma unroll
    for (int ri = 0; ri < 2; ++ri)
      #pragma unroll
      for (int bi = 0; bi < 4; ++bi) accd[np][ri][bi] = fzero;

  #pragma unroll 1
  for (int sh = 0; sh < SH_NUM; ++sh) {
    // gate then up, K = 512
    #pragma unroll 1
    for (int which = 0; which < 2; ++which) {
      const float* wsrc = (which == 0 ? swg : swu) + (size_t)sh * F_DIM * D_DIM;
      f32x4 acc[2][4];
      #pragma unroll
      for (int ri = 0; ri < 2; ++ri)
        #pragma unroll
        for (int bi = 0; bi < 4; ++bi) acc[ri][bi] = fzero;

      loadX(0); loadW(wsrc, D_DIM, 0);
      writeX(); writeW();
      __syncthreads();
      for (int kb = 0; kb < 8; ++kb) {
        if (kb < 7) { loadX(kb + 1); loadW(wsrc, D_DIM, kb + 1); }
        compute(&Xs[0][0], 72, acc);
        __syncthreads();
        if (kb < 7) { writeX(); writeW(); __syncthreads(); }
      }
      #pragma unroll
      for (int ri = 0; ri < 2; ++ri)
        #pragma unroll
        for (int bi = 0; bi < 4; ++bi)
          #pragma unroll
          for (int j = 0; j < 4; ++j) {
            int r = ri * 16 + rquad + j;
            int c = wid * 64 + bi * 16 + rl;
            if (which == 0) {
              Act[r][c] = f2bf(acc[ri][bi][j]);
            } else {
              float hg = bf2f(Act[r][c]);
              float a = hg / (1.f + __expf(-hg)) * acc[ri][bi][j];
              Act[r][c] = f2bf(a);
            }
          }
      __syncthreads();
    }
    // down, K = 256, accumulate across sh
    #pragma unroll
    for (int np = 0; np < 2; ++np) {
      const float* wsrc = swd + ((size_t)sh * D_DIM + np * 256) * F_DIM;
      loadW(wsrc, F_DIM, 0); writeW();
      __syncthreads();
      for (int kb = 0; kb < 4; ++kb) {
        if (kb < 3) loadW(wsrc, F_DIM, kb + 1);
        compute(&Act[0][kb * 64], 264, accd[np]);
        __syncthreads();
        if (kb < 3) { writeW(); __syncthreads(); }
      }
    }
  }

  #pragma unroll
  for (int np = 0; np < 2; ++np)
    #pragma unroll
    for (int ri = 0; ri < 2; ++ri)
      #pragma unroll
      for (int bi = 0; bi < 4; ++bi)
        #pragma unroll
        for (int j = 0; j < 4; ++j) {
          int r = ri * 16 + rquad + j;
          int c = np * 256 + wid * 64 + bi * 16 + rl;
          out[(size_t)(row0 + r) * D_DIM + c] = 0.5f * accd[np][ri][bi][j];
        }
}

extern "C" void kernel_launch(void* const* d_in, const int* in_sizes, int n_in,
                              void* d_out, int out_size, void* d_ws, size_t ws_size,
                              hipStream_t stream) {
  const float* x    = (const float*)d_in[0];
  const float* rw   = (const float*)d_in[1];
  const float* bias = (const float*)d_in[2];
  const float* swg  = (const float*)d_in[3];
  const float* swu  = (const float*)d_in[4];
  const float* swd  = (const float*)d_in[5];
  const float* wg   = (const float*)d_in[6];
  const float* wu   = (const float*)d_in[7];
  const float* wd   = (const float*)d_in[8];
  float* out = (float*)d_out;

  char* ws = (char*)d_ws;
  int*   topk_i      = (int*)ws;   ws += (size_t)M_ENT * 4;
  float* topk_p      = (float*)ws; ws += (size_t)M_ENT * 4;
  int*   chunk_hist  = (int*)ws;   ws += (size_t)NCHUNK * E_NUM * 4;
  int*   chunk_base  = (int*)ws;   ws += (size_t)NCHUNK * E_NUM * 4;
  int*   expert_tok  = (int*)ws;   ws += (size_t)E_NUM * CAP * 4;
  float* expert_gate = (float*)ws; ws += (size_t)E_NUM * CAP * 4;

  router_topk<<<N_TOK / 4, 256, 0, stream>>>(x, rw, bias, topk_i, topk_p);
  hipMemsetAsync(expert_tok, 0xFF, (size_t)E_NUM * CAP * 4, stream);
  hist_kernel<<<NCHUNK, 256, 0, stream>>>(topk_i, chunk_hist);
  scan_kernel<<<1, 64, 0, stream>>>(chunk_hist, chunk_base);
  dispatch_kernel<<<NCHUNK, 256, 0, stream>>>(topk_i, topk_p, chunk_base, expert_tok, expert_gate);
  shared_ffn_mfma<<<N_TOK / 32, 256, 0, stream>>>(x, swg, swu, swd, out);
  expert_ffn_mfma<<<(CAP / 64) * E_NUM, 256, 0, stream>>>(x, wg, wu, wd, expert_tok, expert_gate, out);
}

// Round 3
// 413.979 us; speedup vs baseline: 4.9176x; 1.1686x over previous
//
#include <hip/hip_runtime.h>
#include <hip/hip_bf16.h>
#include <math.h>

#define N_TOK 8192
#define D_DIM 512
#define F_DIM 256
#define E_NUM 64
#define SH_NUM 2
#define K_TOP 6
#define CAP   1536
#define M_ENT (N_TOK * K_TOP)   // 49152
#define NCHUNK (M_ENT / 256)    // 192

// fast-path workspace geometry (element = ushort/bf16 unless noted)
#define EW_STRIDE 393216            // shorts per expert blob (48 chunks x 8192)
#define E_TOT (E_NUM + SH_NUM)      // 66
#define X_BF_BYTES   (8388608ull)                    // 8192*512*2
#define WT_BYTES     ((size_t)E_TOT * EW_STRIDE * 2) // 51,904,512
#define TOK_ROUTED   (E_NUM * CAP)                   // 98304 entries
#define TOK_TOTAL    (TOK_ROUTED + SH_NUM * N_TOK)   // +16384

typedef __attribute__((ext_vector_type(8))) short bf16x8;
typedef __attribute__((ext_vector_type(8))) short short8;
typedef __attribute__((ext_vector_type(4))) float f32x4;

__device__ __forceinline__ ushort f2bf(float f) {
  union { float f; unsigned u; } c; c.f = f;
  return (ushort)((c.u + 0x7FFFu + ((c.u >> 16) & 1u)) >> 16);
}
__device__ __forceinline__ float bf2f(ushort h) {
  union { unsigned u; float f; } c; c.u = ((unsigned)h) << 16;
  return c.f;
}
__device__ __forceinline__ void gload16(const void* g, void* l) {
  __builtin_amdgcn_global_load_lds(
      (const __attribute__((address_space(1))) void*)g,
      (__attribute__((address_space(3))) void*)l, 16, 0, 0);
}

// ---------------- Router + softmax + top-6 (one wave per token) ----------------
__global__ void router_topk(const float* __restrict__ x, const float* __restrict__ rw,
                            const float* __restrict__ bias, int* __restrict__ topk_i,
                            float* __restrict__ topk_p) {
  const int wave = threadIdx.x >> 6;
  const int lane = threadIdx.x & 63;      // lane == expert id (E=64)
  const int n = blockIdx.x * 4 + wave;
  if (n >= N_TOK) return;

  const float4* xr = (const float4*)(x + (size_t)n * D_DIM);
  const float4* wr = (const float4*)(rw + (size_t)lane * D_DIM);
  float acc = 0.f;
  #pragma unroll 4
  for (int d4 = 0; d4 < D_DIM / 4; ++d4) {
    float4 xv = xr[d4]; float4 wv = wr[d4];
    acc += xv.x * wv.x + xv.y * wv.y + xv.z * wv.z + xv.w * wv.w;
  }
  float logit = acc + bias[lane];

  float m = logit;
  for (int off = 32; off > 0; off >>= 1) m = fmaxf(m, __shfl_xor(m, off));
  float p = expf(logit - m);
  float s = p;
  for (int off = 32; off > 0; off >>= 1) s += __shfl_xor(s, off);
  float prob = p / s;

  float myp = prob;
  float gsum = 0.f;
  float myg = 0.f; int myi = -1;
  for (int k = 0; k < K_TOP; ++k) {
    float bp = myp; int bi = lane;
    for (int off = 32; off > 0; off >>= 1) {
      float op = __shfl_xor(bp, off); int oi = __shfl_xor(bi, off);
      if (op > bp || (op == bp && oi < bi)) { bp = op; bi = oi; }
    }
    gsum += bp;
    if (lane == k) { myg = bp; myi = bi; }
    if (lane == bi) myp = -1.f;
  }
  if (lane < K_TOP) {
    topk_i[n * K_TOP + lane] = myi;
    topk_p[n * K_TOP + lane] = myg / (gsum + 1e-9f);
  }
}

// ---------------- per-chunk expert histogram ----------------
__global__ void hist_kernel(const int* __restrict__ topk_i, int* __restrict__ chunk_hist) {
  __shared__ int h[E_NUM];
  const int tid = threadIdx.x;
  if (tid < E_NUM) h[tid] = 0;
  __syncthreads();
  int e = topk_i[blockIdx.x * 256 + tid];
  atomicAdd(&h[e], 1);
  __syncthreads();
  if (tid < E_NUM) chunk_hist[blockIdx.x * E_NUM + tid] = h[tid];
}

// ---------------- exclusive scan over chunks, per expert ----------------
__global__ void scan_kernel(const int* __restrict__ chunk_hist, int* __restrict__ chunk_base) {
  const int e = threadIdx.x;  // 64 threads
  int run = 0;
  for (int c = 0; c < NCHUNK; ++c) {
    chunk_base[c * E_NUM + e] = run;
    run += chunk_hist[c * E_NUM + e];
  }
}

// ---------------- dispatch: slot = global stable rank within expert ----------------
__global__ void dispatch_kernel(const int* __restrict__ topk_i, const float* __restrict__ topk_p,
                                const int* __restrict__ chunk_base,
                                int* __restrict__ expert_tok, float* __restrict__ expert_gate) {
  __shared__ int eid[256];
  const int tid = threadIdx.x;
  const int m = blockIdx.x * 256 + tid;
  const int e = topk_i[m];
  eid[tid] = e;
  __syncthreads();
  int rank = 0;
  for (int t = 0; t < tid; ++t) rank += (eid[t] == e);
  int slot = chunk_base[blockIdx.x * E_NUM + e] + rank;
  if (slot < CAP) {
    expert_tok[e * CAP + slot] = m / K_TOP;
    expert_gate[e * CAP + slot] = topk_p[m];
  }
}

// ================= FAST PATH =================

// x fp32 -> bf16 row-major
__global__ void convert_x(const float* __restrict__ x, ushort* __restrict__ xb) {
  size_t idx = (size_t)blockIdx.x * 256 + threadIdx.x;   // 524288 threads, 8 elems each
  const float4* s4 = (const float4*)(x + idx * 8);
  float4 v0 = s4[0], v1 = s4[1];
  short8 o;
  o[0] = f2bf(v0.x); o[1] = f2bf(v0.y); o[2] = f2bf(v0.z); o[3] = f2bf(v0.w);
  o[4] = f2bf(v1.x); o[5] = f2bf(v1.y); o[6] = f2bf(v1.z); o[7] = f2bf(v1.w);
  *(short8*)(xb + idx * 8) = o;
}

// weights fp32 -> bf16, pre-tiled fragment layout.
// per expert blob (EW_STRIDE shorts): chunks c=0..47 (gate 0-15, up 16-31, down 32-47),
// chunk = 256n x 32k = 16 subtiles of 16n x 32k; subtile st=nt, within-subtile short
// idx = k8*128 + n_lo*8 + k_lo  (so lane l's 16B at l*16 = fragment (n=l&15, k=(l>>4)*8..)).
__global__ void convert_w(const float* __restrict__ wg_, const float* __restrict__ wu_,
                          const float* __restrict__ wd_, const float* __restrict__ swg,
                          const float* __restrict__ swu, const float* __restrict__ swd,
                          ushort* __restrict__ Wt) {
  int e = blockIdx.x / 48;
  int c = blockIdx.x - e * 48;
  int pass = c >> 4, ci = c & 15;
  const float* src;
  if (pass == 0)      src = (e < E_NUM) ? wg_ + (size_t)e * 131072 : swg + (size_t)(e - E_NUM) * 131072;
  else if (pass == 1) src = (e < E_NUM) ? wu_ + (size_t)e * 131072 : swu + (size_t)(e - E_NUM) * 131072;
  else                src = (e < E_NUM) ? wd_ + (size_t)e * 131072 : swd + (size_t)(e - E_NUM) * 131072;
  ushort* dst = Wt + (size_t)e * EW_STRIDE + (size_t)c * 8192;
  #pragma unroll
  for (int i = 0; i < 4; ++i) {
    int g = threadIdx.x + i * 256;        // 8-elem group, 0..1023
    int nt = g >> 6;
    int k8 = (g >> 4) & 3;
    int nl = g & 15;
    int n = nt * 16 + nl;
    size_t srcidx;
    if (pass < 2) srcidx = (size_t)n * 512 + ci * 32 + k8 * 8;
    else {
      int np = ci >> 3, kc = ci & 7;
      srcidx = (size_t)(np * 256 + n) * 256 + kc * 32 + k8 * 8;
    }
    const float4* s4 = (const float4*)(src + srcidx);
    float4 v0 = s4[0], v1 = s4[1];
    short8 o;
    o[0] = f2bf(v0.x); o[1] = f2bf(v0.y); o[2] = f2bf(v0.z); o[3] = f2bf(v0.w);
    o[4] = f2bf(v1.x); o[5] = f2bf(v1.y); o[6] = f2bf(v1.z); o[7] = f2bf(v1.w);
    *(short8*)(dst + g * 8) = o;
  }
}

// fill token lists for the two shared experts: every token, gate = 0.5
__global__ void init_shared_tok(int* __restrict__ tok_all, float* __restrict__ gate_all) {
  int i = blockIdx.x * 256 + threadIdx.x;   // 0..16383
  tok_all[TOK_ROUTED + i] = i & (N_TOK - 1);
  gate_all[TOK_ROUTED + i] = 0.5f;
}

// Unified FFN: 64-token tile x one (routed|shared) expert. bf16 pre-tiled weights,
// global_load_lds staging, 2-phase double-buffered K-loop (K-step 32).
__global__ void __launch_bounds__(256, 2) ffn_mfma(
    const ushort* __restrict__ xb, const ushort* __restrict__ Wt,
    const int* __restrict__ tok_all, const float* __restrict__ gate_all,
    float* __restrict__ out) {
  int e, tbase;
  if (blockIdx.x < 2 * (N_TOK / 64)) {          // shared tiles first (always full)
    int sid = blockIdx.x;
    int sh = sid & 1, mt = sid >> 1;
    e = E_NUM + sh;
    tbase = TOK_ROUTED + sh * N_TOK + mt * 64;
  } else {
    int rb = blockIdx.x - 2 * (N_TOK / 64);
    e = rb & (E_NUM - 1);
    int mt = rb >> 6;
    tbase = e * CAP + mt * 64;
    if (tok_all[tbase] < 0) return;             // contiguous fill -> empty tile
  }
  const ushort* wbase = Wt + (size_t)e * EW_STRIDE;

  __shared__ ushort Xs[2][2048];    // 2 x 4KB : 64tok x 32k tile
  __shared__ ushort Ws[2][8192];    // 2 x 16KB: 256n x 32k tile
  __shared__ ushort Act[16384];     // 32KB   : 64tok x 256f, tiled (st = rt*8 + f>>5)
  __shared__ int   toks[64];
  __shared__ float gts[64];

  const int tid = threadIdx.x;
  const int lane = tid & 63;
  const int wid = tid >> 6;
  const int rl = lane & 15;
  const int hi = lane >> 4;

  if (tid < 64) {
    int t = tok_all[tbase + tid];
    toks[tid] = t;
    gts[tid] = (t >= 0) ? gate_all[tbase + tid] : 0.f;
  }
  __syncthreads();

  int t0 = toks[wid * 16 + rl];
  const size_t myrow = (size_t)(t0 < 0 ? 0 : t0) * D_DIM + hi * 8;  // clamped; garbage rows discarded

  auto stageX = [&](int buf, int kc) {
    gload16(xb + myrow + kc * 32, &Xs[buf][wid * 512]);
  };
  auto stageW = [&](int buf, const ushort* chunk) {
    #pragma unroll
    for (int i = 0; i < 4; ++i)
      gload16(chunk + (wid * 4 + i) * 512 + lane * 8, &Ws[buf][(wid * 4 + i) * 512]);
  };
  auto compute_gu = [&](int buf, f32x4 (&acc)[4][4]) {
    bf16x8 a[4], b[4];
    #pragma unroll
    for (int ri = 0; ri < 4; ++ri) a[ri] = *(const bf16x8*)(&Xs[buf][ri * 512 + lane * 8]);
    #pragma unroll
    for (int bi = 0; bi < 4; ++bi) b[bi] = *(const bf16x8*)(&Ws[buf][(wid * 4 + bi) * 512 + lane * 8]);
    #pragma unroll
    for (int ri = 0; ri < 4; ++ri)
      #pragma unroll
      for (int bi = 0; bi < 4; ++bi)
        acc[ri][bi] = __builtin_amdgcn_mfma_f32_16x16x32_bf16(a[ri], b[bi], acc[ri][bi], 0, 0, 0);
  };
  auto compute_dn = [&](int buf, int kc, f32x4 (&acc)[4][4]) {
    bf16x8 a[4], b[4];
    #pragma unroll
    for (int ri = 0; ri < 4; ++ri) a[ri] = *(const bf16x8*)(&Act[(ri * 8 + kc) * 512 + lane * 8]);
    #pragma unroll
    for (int bi = 0; bi < 4; ++bi) b[bi] = *(const bf16x8*)(&Ws[buf][(wid * 4 + bi) * 512 + lane * 8]);
    #pragma unroll
    for (int ri = 0; ri < 4; ++ri)
      #pragma unroll
      for (int bi = 0; bi < 4; ++bi)
        acc[ri][bi] = __builtin_amdgcn_mfma_f32_16x16x32_bf16(a[ri], b[bi], acc[ri][bi], 0, 0, 0);
  };

  const f32x4 fzero = {0.f, 0.f, 0.f, 0.f};

  // ---- gate (which=0) then up (which=1); K = 512 = 16 chunks of 32 ----
  #pragma unroll 1
  for (int which = 0; which < 2; ++which) {
    const ushort* wblob = wbase + which * 131072;
    f32x4 acc[4][4];
    #pragma unroll
    for (int ri = 0; ri < 4; ++ri)
      #pragma unroll
      for (int bi = 0; bi < 4; ++bi) acc[ri][bi] = fzero;

    int cur = 0;
    stageX(0, 0); stageW(0, wblob);
    __syncthreads();
    #pragma unroll 1
    for (int kc = 0; kc < 16; ++kc) {
      if (kc < 15) { stageX(cur ^ 1, kc + 1); stageW(cur ^ 1, wblob + (kc + 1) * 8192); }
      compute_gu(cur, acc);
      __syncthreads();
      cur ^= 1;
    }
    // epilogue into tiled Act: element (r = ri*16+hi*4+j, f = wid*64+bi*16+rl)
    #pragma unroll
    for (int ri = 0; ri < 4; ++ri)
      #pragma unroll
      for (int bi = 0; bi < 4; ++bi) {
        int st = ri * 8 + wid * 2 + (bi >> 1);
        int base = st * 512 + ((bi & 1) * 2 + (rl >> 3)) * 128 + (rl & 7);
        #pragma unroll
        for (int j = 0; j < 4; ++j) {
          int idx = base + (hi * 4 + j) * 8;
          if (which == 0) {
            Act[idx] = f2bf(acc[ri][bi][j]);            // hg
          } else {
            float hg = bf2f(Act[idx]);
            float a = hg / (1.f + __expf(-hg)) * acc[ri][bi][j];
            Act[idx] = f2bf(a);                         // silu(hg)*hu
          }
        }
      }
    __syncthreads();
  }

  // ---- down: out[64 x 512], K = 256 = 8 chunks of 32, np halves of 256 cols ----
  #pragma unroll 1
  for (int np = 0; np < 2; ++np) {
    const ushort* wblob = wbase + 262144 + np * 65536;
    f32x4 acc[4][4];
    #pragma unroll
    for (int ri = 0; ri < 4; ++ri)
      #pragma unroll
      for (int bi = 0; bi < 4; ++bi) acc[ri][bi] = fzero;

    int cur = 0;
    stageW(0, wblob);
    __syncthreads();
    #pragma unroll 1
    for (int kc = 0; kc < 8; ++kc) {
      if (kc < 7) stageW(cur ^ 1, wblob + (kc + 1) * 8192);
      compute_dn(cur, kc, acc);
      __syncthreads();
      cur ^= 1;
    }
    #pragma unroll
    for (int ri = 0; ri < 4; ++ri)
      #pragma unroll
      for (int bi = 0; bi < 4; ++bi)
        #pragma unroll
        for (int j = 0; j < 4; ++j) {
          int r = ri * 16 + hi * 4 + j;
          int t = toks[r];
          if (t >= 0) {
            int col = np * 256 + wid * 64 + bi * 16 + rl;
            atomicAdd(out + (size_t)t * D_DIM + col, gts[r] * acc[ri][bi][j]);
          }
        }
  }
}

// ================= LEGACY PATH (round-2, used when ws too small) =================

__global__ void __launch_bounds__(256, 2) expert_ffn_mfma(
    const float* __restrict__ x, const float* __restrict__ wg_,
    const float* __restrict__ wu_, const float* __restrict__ wd_,
    const int* __restrict__ expert_tok, const float* __restrict__ expert_gate,
    float* __restrict__ out) {
  const int e = blockIdx.x & (E_NUM - 1);
  const int mt = blockIdx.x >> 6;
  const int s0 = mt * 64;
  if (expert_tok[e * CAP + s0] < 0) return;

  __shared__ ushort Xs[64][72];
  __shared__ ushort Ws[256][72];
  __shared__ ushort Act[64][264];
  __shared__ int   toks[64];
  __shared__ float gts[64];

  const int tid = threadIdx.x;
  const int lane = tid & 63;
  const int wid = tid >> 6;
  const int rl = lane & 15;
  const int ko = (lane >> 4) * 8;
  const int rquad = (lane >> 4) * 4;

  if (tid < 64) {
    int t = expert_tok[e * CAP + s0 + tid];
    toks[tid] = t;
    gts[tid] = (t >= 0) ? expert_gate[e * CAP + s0 + tid] : 0.f;
  }
  __syncthreads();

  float4 px[4], pw[16];

  auto loadX = [&](int kb) {
    #pragma unroll
    for (int it = 0; it < 4; ++it) {
      int idx = tid + it * 256;
      int row = idx >> 4, c4 = (idx & 15) << 2;
      int t = toks[row];
      px[it] = (t >= 0) ? *(const float4*)(x + (size_t)t * D_DIM + kb * 64 + c4)
                        : make_float4(0.f, 0.f, 0.f, 0.f);
    }
  };
  auto writeX = [&]() {
    #pragma unroll
    for (int it = 0; it < 4; ++it) {
      int idx = tid + it * 256;
      int row = idx >> 4, c4 = (idx & 15) << 2;
      ushort4 h; h.x = f2bf(px[it].x); h.y = f2bf(px[it].y);
      h.z = f2bf(px[it].z); h.w = f2bf(px[it].w);
      *(ushort4*)&Xs[row][c4] = h;
    }
  };
  auto loadW = [&](const float* src, int ldk, int kb) {
    #pragma unroll
    for (int it = 0; it < 16; ++it) {
      int idx = tid + it * 256;
      int row = idx >> 4, c4 = (idx & 15) << 2;
      pw[it] = *(const float4*)(src + (size_t)row * ldk + kb * 64 + c4);
    }
  };
  auto writeW = [&]() {
    #pragma unroll
    for (int it = 0; it < 16; ++it) {
      int idx = tid + it * 256;
      int row = idx >> 4, c4 = (idx & 15) << 2;
      ushort4 h; h.x = f2bf(pw[it].x); h.y = f2bf(pw[it].y);
      h.z = f2bf(pw[it].z); h.w = f2bf(pw[it].w);
      *(ushort4*)&Ws[row][c4] = h;
    }
  };
  auto compute = [&](const ushort* Ab, int lda, f32x4 (&acc)[4][4]) {
    #pragma unroll
    for (int kk = 0; kk < 2; ++kk) {
      bf16x8 a[4], b[4];
      #pragma unroll
      for (int ri = 0; ri < 4; ++ri)
        a[ri] = *(const bf16x8*)(Ab + (size_t)(ri * 16 + rl) * lda + kk * 32 + ko);
      #pragma unroll
      for (int bi = 0; bi < 4; ++bi)
        b[bi] = *(const bf16x8*)(&Ws[wid * 64 + bi * 16 + rl][kk * 32 + ko]);
      #pragma unroll
      for (int ri = 0; ri < 4; ++ri)
        #pragma unroll
        for (int bi = 0; bi < 4; ++bi)
          acc[ri][bi] = __builtin_amdgcn_mfma_f32_16x16x32_bf16(a[ri], b[bi], acc[ri][bi], 0, 0, 0);
    }
  };

  const f32x4 fzero = {0.f, 0.f, 0.f, 0.f};

  #pragma unroll 1
  for (int which = 0; which < 2; ++which) {
    const float* wsrc = (which == 0 ? wg_ : wu_) + (size_t)e * F_DIM * D_DIM;
    f32x4 acc[4][4];
    #pragma unroll
    for (int ri = 0; ri < 4; ++ri)
      #pragma unroll
      for (int bi = 0; bi < 4; ++bi) acc[ri][bi] = fzero;

    loadX(0); loadW(wsrc, D_DIM, 0);
    writeX(); writeW();
    __syncthreads();
    for (int kb = 0; kb < 8; ++kb) {
      if (kb < 7) { loadX(kb + 1); loadW(wsrc, D_DIM, kb + 1); }
      compute(&Xs[0][0], 72, acc);
      __syncthreads();
      if (kb < 7) { writeX(); writeW(); __syncthreads(); }
    }
    #pragma unroll
    for (int ri = 0; ri < 4; ++ri)
      #pragma unroll
      for (int bi = 0; bi < 4; ++bi)
        #pragma unroll
        for (int j = 0; j < 4; ++j) {
          int r = ri * 16 + rquad + j;
          int c = wid * 64 + bi * 16 + rl;
          if (which == 0) {
            Act[r][c] = f2bf(acc[ri][bi][j]);
          } else {
            float hg = bf2f(Act[r][c]);
            float a = hg / (1.f + __expf(-hg)) * acc[ri][bi][j];
            Act[r][c] = f2bf(a);
          }
        }
    __syncthreads();
  }

  #pragma unroll 1
  for (int np = 0; np < 2; ++np) {
    const float* wsrc = wd_ + ((size_t)e * D_DIM + np * 256) * F_DIM;
    f32x4 acc[4][4];
    #pragma unroll
    for (int ri = 0; ri < 4; ++ri)
      #pragma unroll
      for (int bi = 0; bi < 4; ++bi) acc[ri][bi] = fzero;

    loadW(wsrc, F_DIM, 0); writeW();
    __syncthreads();
    for (int kb = 0; kb < 4; ++kb) {
      if (kb < 3) loadW(wsrc, F_DIM, kb + 1);
      compute(&Act[0][kb * 64], 264, acc);
      __syncthreads();
      if (kb < 3) { writeW(); __syncthreads(); }
    }
    #pragma unroll
    for (int ri = 0; ri < 4; ++ri)
      #pragma unroll
      for (int bi = 0; bi < 4; ++bi)
        #pragma unroll
        for (int j = 0; j < 4; ++j) {
          int r = ri * 16 + rquad + j;
          int t = toks[r];
          if (t >= 0) {
            int c = np * 256 + wid * 64 + bi * 16 + rl;
            atomicAdd(out + (size_t)t * D_DIM + c, gts[r] * acc[ri][bi][j]);
          }
        }
  }
}

__global__ void __launch_bounds__(256, 2) shared_ffn_mfma(
    const float* __restrict__ x, const float* __restrict__ swg,
    const float* __restrict__ swu, const float* __restrict__ swd,
    float* __restrict__ out) {
  const int row0 = blockIdx.x * 32;

  __shared__ ushort Xs[32][72];
  __shared__ ushort Ws[256][72];
  __shared__ ushort Act[32][264];

  const int tid = threadIdx.x;
  const int lane = tid & 63;
  const int wid = tid >> 6;
  const int rl = lane & 15;
  const int ko = (lane >> 4) * 8;
  const int rquad = (lane >> 4) * 4;

  float4 px[2], pw[16];

  auto loadX = [&](int kb) {
    #pragma unroll
    for (int it = 0; it < 2; ++it) {
      int idx = tid + it * 256;
      int row = idx >> 4, c4 = (idx & 15) << 2;
      px[it] = *(const float4*)(x + (size_t)(row0 + row) * D_DIM + kb * 64 + c4);
    }
  };
  auto writeX = [&]() {
    #pragma unroll
    for (int it = 0; it < 2; ++it) {
      int idx = tid + it * 256;
      int row = idx >> 4, c4 = (idx & 15) << 2;
      ushort4 h; h.x = f2bf(px[it].x); h.y = f2bf(px[it].y);
      h.z = f2bf(px[it].z); h.w = f2bf(px[it].w);
      *(ushort4*)&Xs[row][c4] = h;
    }
  };
  auto loadW = [&](const float* src, int ldk, int kb) {
    #pragma unroll
    for (int it = 0; it < 16; ++it) {
      int idx = tid + it * 256;
      int row = idx >> 4, c4 = (idx & 15) << 2;
      pw[it] = *(const float4*)(src + (size_t)row * ldk + kb * 64 + c4);
    }
  };
  auto writeW = [&]() {
    #pragma unroll
    for (int it = 0; it < 16; ++it) {
      int idx = tid + it * 256;
      int row = idx >> 4, c4 = (idx & 15) << 2;
      ushort4 h; h.x = f2bf(pw[it].x); h.y = f2bf(pw[it].y);
      h.z = f2bf(pw[it].z); h.w = f2bf(pw[it].w);
      *(ushort4*)&Ws[row][c4] = h;
    }
  };
  auto compute = [&](const ushort* Ab, int lda, f32x4 (&acc)[2][4]) {
    #pragma unroll
    for (int kk = 0; kk < 2; ++kk) {
      bf16x8 a[2], b[4];
      #pragma unroll
      for (int ri = 0; ri < 2; ++ri)
        a[ri] = *(const bf16x8*)(Ab + (size_t)(ri * 16 + rl) * lda + kk * 32 + ko);
      #pragma unroll
      for (int bi = 0; bi < 4; ++bi)
        b[bi] = *(const bf16x8*)(&Ws[wid * 64 + bi * 16 + rl][kk * 32 + ko]);
      #pragma unroll
      for (int ri = 0; ri < 2; ++ri)
        #pragma unroll
        for (int bi = 0; bi < 4; ++bi)
          acc[ri][bi] = __builtin_amdgcn_mfma_f32_16x16x32_bf16(a[ri], b[bi], acc[ri][bi], 0, 0, 0);
    }
  };

  const f32x4 fzero = {0.f, 0.f, 0.f, 0.f};
  f32x4 accd[2][2][4];
  #pragma unroll
  for (int np = 0; np < 2; ++np)
    #pragma unroll
    for (int ri = 0; ri < 2; ++ri)
      #pragma unroll
      for (int bi = 0; bi < 4; ++bi) accd[np][ri][bi] = fzero;

  #pragma unroll 1
  for (int sh = 0; sh < SH_NUM; ++sh) {
    #pragma unroll 1
    for (int which = 0; which < 2; ++which) {
      const float* wsrc = (which == 0 ? swg : swu) + (size_t)sh * F_DIM * D_DIM;
      f32x4 acc[2][4];
      #pragma unroll
      for (int ri = 0; ri < 2; ++ri)
        #pragma unroll
        for (int bi = 0; bi < 4; ++bi) acc[ri][bi] = fzero;

      loadX(0); loadW(wsrc, D_DIM, 0);
      writeX(); writeW();
      __syncthreads();
      for (int kb = 0; kb < 8; ++kb) {
        if (kb < 7) { loadX(kb + 1); loadW(wsrc, D_DIM, kb + 1); }
        compute(&Xs[0][0], 72, acc);
        __syncthreads();
        if (kb < 7) { writeX(); writeW(); __syncthreads(); }
      }
      #pragma unroll
      for (int ri = 0; ri < 2; ++ri)
        #pragma unroll
        for (int bi = 0; bi < 4; ++bi)
          #pragma unroll
          for (int j = 0; j < 4; ++j) {
            int r = ri * 16 + rquad + j;
            int c = wid * 64 + bi * 16 + rl;
            if (which == 0) {
              Act[r][c] = f2bf(acc[ri][bi][j]);
            } else {
              float hg = bf2f(Act[r][c]);
              float a = hg / (1.f + __expf(-hg)) * acc[ri][bi][j];
              Act[r][c] = f2bf(a);
            }
          }
      __syncthreads();
    }
    #pragma unroll
    for (int np = 0; np < 2; ++np) {
      const float* wsrc = swd + ((size_t)sh * D_DIM + np * 256) * F_DIM;
      loadW(wsrc, F_DIM, 0); writeW();
      __syncthreads();
      for (int kb = 0; kb < 4; ++kb) {
        if (kb < 3) loadW(wsrc, F_DIM, kb + 1);
        compute(&Act[0][kb * 64], 264, accd[np]);
        __syncthreads();
        if (kb < 3) { writeW(); __syncthreads(); }
      }
    }
  }

  #pragma unroll
  for (int np = 0; np < 2; ++np)
    #pragma unroll
    for (int ri = 0; ri < 2; ++ri)
      #pragma unroll
      for (int bi = 0; bi < 4; ++bi)
        #pragma unroll
        for (int j = 0; j < 4; ++j) {
          int r = ri * 16 + rquad + j;
          int c = np * 256 + wid * 64 + bi * 16 + rl;
          out[(size_t)(row0 + r) * D_DIM + c] = 0.5f * accd[np][ri][bi][j];
        }
}

extern "C" void kernel_launch(void* const* d_in, const int* in_sizes, int n_in,
                              void* d_out, int out_size, void* d_ws, size_t ws_size,
                              hipStream_t stream) {
  const float* x    = (const float*)d_in[0];
  const float* rw   = (const float*)d_in[1];
  const float* bias = (const float*)d_in[2];
  const float* swg  = (const float*)d_in[3];
  const float* swu  = (const float*)d_in[4];
  const float* swd  = (const float*)d_in[5];
  const float* wg   = (const float*)d_in[6];
  const float* wu   = (const float*)d_in[7];
  const float* wd   = (const float*)d_in[8];
  float* out = (float*)d_out;

  const size_t need = X_BF_BYTES + WT_BYTES + 2 * (size_t)M_ENT * 4 +
                      2 * (size_t)NCHUNK * E_NUM * 4 + 2 * (size_t)TOK_TOTAL * 4;

  if (ws_size >= need) {
    char* ws = (char*)d_ws;
    ushort* x_bf     = (ushort*)ws; ws += X_BF_BYTES;
    ushort* Wt       = (ushort*)ws; ws += WT_BYTES;
    int*   topk_i    = (int*)ws;    ws += (size_t)M_ENT * 4;
    float* topk_p    = (float*)ws;  ws += (size_t)M_ENT * 4;
    int*   chunk_hist= (int*)ws;    ws += (size_t)NCHUNK * E_NUM * 4;
    int*   chunk_base= (int*)ws;    ws += (size_t)NCHUNK * E_NUM * 4;
    int*   tok_all   = (int*)ws;    ws += (size_t)TOK_TOTAL * 4;
    float* gate_all  = (float*)ws;  ws += (size_t)TOK_TOTAL * 4;

    convert_x<<<2048, 256, 0, stream>>>(x, x_bf);
    convert_w<<<E_TOT * 48, 256, 0, stream>>>(wg, wu, wd, swg, swu, swd, Wt);
    router_topk<<<N_TOK / 4, 256, 0, stream>>>(x, rw, bias, topk_i, topk_p);
    hipMemsetAsync(tok_all, 0xFF, (size_t)TOK_ROUTED * 4, stream);
    hipMemsetAsync(out, 0, (size_t)out_size * 4, stream);
    hist_kernel<<<NCHUNK, 256, 0, stream>>>(topk_i, chunk_hist);
    scan_kernel<<<1, 64, 0, stream>>>(chunk_hist, chunk_base);
    dispatch_kernel<<<NCHUNK, 256, 0, stream>>>(topk_i, topk_p, chunk_base, tok_all, gate_all);
    init_shared_tok<<<64, 256, 0, stream>>>(tok_all, gate_all);
    ffn_mfma<<<2 * (N_TOK / 64) + (CAP / 64) * E_NUM, 256, 0, stream>>>(
        x_bf, Wt, tok_all, gate_all, out);
  } else {
    char* ws = (char*)d_ws;
    int*   topk_i      = (int*)ws;   ws += (size_t)M_ENT * 4;
    float* topk_p      = (float*)ws; ws += (size_t)M_ENT * 4;
    int*   chunk_hist  = (int*)ws;   ws += (size_t)NCHUNK * E_NUM * 4;
    int*   chunk_base  = (int*)ws;   ws += (size_t)NCHUNK * E_NUM * 4;
    int*   expert_tok  = (int*)ws;   ws += (size_t)E_NUM * CAP * 4;
    float* expert_gate = (float*)ws; ws += (size_t)E_NUM * CAP * 4;

    router_topk<<<N_TOK / 4, 256, 0, stream>>>(x, rw, bias, topk_i, topk_p);
    hipMemsetAsync(expert_tok, 0xFF, (size_t)E_NUM * CAP * 4, stream);
    hist_kernel<<<NCHUNK, 256, 0, stream>>>(topk_i, chunk_hist);
    scan_kernel<<<1, 64, 0, stream>>>(chunk_hist, chunk_base);
    dispatch_kernel<<<NCHUNK, 256, 0, stream>>>(topk_i, topk_p, chunk_base, expert_tok, expert_gate);
    shared_ffn_mfma<<<N_TOK / 32, 256, 0, stream>>>(x, swg, swu, swd, out);
    expert_ffn_mfma<<<(CAP / 64) * E_NUM, 256, 0, stream>>>(x, wg, wu, wd, expert_tok, expert_gate, out);
  }
}

// Round 4
// 408.987 us; speedup vs baseline: 4.9776x; 1.0122x over previous
//
#include <hip/hip_runtime.h>
#include <hip/hip_bf16.h>
#include <math.h>

#define N_TOK 8192
#define D_DIM 512
#define F_DIM 256
#define E_NUM 64
#define SH_NUM 2
#define K_TOP 6
#define CAP   1536
#define M_ENT (N_TOK * K_TOP)   // 49152
#define NCHUNK (M_ENT / 256)    // 192

// fast-path workspace geometry (element = ushort/bf16 unless noted)
#define EW_STRIDE 393216            // shorts per expert blob (48 chunks x 8192)
#define E_TOT (E_NUM + SH_NUM)      // 66
#define X_BF_BYTES   (8388608ull)                    // 8192*512*2
#define WT_BYTES     ((size_t)E_TOT * EW_STRIDE * 2) // 51,904,512
#define TOK_ROUTED   (E_NUM * CAP)                   // 98304 entries
#define TOK_TOTAL    (TOK_ROUTED + SH_NUM * N_TOK)   // +16384

#define SLOT 18432                  // shorts per ring slot (X 2048 | Wg 8192 | Wu 8192)

typedef __attribute__((ext_vector_type(8))) short bf16x8;
typedef __attribute__((ext_vector_type(8))) short short8;
typedef __attribute__((ext_vector_type(4))) float f32x4;

#define VMCNT(n) asm volatile("s_waitcnt vmcnt(" #n ")" ::: "memory")

__device__ __forceinline__ ushort f2bf(float f) {
  union { float f; unsigned u; } c; c.f = f;
  return (ushort)((c.u + 0x7FFFu + ((c.u >> 16) & 1u)) >> 16);
}
__device__ __forceinline__ float bf2f(ushort h) {
  union { unsigned u; float f; } c; c.u = ((unsigned)h) << 16;
  return c.f;
}
__device__ __forceinline__ void gload16(const void* g, void* l) {
  __builtin_amdgcn_global_load_lds(
      (const __attribute__((address_space(1))) void*)g,
      (__attribute__((address_space(3))) void*)l, 16, 0, 0);
}

// ---------------- Router + softmax + top-6 (one wave per token) ----------------
__global__ void router_topk(const float* __restrict__ x, const float* __restrict__ rw,
                            const float* __restrict__ bias, int* __restrict__ topk_i,
                            float* __restrict__ topk_p) {
  const int wave = threadIdx.x >> 6;
  const int lane = threadIdx.x & 63;      // lane == expert id (E=64)
  const int n = blockIdx.x * 4 + wave;
  if (n >= N_TOK) return;

  const float4* xr = (const float4*)(x + (size_t)n * D_DIM);
  const float4* wr = (const float4*)(rw + (size_t)lane * D_DIM);
  float acc = 0.f;
  #pragma unroll 4
  for (int d4 = 0; d4 < D_DIM / 4; ++d4) {
    float4 xv = xr[d4]; float4 wv = wr[d4];
    acc += xv.x * wv.x + xv.y * wv.y + xv.z * wv.z + xv.w * wv.w;
  }
  float logit = acc + bias[lane];

  float m = logit;
  for (int off = 32; off > 0; off >>= 1) m = fmaxf(m, __shfl_xor(m, off));
  float p = expf(logit - m);
  float s = p;
  for (int off = 32; off > 0; off >>= 1) s += __shfl_xor(s, off);
  float prob = p / s;

  float myp = prob;
  float gsum = 0.f;
  float myg = 0.f; int myi = -1;
  for (int k = 0; k < K_TOP; ++k) {
    float bp = myp; int bi = lane;
    for (int off = 32; off > 0; off >>= 1) {
      float op = __shfl_xor(bp, off); int oi = __shfl_xor(bi, off);
      if (op > bp || (op == bp && oi < bi)) { bp = op; bi = oi; }
    }
    gsum += bp;
    if (lane == k) { myg = bp; myi = bi; }
    if (lane == bi) myp = -1.f;
  }
  if (lane < K_TOP) {
    topk_i[n * K_TOP + lane] = myi;
    topk_p[n * K_TOP + lane] = myg / (gsum + 1e-9f);
  }
}

// ---------------- per-chunk expert histogram ----------------
__global__ void hist_kernel(const int* __restrict__ topk_i, int* __restrict__ chunk_hist) {
  __shared__ int h[E_NUM];
  const int tid = threadIdx.x;
  if (tid < E_NUM) h[tid] = 0;
  __syncthreads();
  int e = topk_i[blockIdx.x * 256 + tid];
  atomicAdd(&h[e], 1);
  __syncthreads();
  if (tid < E_NUM) chunk_hist[blockIdx.x * E_NUM + tid] = h[tid];
}

// ---------------- exclusive scan over chunks, per expert ----------------
__global__ void scan_kernel(const int* __restrict__ chunk_hist, int* __restrict__ chunk_base) {
  const int e = threadIdx.x;  // 64 threads
  int run = 0;
  for (int c = 0; c < NCHUNK; ++c) {
    chunk_base[c * E_NUM + e] = run;
    run += chunk_hist[c * E_NUM + e];
  }
}

// ---------------- dispatch: slot = global stable rank within expert ----------------
__global__ void dispatch_kernel(const int* __restrict__ topk_i, const float* __restrict__ topk_p,
                                const int* __restrict__ chunk_base,
                                int* __restrict__ expert_tok, float* __restrict__ expert_gate) {
  __shared__ int eid[256];
  const int tid = threadIdx.x;
  const int m = blockIdx.x * 256 + tid;
  const int e = topk_i[m];
  eid[tid] = e;
  __syncthreads();
  int rank = 0;
  for (int t = 0; t < tid; ++t) rank += (eid[t] == e);
  int slot = chunk_base[blockIdx.x * E_NUM + e] + rank;
  if (slot < CAP) {
    expert_tok[e * CAP + slot] = m / K_TOP;
    expert_gate[e * CAP + slot] = topk_p[m];
  }
}

// ================= FAST PATH =================

// x fp32 -> bf16 row-major
__global__ void convert_x(const float* __restrict__ x, ushort* __restrict__ xb) {
  size_t idx = (size_t)blockIdx.x * 256 + threadIdx.x;
  const float4* s4 = (const float4*)(x + idx * 8);
  float4 v0 = s4[0], v1 = s4[1];
  short8 o;
  o[0] = f2bf(v0.x); o[1] = f2bf(v0.y); o[2] = f2bf(v0.z); o[3] = f2bf(v0.w);
  o[4] = f2bf(v1.x); o[5] = f2bf(v1.y); o[6] = f2bf(v1.z); o[7] = f2bf(v1.w);
  *(short8*)(xb + idx * 8) = o;
}

// weights fp32 -> bf16, pre-tiled fragment layout (see round-3 notes).
__global__ void convert_w(const float* __restrict__ wg_, const float* __restrict__ wu_,
                          const float* __restrict__ wd_, const float* __restrict__ swg,
                          const float* __restrict__ swu, const float* __restrict__ swd,
                          ushort* __restrict__ Wt) {
  int e = blockIdx.x / 48;
  int c = blockIdx.x - e * 48;
  int pass = c >> 4, ci = c & 15;
  const float* src;
  if (pass == 0)      src = (e < E_NUM) ? wg_ + (size_t)e * 131072 : swg + (size_t)(e - E_NUM) * 131072;
  else if (pass == 1) src = (e < E_NUM) ? wu_ + (size_t)e * 131072 : swu + (size_t)(e - E_NUM) * 131072;
  else                src = (e < E_NUM) ? wd_ + (size_t)e * 131072 : swd + (size_t)(e - E_NUM) * 131072;
  ushort* dst = Wt + (size_t)e * EW_STRIDE + (size_t)c * 8192;
  #pragma unroll
  for (int i = 0; i < 4; ++i) {
    int g = threadIdx.x + i * 256;
    int nt = g >> 6;
    int k8 = (g >> 4) & 3;
    int nl = g & 15;
    int n = nt * 16 + nl;
    size_t srcidx;
    if (pass < 2) srcidx = (size_t)n * 512 + ci * 32 + k8 * 8;
    else {
      int np = ci >> 3, kc = ci & 7;
      srcidx = (size_t)(np * 256 + n) * 256 + kc * 32 + k8 * 8;
    }
    const float4* s4 = (const float4*)(src + srcidx);
    float4 v0 = s4[0], v1 = s4[1];
    short8 o;
    o[0] = f2bf(v0.x); o[1] = f2bf(v0.y); o[2] = f2bf(v0.z); o[3] = f2bf(v0.w);
    o[4] = f2bf(v1.x); o[5] = f2bf(v1.y); o[6] = f2bf(v1.z); o[7] = f2bf(v1.w);
    *(short8*)(dst + g * 8) = o;
  }
}

// fill token lists for the two shared experts: every token, gate = 0.5
__global__ void init_shared_tok(int* __restrict__ tok_all, float* __restrict__ gate_all) {
  int i = blockIdx.x * 256 + threadIdx.x;
  tok_all[TOK_ROUTED + i] = i & (N_TOK - 1);
  gate_all[TOK_ROUTED + i] = 0.5f;
}

// Unified FFN v2: 64-token tile x one expert, 512 threads (8 waves, 2 row x 4 col),
// fused gate+up, 3-slot ring with counted vmcnt (never 0 in steady state),
// raw s_barrier + sched_barrier, setprio around MFMA clusters.
__global__ void __launch_bounds__(512, 1) ffn_mfma(
    const ushort* __restrict__ xb, const ushort* __restrict__ Wt,
    const int* __restrict__ tok_all, const float* __restrict__ gate_all,
    float* __restrict__ out) {
  int e, tbase;
  if (blockIdx.x < 2 * (N_TOK / 64)) {          // shared tiles first (always full)
    int sid = blockIdx.x;
    int sh = sid & 1, mt = sid >> 1;
    e = E_NUM + sh;
    tbase = TOK_ROUTED + sh * N_TOK + mt * 64;
  } else {
    int rb = blockIdx.x - 2 * (N_TOK / 64);
    e = rb & (E_NUM - 1);
    int mt = rb >> 6;
    tbase = e * CAP + mt * 64;
    if (tok_all[tbase] < 0) return;             // contiguous fill -> empty tile
  }
  const ushort* wbase = Wt + (size_t)e * EW_STRIDE;

  __shared__ ushort RING[3 * SLOT];   // 108 KB: per slot X[2048] Wg[8192] Wu[8192]
  __shared__ ushort Act[16384];       // 32 KB: 64tok x 256f, fragment-tiled
  __shared__ int   toks[64];
  __shared__ float gts[64];

  const int tid = threadIdx.x;
  const int lane = tid & 63;
  const int wid = tid >> 6;        // 0..7
  const int wr = wid >> 2;         // 0..1  (row half: 32 tokens)
  const int wc = wid & 3;          // 0..3  (col quarter)
  const int rl = lane & 15;
  const int hi = lane >> 4;

  if (tid < 64) {
    int t = tok_all[tbase + tid];
    toks[tid] = t;
    gts[tid] = (t >= 0) ? gate_all[tbase + tid] : 0.f;
  }
  __syncthreads();

  // waves 0-3 stage the X tile (subtile = wid): per-lane source row
  int stok = 0;
  if (wid < 4) { int t = toks[wid * 16 + rl]; stok = (t < 0) ? 0 : t; }
  const ushort* xsrc = xb + (size_t)stok * D_DIM + hi * 8;

  auto stage_gu = [&](int sl, int kc) {
    ushort* dst = RING + sl * SLOT;
    if (wid < 4)
      gload16(xsrc + kc * 32, dst + wid * 512);
    #pragma unroll
    for (int i = 0; i < 2; ++i) {
      int s = wid * 2 + i;
      gload16(wbase + kc * 8192 + s * 512 + lane * 8, dst + 2048 + s * 512);
      gload16(wbase + 131072 + kc * 8192 + s * 512 + lane * 8, dst + 10240 + s * 512);
    }
  };
  auto stage_dn = [&](int sl, int kc) {
    ushort* dst = RING + sl * SLOT;
    #pragma unroll
    for (int i = 0; i < 4; ++i) {
      int s = wid * 4 + i;
      gload16(wbase + 262144 + (s >> 4) * 65536 + kc * 8192 + (s & 15) * 512 + lane * 8,
              dst + s * 512);
    }
  };

  const f32x4 fzero = {0.f, 0.f, 0.f, 0.f};
  f32x4 accg[2][4], accu[2][4];
  #pragma unroll
  for (int ri = 0; ri < 2; ++ri)
    #pragma unroll
    for (int bi = 0; bi < 4; ++bi) { accg[ri][bi] = fzero; accu[ri][bi] = fzero; }

  // ---- fused gate+up: 16 K-steps of 32 ----
  stage_gu(0, 0); stage_gu(1, 1);
  {
    int sl_c = 0, sl_n = 2;
    #pragma unroll 1
    for (int kc = 0; kc < 16; ++kc) {
      if (kc < 14) { stage_gu(sl_n, kc + 2); sl_n = (sl_n == 2) ? 0 : sl_n + 1; }
      if (kc < 14)      { if (wid < 4) VMCNT(10); else VMCNT(8); }
      else if (kc == 14){ if (wid < 4) VMCNT(5);  else VMCNT(4); }
      else              VMCNT(0);
      __builtin_amdgcn_s_barrier();
      __builtin_amdgcn_sched_barrier(0);
      {
        const ushort* base = RING + sl_c * SLOT;
        bf16x8 a[2], bg[4], bu[4];
        #pragma unroll
        for (int ri = 0; ri < 2; ++ri)
          a[ri] = *(const bf16x8*)(base + (wr * 2 + ri) * 512 + lane * 8);
        #pragma unroll
        for (int bi = 0; bi < 4; ++bi) {
          bg[bi] = *(const bf16x8*)(base + 2048 + (wc * 4 + bi) * 512 + lane * 8);
          bu[bi] = *(const bf16x8*)(base + 10240 + (wc * 4 + bi) * 512 + lane * 8);
        }
        __builtin_amdgcn_s_setprio(1);
        #pragma unroll
        for (int ri = 0; ri < 2; ++ri)
          #pragma unroll
          for (int bi = 0; bi < 4; ++bi) {
            accg[ri][bi] = __builtin_amdgcn_mfma_f32_16x16x32_bf16(a[ri], bg[bi], accg[ri][bi], 0, 0, 0);
            accu[ri][bi] = __builtin_amdgcn_mfma_f32_16x16x32_bf16(a[ri], bu[bi], accu[ri][bi], 0, 0, 0);
          }
        __builtin_amdgcn_s_setprio(0);
      }
      sl_c = (sl_c == 2) ? 0 : sl_c + 1;
      __builtin_amdgcn_s_barrier();
    }
  }

  // ---- silu(g)*u in-register -> Act (fragment-tiled bf16) ----
  #pragma unroll
  for (int ri = 0; ri < 2; ++ri)
    #pragma unroll
    for (int bi = 0; bi < 4; ++bi) {
      int st = (wr * 2 + ri) * 8 + wc * 2 + (bi >> 1);
      int base = st * 512 + ((bi & 1) * 2 + (rl >> 3)) * 128 + (rl & 7);
      #pragma unroll
      for (int j = 0; j < 4; ++j) {
        float g = accg[ri][bi][j], u = accu[ri][bi][j];
        Act[base + (hi * 4 + j) * 8] = f2bf(g / (1.f + __expf(-g)) * u);
      }
    }

  // ---- down: out[64 x 512], 8 K-steps of 32 over F ----
  f32x4 accd[2][8];
  #pragma unroll
  for (int ri = 0; ri < 2; ++ri)
    #pragma unroll
    for (int bj = 0; bj < 8; ++bj) accd[ri][bj] = fzero;

  stage_dn(0, 0); stage_dn(1, 1);
  asm volatile("s_waitcnt lgkmcnt(0)" ::: "memory");
  __builtin_amdgcn_s_barrier();
  __builtin_amdgcn_sched_barrier(0);
  {
    int sl_c = 0, sl_n = 2;
    #pragma unroll 1
    for (int kc = 0; kc < 8; ++kc) {
      if (kc < 6) { stage_dn(sl_n, kc + 2); sl_n = (sl_n == 2) ? 0 : sl_n + 1; }
      if (kc < 6)       VMCNT(8);
      else if (kc == 6) VMCNT(4);
      else              VMCNT(0);
      __builtin_amdgcn_s_barrier();
      __builtin_amdgcn_sched_barrier(0);
      {
        const ushort* base = RING + sl_c * SLOT;
        bf16x8 a[2], b[8];
        #pragma unroll
        for (int ri = 0; ri < 2; ++ri)
          a[ri] = *(const bf16x8*)(Act + ((wr * 2 + ri) * 8 + kc) * 512 + lane * 8);
        #pragma unroll
        for (int bj = 0; bj < 8; ++bj)
          b[bj] = *(const bf16x8*)(base + (wc * 8 + bj) * 512 + lane * 8);
        __builtin_amdgcn_s_setprio(1);
        #pragma unroll
        for (int ri = 0; ri < 2; ++ri)
          #pragma unroll
          for (int bj = 0; bj < 8; ++bj)
            accd[ri][bj] = __builtin_amdgcn_mfma_f32_16x16x32_bf16(a[ri], b[bj], accd[ri][bj], 0, 0, 0);
        __builtin_amdgcn_s_setprio(0);
      }
      sl_c = (sl_c == 2) ? 0 : sl_c + 1;
      __builtin_amdgcn_s_barrier();
    }
  }

  // ---- scatter-add epilogue ----
  #pragma unroll
  for (int ri = 0; ri < 2; ++ri)
    #pragma unroll
    for (int j = 0; j < 4; ++j) {
      int r = wr * 32 + ri * 16 + hi * 4 + j;
      int t = toks[r];
      if (t < 0) continue;
      float gt = gts[r];
      float* orow = out + (size_t)t * D_DIM + wc * 128 + rl;
      #pragma unroll
      for (int bj = 0; bj < 8; ++bj)
        atomicAdd(orow + bj * 16, gt * accd[ri][bj][j]);
    }
}

// ================= LEGACY PATH (round-2, used when ws too small) =================

__global__ void __launch_bounds__(256, 2) expert_ffn_mfma(
    const float* __restrict__ x, const float* __restrict__ wg_,
    const float* __restrict__ wu_, const float* __restrict__ wd_,
    const int* __restrict__ expert_tok, const float* __restrict__ expert_gate,
    float* __restrict__ out) {
  const int e = blockIdx.x & (E_NUM - 1);
  const int mt = blockIdx.x >> 6;
  const int s0 = mt * 64;
  if (expert_tok[e * CAP + s0] < 0) return;

  __shared__ ushort Xs[64][72];
  __shared__ ushort Ws[256][72];
  __shared__ ushort Act[64][264];
  __shared__ int   toks[64];
  __shared__ float gts[64];

  const int tid = threadIdx.x;
  const int lane = tid & 63;
  const int wid = tid >> 6;
  const int rl = lane & 15;
  const int ko = (lane >> 4) * 8;
  const int rquad = (lane >> 4) * 4;

  if (tid < 64) {
    int t = expert_tok[e * CAP + s0 + tid];
    toks[tid] = t;
    gts[tid] = (t >= 0) ? expert_gate[e * CAP + s0 + tid] : 0.f;
  }
  __syncthreads();

  float4 px[4], pw[16];

  auto loadX = [&](int kb) {
    #pragma unroll
    for (int it = 0; it < 4; ++it) {
      int idx = tid + it * 256;
      int row = idx >> 4, c4 = (idx & 15) << 2;
      int t = toks[row];
      px[it] = (t >= 0) ? *(const float4*)(x + (size_t)t * D_DIM + kb * 64 + c4)
                        : make_float4(0.f, 0.f, 0.f, 0.f);
    }
  };
  auto writeX = [&]() {
    #pragma unroll
    for (int it = 0; it < 4; ++it) {
      int idx = tid + it * 256;
      int row = idx >> 4, c4 = (idx & 15) << 2;
      ushort4 h; h.x = f2bf(px[it].x); h.y = f2bf(px[it].y);
      h.z = f2bf(px[it].z); h.w = f2bf(px[it].w);
      *(ushort4*)&Xs[row][c4] = h;
    }
  };
  auto loadW = [&](const float* src, int ldk, int kb) {
    #pragma unroll
    for (int it = 0; it < 16; ++it) {
      int idx = tid + it * 256;
      int row = idx >> 4, c4 = (idx & 15) << 2;
      pw[it] = *(const float4*)(src + (size_t)row * ldk + kb * 64 + c4);
    }
  };
  auto writeW = [&]() {
    #pragma unroll
    for (int it = 0; it < 16; ++it) {
      int idx = tid + it * 256;
      int row = idx >> 4, c4 = (idx & 15) << 2;
      ushort4 h; h.x = f2bf(pw[it].x); h.y = f2bf(pw[it].y);
      h.z = f2bf(pw[it].z); h.w = f2bf(pw[it].w);
      *(ushort4*)&Ws[row][c4] = h;
    }
  };
  auto compute = [&](const ushort* Ab, int lda, f32x4 (&acc)[4][4]) {
    #pragma unroll
    for (int kk = 0; kk < 2; ++kk) {
      bf16x8 a[4], b[4];
      #pragma unroll
      for (int ri = 0; ri < 4; ++ri)
        a[ri] = *(const bf16x8*)(Ab + (size_t)(ri * 16 + rl) * lda + kk * 32 + ko);
      #pragma unroll
      for (int bi = 0; bi < 4; ++bi)
        b[bi] = *(const bf16x8*)(&Ws[wid * 64 + bi * 16 + rl][kk * 32 + ko]);
      #pragma unroll
      for (int ri = 0; ri < 4; ++ri)
        #pragma unroll
        for (int bi = 0; bi < 4; ++bi)
          acc[ri][bi] = __builtin_amdgcn_mfma_f32_16x16x32_bf16(a[ri], b[bi], acc[ri][bi], 0, 0, 0);
    }
  };

  const f32x4 fzero = {0.f, 0.f, 0.f, 0.f};

  #pragma unroll 1
  for (int which = 0; which < 2; ++which) {
    const float* wsrc = (which == 0 ? wg_ : wu_) + (size_t)e * F_DIM * D_DIM;
    f32x4 acc[4][4];
    #pragma unroll
    for (int ri = 0; ri < 4; ++ri)
      #pragma unroll
      for (int bi = 0; bi < 4; ++bi) acc[ri][bi] = fzero;

    loadX(0); loadW(wsrc, D_DIM, 0);
    writeX(); writeW();
    __syncthreads();
    for (int kb = 0; kb < 8; ++kb) {
      if (kb < 7) { loadX(kb + 1); loadW(wsrc, D_DIM, kb + 1); }
      compute(&Xs[0][0], 72, acc);
      __syncthreads();
      if (kb < 7) { writeX(); writeW(); __syncthreads(); }
    }
    #pragma unroll
    for (int ri = 0; ri < 4; ++ri)
      #pragma unroll
      for (int bi = 0; bi < 4; ++bi)
        #pragma unroll
        for (int j = 0; j < 4; ++j) {
          int r = ri * 16 + rquad + j;
          int c = wid * 64 + bi * 16 + rl;
          if (which == 0) {
            Act[r][c] = f2bf(acc[ri][bi][j]);
          } else {
            float hg = bf2f(Act[r][c]);
            float a = hg / (1.f + __expf(-hg)) * acc[ri][bi][j];
            Act[r][c] = f2bf(a);
          }
        }
    __syncthreads();
  }

  #pragma unroll 1
  for (int np = 0; np < 2; ++np) {
    const float* wsrc = wd_ + ((size_t)e * D_DIM + np * 256) * F_DIM;
    f32x4 acc[4][4];
    #pragma unroll
    for (int ri = 0; ri < 4; ++ri)
      #pragma unroll
      for (int bi = 0; bi < 4; ++bi) acc[ri][bi] = fzero;

    loadW(wsrc, F_DIM, 0); writeW();
    __syncthreads();
    for (int kb = 0; kb < 4; ++kb) {
      if (kb < 3) loadW(wsrc, F_DIM, kb + 1);
      compute(&Act[0][kb * 64], 264, acc);
      __syncthreads();
      if (kb < 3) { writeW(); __syncthreads(); }
    }
    #pragma unroll
    for (int ri = 0; ri < 4; ++ri)
      #pragma unroll
      for (int bi = 0; bi < 4; ++bi)
        #pragma unroll
        for (int j = 0; j < 4; ++j) {
          int r = ri * 16 + rquad + j;
          int t = toks[r];
          if (t >= 0) {
            int c = np * 256 + wid * 64 + bi * 16 + rl;
            atomicAdd(out + (size_t)t * D_DIM + c, gts[r] * acc[ri][bi][j]);
          }
        }
  }
}

__global__ void __launch_bounds__(256, 2) shared_ffn_mfma(
    const float* __restrict__ x, const float* __restrict__ swg,
    const float* __restrict__ swu, const float* __restrict__ swd,
    float* __restrict__ out) {
  const int row0 = blockIdx.x * 32;

  __shared__ ushort Xs[32][72];
  __shared__ ushort Ws[256][72];
  __shared__ ushort Act[32][264];

  const int tid = threadIdx.x;
  const int lane = tid & 63;
  const int wid = tid >> 6;
  const int rl = lane & 15;
  const int ko = (lane >> 4) * 8;
  const int rquad = (lane >> 4) * 4;

  float4 px[2], pw[16];

  auto loadX = [&](int kb) {
    #pragma unroll
    for (int it = 0; it < 2; ++it) {
      int idx = tid + it * 256;
      int row = idx >> 4, c4 = (idx & 15) << 2;
      px[it] = *(const float4*)(x + (size_t)(row0 + row) * D_DIM + kb * 64 + c4);
    }
  };
  auto writeX = [&]() {
    #pragma unroll
    for (int it = 0; it < 2; ++it) {
      int idx = tid + it * 256;
      int row = idx >> 4, c4 = (idx & 15) << 2;
      ushort4 h; h.x = f2bf(px[it].x); h.y = f2bf(px[it].y);
      h.z = f2bf(px[it].z); h.w = f2bf(px[it].w);
      *(ushort4*)&Xs[row][c4] = h;
    }
  };
  auto loadW = [&](const float* src, int ldk, int kb) {
    #pragma unroll
    for (int it = 0; it < 16; ++it) {
      int idx = tid + it * 256;
      int row = idx >> 4, c4 = (idx & 15) << 2;
      pw[it] = *(const float4*)(src + (size_t)row * ldk + kb * 64 + c4);
    }
  };
  auto writeW = [&]() {
    #pragma unroll
    for (int it = 0; it < 16; ++it) {
      int idx = tid + it * 256;
      int row = idx >> 4, c4 = (idx & 15) << 2;
      ushort4 h; h.x = f2bf(pw[it].x); h.y = f2bf(pw[it].y);
      h.z = f2bf(pw[it].z); h.w = f2bf(pw[it].w);
      *(ushort4*)&Ws[row][c4] = h;
    }
  };
  auto compute = [&](const ushort* Ab, int lda, f32x4 (&acc)[2][4]) {
    #pragma unroll
    for (int kk = 0; kk < 2; ++kk) {
      bf16x8 a[2], b[4];
      #pragma unroll
      for (int ri = 0; ri < 2; ++ri)
        a[ri] = *(const bf16x8*)(Ab + (size_t)(ri * 16 + rl) * lda + kk * 32 + ko);
      #pragma unroll
      for (int bi = 0; bi < 4; ++bi)
        b[bi] = *(const bf16x8*)(&Ws[wid * 64 + bi * 16 + rl][kk * 32 + ko]);
      #pragma unroll
      for (int ri = 0; ri < 2; ++ri)
        #pragma unroll
        for (int bi = 0; bi < 4; ++bi)
          acc[ri][bi] = __builtin_amdgcn_mfma_f32_16x16x32_bf16(a[ri], b[bi], acc[ri][bi], 0, 0, 0);
    }
  };

  const f32x4 fzero = {0.f, 0.f, 0.f, 0.f};
  f32x4 accd[2][2][4];
  #pragma unroll
  for (int np = 0; np < 2; ++np)
    #pragma unroll
    for (int ri = 0; ri < 2; ++ri)
      #pragma unroll
      for (int bi = 0; bi < 4; ++bi) accd[np][ri][bi] = fzero;

  #pragma unroll 1
  for (int sh = 0; sh < SH_NUM; ++sh) {
    #pragma unroll 1
    for (int which = 0; which < 2; ++which) {
      const float* wsrc = (which == 0 ? swg : swu) + (size_t)sh * F_DIM * D_DIM;
      f32x4 acc[2][4];
      #pragma unroll
      for (int ri = 0; ri < 2; ++ri)
        #pragma unroll
        for (int bi = 0; bi < 4; ++bi) acc[ri][bi] = fzero;

      loadX(0); loadW(wsrc, D_DIM, 0);
      writeX(); writeW();
      __syncthreads();
      for (int kb = 0; kb < 8; ++kb) {
        if (kb < 7) { loadX(kb + 1); loadW(wsrc, D_DIM, kb + 1); }
        compute(&Xs[0][0], 72, acc);
        __syncthreads();
        if (kb < 7) { writeX(); writeW(); __syncthreads(); }
      }
      #pragma unroll
      for (int ri = 0; ri < 2; ++ri)
        #pragma unroll
        for (int bi = 0; bi < 4; ++bi)
          #pragma unroll
          for (int j = 0; j < 4; ++j) {
            int r = ri * 16 + rquad + j;
            int c = wid * 64 + bi * 16 + rl;
            if (which == 0) {
              Act[r][c] = f2bf(acc[ri][bi][j]);
            } else {
              float hg = bf2f(Act[r][c]);
              float a = hg / (1.f + __expf(-hg)) * acc[ri][bi][j];
              Act[r][c] = f2bf(a);
            }
          }
      __syncthreads();
    }
    #pragma unroll
    for (int np = 0; np < 2; ++np) {
      const float* wsrc = swd + ((size_t)sh * D_DIM + np * 256) * F_DIM;
      loadW(wsrc, F_DIM, 0); writeW();
      __syncthreads();
      for (int kb = 0; kb < 4; ++kb) {
        if (kb < 3) loadW(wsrc, F_DIM, kb + 1);
        compute(&Act[0][kb * 64], 264, accd[np]);
        __syncthreads();
        if (kb < 3) { writeW(); __syncthreads(); }
      }
    }
  }

  #pragma unroll
  for (int np = 0; np < 2; ++np)
    #pragma unroll
    for (int ri = 0; ri < 2; ++ri)
      #pragma unroll
      for (int bi = 0; bi < 4; ++bi)
        #pragma unroll
        for (int j = 0; j < 4; ++j) {
          int r = ri * 16 + rquad + j;
          int c = np * 256 + wid * 64 + bi * 16 + rl;
          out[(size_t)(row0 + r) * D_DIM + c] = 0.5f * accd[np][ri][bi][j];
        }
}

extern "C" void kernel_launch(void* const* d_in, const int* in_sizes, int n_in,
                              void* d_out, int out_size, void* d_ws, size_t ws_size,
                              hipStream_t stream) {
  const float* x    = (const float*)d_in[0];
  const float* rw   = (const float*)d_in[1];
  const float* bias = (const float*)d_in[2];
  const float* swg  = (const float*)d_in[3];
  const float* swu  = (const float*)d_in[4];
  const float* swd  = (const float*)d_in[5];
  const float* wg   = (const float*)d_in[6];
  const float* wu   = (const float*)d_in[7];
  const float* wd   = (const float*)d_in[8];
  float* out = (float*)d_out;

  const size_t need = X_BF_BYTES + WT_BYTES + 2 * (size_t)M_ENT * 4 +
                      2 * (size_t)NCHUNK * E_NUM * 4 + 2 * (size_t)TOK_TOTAL * 4;

  if (ws_size >= need) {
    char* ws = (char*)d_ws;
    ushort* x_bf     = (ushort*)ws; ws += X_BF_BYTES;
    ushort* Wt       = (ushort*)ws; ws += WT_BYTES;
    int*   topk_i    = (int*)ws;    ws += (size_t)M_ENT * 4;
    float* topk_p    = (float*)ws;  ws += (size_t)M_ENT * 4;
    int*   chunk_hist= (int*)ws;    ws += (size_t)NCHUNK * E_NUM * 4;
    int*   chunk_base= (int*)ws;    ws += (size_t)NCHUNK * E_NUM * 4;
    int*   tok_all   = (int*)ws;    ws += (size_t)TOK_TOTAL * 4;
    float* gate_all  = (float*)ws;  ws += (size_t)TOK_TOTAL * 4;

    convert_x<<<2048, 256, 0, stream>>>(x, x_bf);
    convert_w<<<E_TOT * 48, 256, 0, stream>>>(wg, wu, wd, swg, swu, swd, Wt);
    router_topk<<<N_TOK / 4, 256, 0, stream>>>(x, rw, bias, topk_i, topk_p);
    hipMemsetAsync(tok_all, 0xFF, (size_t)TOK_ROUTED * 4, stream);
    hipMemsetAsync(out, 0, (size_t)out_size * 4, stream);
    hist_kernel<<<NCHUNK, 256, 0, stream>>>(topk_i, chunk_hist);
    scan_kernel<<<1, 64, 0, stream>>>(chunk_hist, chunk_base);
    dispatch_kernel<<<NCHUNK, 256, 0, stream>>>(topk_i, topk_p, chunk_base, tok_all, gate_all);
    init_shared_tok<<<64, 256, 0, stream>>>(tok_all, gate_all);
    ffn_mfma<<<2 * (N_TOK / 64) + (CAP / 64) * E_NUM, 512, 0, stream>>>(
        x_bf, Wt, tok_all, gate_all, out);
  } else {
    char* ws = (char*)d_ws;
    int*   topk_i      = (int*)ws;   ws += (size_t)M_ENT * 4;
    float* topk_p      = (float*)ws; ws += (size_t)M_ENT * 4;
    int*   chunk_hist  = (int*)ws;   ws += (size_t)NCHUNK * E_NUM * 4;
    int*   chunk_base  = (int*)ws;   ws += (size_t)NCHUNK * E_NUM * 4;
    int*   expert_tok  = (int*)ws;   ws += (size_t)E_NUM * CAP * 4;
    float* expert_gate = (float*)ws; ws += (size_t)E_NUM * CAP * 4;

    router_topk<<<N_TOK / 4, 256, 0, stream>>>(x, rw, bias, topk_i, topk_p);
    hipMemsetAsync(expert_tok, 0xFF, (size_t)E_NUM * CAP * 4, stream);
    hist_kernel<<<NCHUNK, 256, 0, stream>>>(topk_i, chunk_hist);
    scan_kernel<<<1, 64, 0, stream>>>(chunk_hist, chunk_base);
    dispatch_kernel<<<NCHUNK, 256, 0, stream>>>(topk_i, topk_p, chunk_base, expert_tok, expert_gate);
    shared_ffn_mfma<<<N_TOK / 32, 256, 0, stream>>>(x, swg, swu, swd, out);
    expert_ffn_mfma<<<(CAP / 64) * E_NUM, 256, 0, stream>>>(x, wg, wu, wd, expert_tok, expert_gate, out);
  }
}

// Round 5
// 368.356 us; speedup vs baseline: 5.5267x; 1.1103x over previous
//
#include <hip/hip_runtime.h>
#include <hip/hip_bf16.h>
#include <math.h>

#define N_TOK 8192
#define D_DIM 512
#define F_DIM 256
#define E_NUM 64
#define SH_NUM 2
#define K_TOP 6
#define CAP   1536
#define M_ENT (N_TOK * K_TOP)   // 49152
#define NCHUNK (M_ENT / 256)    // 192

// fast-path workspace geometry (element = ushort/bf16 unless noted)
#define EW_STRIDE 393216            // shorts per expert blob (48 chunks x 8192)
#define E_TOT (E_NUM + SH_NUM)      // 66
#define X_BF_BYTES   (8388608ull)                    // 8192*512*2
#define WT_BYTES     ((size_t)E_TOT * EW_STRIDE * 2) // 51,904,512
#define TOK_ROUTED   (E_NUM * CAP)                   // 98304 entries
#define TOK_TOTAL    (TOK_ROUTED + SH_NUM * N_TOK)   // +16384
#define EO_BYTES     ((size_t)TOK_TOTAL * D_DIM * 2) // 117,440,512

#define SLOT 18432                  // shorts per ring slot (X 2048 | Wg 8192 | Wu 8192)

typedef __attribute__((ext_vector_type(8))) short bf16x8;
typedef __attribute__((ext_vector_type(8))) short short8;
typedef __attribute__((ext_vector_type(4))) float f32x4;

#define VMCNT(n) asm volatile("s_waitcnt vmcnt(" #n ")" ::: "memory")

__device__ __forceinline__ ushort f2bf(float f) {
  union { float f; unsigned u; } c; c.f = f;
  return (ushort)((c.u + 0x7FFFu + ((c.u >> 16) & 1u)) >> 16);
}
__device__ __forceinline__ float bf2f(ushort h) {
  union { unsigned u; float f; } c; c.u = ((unsigned)h) << 16;
  return c.f;
}
__device__ __forceinline__ void gload16(const void* g, void* l) {
  __builtin_amdgcn_global_load_lds(
      (const __attribute__((address_space(1))) void*)g,
      (__attribute__((address_space(3))) void*)l, 16, 0, 0);
}

// ---------------- Router + softmax + top-6 (one wave per token) ----------------
__global__ void router_topk(const float* __restrict__ x, const float* __restrict__ rw,
                            const float* __restrict__ bias, int* __restrict__ topk_i,
                            float* __restrict__ topk_p) {
  const int wave = threadIdx.x >> 6;
  const int lane = threadIdx.x & 63;      // lane == expert id (E=64)
  const int n = blockIdx.x * 4 + wave;
  if (n >= N_TOK) return;

  const float4* xr = (const float4*)(x + (size_t)n * D_DIM);
  const float4* wr = (const float4*)(rw + (size_t)lane * D_DIM);
  float acc = 0.f;
  #pragma unroll 4
  for (int d4 = 0; d4 < D_DIM / 4; ++d4) {
    float4 xv = xr[d4]; float4 wv = wr[d4];
    acc += xv.x * wv.x + xv.y * wv.y + xv.z * wv.z + xv.w * wv.w;
  }
  float logit = acc + bias[lane];

  float m = logit;
  for (int off = 32; off > 0; off >>= 1) m = fmaxf(m, __shfl_xor(m, off));
  float p = expf(logit - m);
  float s = p;
  for (int off = 32; off > 0; off >>= 1) s += __shfl_xor(s, off);
  float prob = p / s;

  float myp = prob;
  float gsum = 0.f;
  float myg = 0.f; int myi = -1;
  for (int k = 0; k < K_TOP; ++k) {
    float bp = myp; int bi = lane;
    for (int off = 32; off > 0; off >>= 1) {
      float op = __shfl_xor(bp, off); int oi = __shfl_xor(bi, off);
      if (op > bp || (op == bp && oi < bi)) { bp = op; bi = oi; }
    }
    gsum += bp;
    if (lane == k) { myg = bp; myi = bi; }
    if (lane == bi) myp = -1.f;
  }
  if (lane < K_TOP) {
    topk_i[n * K_TOP + lane] = myi;
    topk_p[n * K_TOP + lane] = myg / (gsum + 1e-9f);
  }
}

// ---------------- per-chunk expert histogram ----------------
__global__ void hist_kernel(const int* __restrict__ topk_i, int* __restrict__ chunk_hist) {
  __shared__ int h[E_NUM];
  const int tid = threadIdx.x;
  if (tid < E_NUM) h[tid] = 0;
  __syncthreads();
  int e = topk_i[blockIdx.x * 256 + tid];
  atomicAdd(&h[e], 1);
  __syncthreads();
  if (tid < E_NUM) chunk_hist[blockIdx.x * E_NUM + tid] = h[tid];
}

// ---------------- exclusive scan over chunks, per expert ----------------
__global__ void scan_kernel(const int* __restrict__ chunk_hist, int* __restrict__ chunk_base) {
  const int e = threadIdx.x;  // 64 threads
  int run = 0;
  for (int c = 0; c < NCHUNK; ++c) {
    chunk_base[c * E_NUM + e] = run;
    run += chunk_hist[c * E_NUM + e];
  }
}

// ---------------- dispatch: slot = global stable rank within expert ----------------
__global__ void dispatch_kernel(const int* __restrict__ topk_i, const float* __restrict__ topk_p,
                                const int* __restrict__ chunk_base,
                                int* __restrict__ expert_tok, float* __restrict__ expert_gate,
                                int* __restrict__ entry_row) {
  __shared__ int eid[256];
  const int tid = threadIdx.x;
  const int m = blockIdx.x * 256 + tid;
  const int e = topk_i[m];
  eid[tid] = e;
  __syncthreads();
  int rank = 0;
  for (int t = 0; t < tid; ++t) rank += (eid[t] == e);
  int slot = chunk_base[blockIdx.x * E_NUM + e] + rank;
  int row = -1;
  if (slot < CAP) {
    expert_tok[e * CAP + slot] = m / K_TOP;
    expert_gate[e * CAP + slot] = topk_p[m];
    row = e * CAP + slot;
  }
  if (entry_row) entry_row[m] = row;
}

// ================= FAST PATH =================

// x fp32 -> bf16 row-major
__global__ void convert_x(const float* __restrict__ x, ushort* __restrict__ xb) {
  size_t idx = (size_t)blockIdx.x * 256 + threadIdx.x;
  const float4* s4 = (const float4*)(x + idx * 8);
  float4 v0 = s4[0], v1 = s4[1];
  short8 o;
  o[0] = f2bf(v0.x); o[1] = f2bf(v0.y); o[2] = f2bf(v0.z); o[3] = f2bf(v0.w);
  o[4] = f2bf(v1.x); o[5] = f2bf(v1.y); o[6] = f2bf(v1.z); o[7] = f2bf(v1.w);
  *(short8*)(xb + idx * 8) = o;
}

// weights fp32 -> bf16, pre-tiled fragment layout; fully-coalesced reads.
// blockIdx.x = e*12 + p*4 + rb  (p: 0 gate / 1 up / 2 down; rb = quarter of the matrix)
__global__ void convert_w(const float* __restrict__ wg_, const float* __restrict__ wu_,
                          const float* __restrict__ wd_, const float* __restrict__ swg,
                          const float* __restrict__ swu, const float* __restrict__ swd,
                          ushort* __restrict__ Wt) {
  int e = blockIdx.x / 12;
  int rem = blockIdx.x - e * 12;
  int p = rem >> 2, rb = rem & 3;
  const float* src;
  if (p == 0)      src = (e < E_NUM) ? wg_ + (size_t)e * 131072 : swg + (size_t)(e - E_NUM) * 131072;
  else if (p == 1) src = (e < E_NUM) ? wu_ + (size_t)e * 131072 : swu + (size_t)(e - E_NUM) * 131072;
  else             src = (e < E_NUM) ? wd_ + (size_t)e * 131072 : swd + (size_t)(e - E_NUM) * 131072;
  src += (size_t)rb * 32768;
  ushort* dst = Wt + (size_t)e * EW_STRIDE + (size_t)p * 131072;
  #pragma unroll
  for (int i = 0; i < 16; ++i) {
    int g = threadIdx.x + i * 256;              // 8-float group, contiguous reads
    const float4* s4 = (const float4*)(src + (size_t)g * 8);
    float4 v0 = s4[0], v1 = s4[1];
    short8 o;
    o[0] = f2bf(v0.x); o[1] = f2bf(v0.y); o[2] = f2bf(v0.z); o[3] = f2bf(v0.w);
    o[4] = f2bf(v1.x); o[5] = f2bf(v1.y); o[6] = f2bf(v1.z); o[7] = f2bf(v1.w);
    size_t L = (size_t)rb * 32768 + (size_t)g * 8;   // linear offset in 131072-float matrix
    size_t d;
    if (p < 2) {
      int n = (int)(L >> 9);          // row (F index), ld = 512
      int k = (int)(L & 511);
      int ci = k >> 5;
      int k8 = (k >> 3) & 3;
      d = (size_t)ci * 8192 + (size_t)(n >> 4) * 512 + k8 * 128 + (n & 15) * 8;
    } else {
      int rd = (int)(L >> 8);         // source row (D index), ld = 256
      int np = rd >> 8;               // 0/1 (which 256-col half of the down output)
      int n  = rd & 255;
      int col = (int)(L & 255);
      int kc = col >> 5;
      int k8 = (col >> 3) & 3;
      int ci = np * 8 + kc;
      d = (size_t)ci * 8192 + (size_t)(n >> 4) * 512 + k8 * 128 + (n & 15) * 8;
    }
    *(short8*)(dst + d) = o;
  }
}

// fill token lists for the two shared experts: every token, gate = 0.5
__global__ void init_shared_tok(int* __restrict__ tok_all, float* __restrict__ gate_all) {
  int i = blockIdx.x * 256 + threadIdx.x;
  tok_all[TOK_ROUTED + i] = i & (N_TOK - 1);
  gate_all[TOK_ROUTED + i] = 0.5f;
}

// Unified FFN: 64-token tile x one expert, 512 threads (8 waves, 2 row x 4 col),
// fused gate+up, 3-slot ring with counted vmcnt.
// GATHER=true: epilogue = plain bf16 stores of raw expert output into expert_out.
// GATHER=false: epilogue = gated fp32 atomicAdd into out (fallback).
template <bool GATHER>
__global__ void __launch_bounds__(512, 1) ffn_mfma(
    const ushort* __restrict__ xb, const ushort* __restrict__ Wt,
    const int* __restrict__ tok_all, const float* __restrict__ gate_all,
    float* __restrict__ out, ushort* __restrict__ expert_out) {
  int e, tbase;
  if (blockIdx.x < 2 * (N_TOK / 64)) {          // shared tiles first (always full)
    int sid = blockIdx.x;
    int sh = sid & 1, mt = sid >> 1;
    e = E_NUM + sh;
    tbase = TOK_ROUTED + sh * N_TOK + mt * 64;
  } else {
    int rb = blockIdx.x - 2 * (N_TOK / 64);
    e = rb & (E_NUM - 1);
    int mt = rb >> 6;
    tbase = e * CAP + mt * 64;
    if (tok_all[tbase] < 0) return;             // contiguous fill -> empty tile
  }
  const ushort* wbase = Wt + (size_t)e * EW_STRIDE;

  __shared__ ushort RING[3 * SLOT];   // 108 KB: per slot X[2048] Wg[8192] Wu[8192]
  __shared__ ushort Act[16384];       // 32 KB: 64tok x 256f, fragment-tiled
  __shared__ int   toks[64];
  __shared__ float gts[64];

  const int tid = threadIdx.x;
  const int lane = tid & 63;
  const int wid = tid >> 6;        // 0..7
  const int wr = wid >> 2;         // 0..1  (row half: 32 tokens)
  const int wc = wid & 3;          // 0..3  (col quarter)
  const int rl = lane & 15;
  const int hi = lane >> 4;

  if (tid < 64) {
    int t = tok_all[tbase + tid];
    toks[tid] = t;
    gts[tid] = (t >= 0) ? gate_all[tbase + tid] : 0.f;
  }
  __syncthreads();

  // waves 0-3 stage the X tile (subtile = wid): per-lane source row
  int stok = 0;
  if (wid < 4) { int t = toks[wid * 16 + rl]; stok = (t < 0) ? 0 : t; }
  const ushort* xsrc = xb + (size_t)stok * D_DIM + hi * 8;

  auto stage_gu = [&](int sl, int kc) {
    ushort* dst = RING + sl * SLOT;
    if (wid < 4)
      gload16(xsrc + kc * 32, dst + wid * 512);
    #pragma unroll
    for (int i = 0; i < 2; ++i) {
      int s = wid * 2 + i;
      gload16(wbase + kc * 8192 + s * 512 + lane * 8, dst + 2048 + s * 512);
      gload16(wbase + 131072 + kc * 8192 + s * 512 + lane * 8, dst + 10240 + s * 512);
    }
  };
  auto stage_dn = [&](int sl, int kc) {
    ushort* dst = RING + sl * SLOT;
    #pragma unroll
    for (int i = 0; i < 4; ++i) {
      int s = wid * 4 + i;
      gload16(wbase + 262144 + (s >> 4) * 65536 + kc * 8192 + (s & 15) * 512 + lane * 8,
              dst + s * 512);
    }
  };

  const f32x4 fzero = {0.f, 0.f, 0.f, 0.f};
  f32x4 accg[2][4], accu[2][4];
  #pragma unroll
  for (int ri = 0; ri < 2; ++ri)
    #pragma unroll
    for (int bi = 0; bi < 4; ++bi) { accg[ri][bi] = fzero; accu[ri][bi] = fzero; }

  // ---- fused gate+up: 16 K-steps of 32 ----
  stage_gu(0, 0); stage_gu(1, 1);
  {
    int sl_c = 0, sl_n = 2;
    #pragma unroll 1
    for (int kc = 0; kc < 16; ++kc) {
      if (kc < 14) { stage_gu(sl_n, kc + 2); sl_n = (sl_n == 2) ? 0 : sl_n + 1; }
      if (kc < 14)      { if (wid < 4) VMCNT(10); else VMCNT(8); }
      else if (kc == 14){ if (wid < 4) VMCNT(5);  else VMCNT(4); }
      else              VMCNT(0);
      __builtin_amdgcn_s_barrier();
      __builtin_amdgcn_sched_barrier(0);
      {
        const ushort* base = RING + sl_c * SLOT;
        bf16x8 a[2], bg[4], bu[4];
        #pragma unroll
        for (int ri = 0; ri < 2; ++ri)
          a[ri] = *(const bf16x8*)(base + (wr * 2 + ri) * 512 + lane * 8);
        #pragma unroll
        for (int bi = 0; bi < 4; ++bi) {
          bg[bi] = *(const bf16x8*)(base + 2048 + (wc * 4 + bi) * 512 + lane * 8);
          bu[bi] = *(const bf16x8*)(base + 10240 + (wc * 4 + bi) * 512 + lane * 8);
        }
        __builtin_amdgcn_s_setprio(1);
        #pragma unroll
        for (int ri = 0; ri < 2; ++ri)
          #pragma unroll
          for (int bi = 0; bi < 4; ++bi) {
            accg[ri][bi] = __builtin_amdgcn_mfma_f32_16x16x32_bf16(a[ri], bg[bi], accg[ri][bi], 0, 0, 0);
            accu[ri][bi] = __builtin_amdgcn_mfma_f32_16x16x32_bf16(a[ri], bu[bi], accu[ri][bi], 0, 0, 0);
          }
        __builtin_amdgcn_s_setprio(0);
      }
      sl_c = (sl_c == 2) ? 0 : sl_c + 1;
      __builtin_amdgcn_s_barrier();
    }
  }

  // ---- silu(g)*u in-register -> Act (fragment-tiled bf16) ----
  #pragma unroll
  for (int ri = 0; ri < 2; ++ri)
    #pragma unroll
    for (int bi = 0; bi < 4; ++bi) {
      int st = (wr * 2 + ri) * 8 + wc * 2 + (bi >> 1);
      int base = st * 512 + ((bi & 1) * 2 + (rl >> 3)) * 128 + (rl & 7);
      #pragma unroll
      for (int j = 0; j < 4; ++j) {
        float g = accg[ri][bi][j], u = accu[ri][bi][j];
        Act[base + (hi * 4 + j) * 8] = f2bf(g / (1.f + __expf(-g)) * u);
      }
    }

  // ---- down: out[64 x 512], 8 K-steps of 32 over F ----
  f32x4 accd[2][8];
  #pragma unroll
  for (int ri = 0; ri < 2; ++ri)
    #pragma unroll
    for (int bj = 0; bj < 8; ++bj) accd[ri][bj] = fzero;

  stage_dn(0, 0); stage_dn(1, 1);
  asm volatile("s_waitcnt lgkmcnt(0)" ::: "memory");
  __builtin_amdgcn_s_barrier();
  __builtin_amdgcn_sched_barrier(0);
  {
    int sl_c = 0, sl_n = 2;
    #pragma unroll 1
    for (int kc = 0; kc < 8; ++kc) {
      if (kc < 6) { stage_dn(sl_n, kc + 2); sl_n = (sl_n == 2) ? 0 : sl_n + 1; }
      if (kc < 6)       VMCNT(8);
      else if (kc == 6) VMCNT(4);
      else              VMCNT(0);
      __builtin_amdgcn_s_barrier();
      __builtin_amdgcn_sched_barrier(0);
      {
        const ushort* base = RING + sl_c * SLOT;
        bf16x8 a[2], b[8];
        #pragma unroll
        for (int ri = 0; ri < 2; ++ri)
          a[ri] = *(const bf16x8*)(Act + ((wr * 2 + ri) * 8 + kc) * 512 + lane * 8);
        #pragma unroll
        for (int bj = 0; bj < 8; ++bj)
          b[bj] = *(const bf16x8*)(base + (wc * 8 + bj) * 512 + lane * 8);
        __builtin_amdgcn_s_setprio(1);
        #pragma unroll
        for (int ri = 0; ri < 2; ++ri)
          #pragma unroll
          for (int bj = 0; bj < 8; ++bj)
            accd[ri][bj] = __builtin_amdgcn_mfma_f32_16x16x32_bf16(a[ri], b[bj], accd[ri][bj], 0, 0, 0);
        __builtin_amdgcn_s_setprio(0);
      }
      sl_c = (sl_c == 2) ? 0 : sl_c + 1;
      __builtin_amdgcn_s_barrier();
    }
  }

  // ---- epilogue ----
  if (GATHER) {
    // raw (un-gated) bf16 rows into expert_out; gather kernel applies gates.
    #pragma unroll
    for (int ri = 0; ri < 2; ++ri)
      #pragma unroll
      for (int j = 0; j < 4; ++j) {
        int r = wr * 32 + ri * 16 + hi * 4 + j;
        if (toks[r] < 0) continue;
        ushort* erow = expert_out + (size_t)(tbase + r) * D_DIM + wc * 128 + rl;
        #pragma unroll
        for (int bj = 0; bj < 8; ++bj)
          erow[bj * 16] = f2bf(accd[ri][bj][j]);
      }
  } else {
    #pragma unroll
    for (int ri = 0; ri < 2; ++ri)
      #pragma unroll
      for (int j = 0; j < 4; ++j) {
        int r = wr * 32 + ri * 16 + hi * 4 + j;
        int t = toks[r];
        if (t < 0) continue;
        float gt = gts[r];
        float* orow = out + (size_t)t * D_DIM + wc * 128 + rl;
        #pragma unroll
        for (int bj = 0; bj < 8; ++bj)
          atomicAdd(orow + bj * 16, gt * accd[ri][bj][j]);
      }
  }
}

// ---------------- gather combine: one wave per token ----------------
__global__ void __launch_bounds__(256) gather_out(
    const ushort* __restrict__ eo, const int* __restrict__ entry_row,
    const float* __restrict__ topk_p, float* __restrict__ out) {
  const int t = blockIdx.x * 4 + (threadIdx.x >> 6);
  const int lane = threadIdx.x & 63;
  const int base = t * K_TOP;

  float acc[8];
  #pragma unroll
  for (int j = 0; j < 8; ++j) acc[j] = 0.f;

  #pragma unroll
  for (int k = 0; k < K_TOP; ++k) {
    int row = entry_row[base + k];
    if (row >= 0) {
      float g = topk_p[base + k];
      bf16x8 v = *(const bf16x8*)(eo + (size_t)row * D_DIM + lane * 8);
      #pragma unroll
      for (int j = 0; j < 8; ++j) acc[j] += g * bf2f((ushort)v[j]);
    }
  }
  #pragma unroll
  for (int sh = 0; sh < SH_NUM; ++sh) {
    int row = TOK_ROUTED + sh * N_TOK + t;
    bf16x8 v = *(const bf16x8*)(eo + (size_t)row * D_DIM + lane * 8);
    #pragma unroll
    for (int j = 0; j < 8; ++j) acc[j] += 0.5f * bf2f((ushort)v[j]);
  }
  float4* o = (float4*)(out + (size_t)t * D_DIM + lane * 8);
  o[0] = make_float4(acc[0], acc[1], acc[2], acc[3]);
  o[1] = make_float4(acc[4], acc[5], acc[6], acc[7]);
}

// ================= LEGACY PATH (round-2, used when ws tiny) =================

__global__ void __launch_bounds__(256, 2) expert_ffn_mfma(
    const float* __restrict__ x, const float* __restrict__ wg_,
    const float* __restrict__ wu_, const float* __restrict__ wd_,
    const int* __restrict__ expert_tok, const float* __restrict__ expert_gate,
    float* __restrict__ out) {
  const int e = blockIdx.x & (E_NUM - 1);
  const int mt = blockIdx.x >> 6;
  const int s0 = mt * 64;
  if (expert_tok[e * CAP + s0] < 0) return;

  __shared__ ushort Xs[64][72];
  __shared__ ushort Ws[256][72];
  __shared__ ushort Act[64][264];
  __shared__ int   toks[64];
  __shared__ float gts[64];

  const int tid = threadIdx.x;
  const int lane = tid & 63;
  const int wid = tid >> 6;
  const int rl = lane & 15;
  const int ko = (lane >> 4) * 8;
  const int rquad = (lane >> 4) * 4;

  if (tid < 64) {
    int t = expert_tok[e * CAP + s0 + tid];
    toks[tid] = t;
    gts[tid] = (t >= 0) ? expert_gate[e * CAP + s0 + tid] : 0.f;
  }
  __syncthreads();

  float4 px[4], pw[16];

  auto loadX = [&](int kb) {
    #pragma unroll
    for (int it = 0; it < 4; ++it) {
      int idx = tid + it * 256;
      int row = idx >> 4, c4 = (idx & 15) << 2;
      int t = toks[row];
      px[it] = (t >= 0) ? *(const float4*)(x + (size_t)t * D_DIM + kb * 64 + c4)
                        : make_float4(0.f, 0.f, 0.f, 0.f);
    }
  };
  auto writeX = [&]() {
    #pragma unroll
    for (int it = 0; it < 4; ++it) {
      int idx = tid + it * 256;
      int row = idx >> 4, c4 = (idx & 15) << 2;
      ushort4 h; h.x = f2bf(px[it].x); h.y = f2bf(px[it].y);
      h.z = f2bf(px[it].z); h.w = f2bf(px[it].w);
      *(ushort4*)&Xs[row][c4] = h;
    }
  };
  auto loadW = [&](const float* src, int ldk, int kb) {
    #pragma unroll
    for (int it = 0; it < 16; ++it) {
      int idx = tid + it * 256;
      int row = idx >> 4, c4 = (idx & 15) << 2;
      pw[it] = *(const float4*)(src + (size_t)row * ldk + kb * 64 + c4);
    }
  };
  auto writeW = [&]() {
    #pragma unroll
    for (int it = 0; it < 16; ++it) {
      int idx = tid + it * 256;
      int row = idx >> 4, c4 = (idx & 15) << 2;
      ushort4 h; h.x = f2bf(pw[it].x); h.y = f2bf(pw[it].y);
      h.z = f2bf(pw[it].z); h.w = f2bf(pw[it].w);
      *(ushort4*)&Ws[row][c4] = h;
    }
  };
  auto compute = [&](const ushort* Ab, int lda, f32x4 (&acc)[4][4]) {
    #pragma unroll
    for (int kk = 0; kk < 2; ++kk) {
      bf16x8 a[4], b[4];
      #pragma unroll
      for (int ri = 0; ri < 4; ++ri)
        a[ri] = *(const bf16x8*)(Ab + (size_t)(ri * 16 + rl) * lda + kk * 32 + ko);
      #pragma unroll
      for (int bi = 0; bi < 4; ++bi)
        b[bi] = *(const bf16x8*)(&Ws[wid * 64 + bi * 16 + rl][kk * 32 + ko]);
      #pragma unroll
      for (int ri = 0; ri < 4; ++ri)
        #pragma unroll
        for (int bi = 0; bi < 4; ++bi)
          acc[ri][bi] = __builtin_amdgcn_mfma_f32_16x16x32_bf16(a[ri], b[bi], acc[ri][bi], 0, 0, 0);
    }
  };

  const f32x4 fzero = {0.f, 0.f, 0.f, 0.f};

  #pragma unroll 1
  for (int which = 0; which < 2; ++which) {
    const float* wsrc = (which == 0 ? wg_ : wu_) + (size_t)e * F_DIM * D_DIM;
    f32x4 acc[4][4];
    #pragma unroll
    for (int ri = 0; ri < 4; ++ri)
      #pragma unroll
      for (int bi = 0; bi < 4; ++bi) acc[ri][bi] = fzero;

    loadX(0); loadW(wsrc, D_DIM, 0);
    writeX(); writeW();
    __syncthreads();
    for (int kb = 0; kb < 8; ++kb) {
      if (kb < 7) { loadX(kb + 1); loadW(wsrc, D_DIM, kb + 1); }
      compute(&Xs[0][0], 72, acc);
      __syncthreads();
      if (kb < 7) { writeX(); writeW(); __syncthreads(); }
    }
    #pragma unroll
    for (int ri = 0; ri < 4; ++ri)
      #pragma unroll
      for (int bi = 0; bi < 4; ++bi)
        #pragma unroll
        for (int j = 0; j < 4; ++j) {
          int r = ri * 16 + rquad + j;
          int c = wid * 64 + bi * 16 + rl;
          if (which == 0) {
            Act[r][c] = f2bf(acc[ri][bi][j]);
          } else {
            float hg = bf2f(Act[r][c]);
            float a = hg / (1.f + __expf(-hg)) * acc[ri][bi][j];
            Act[r][c] = f2bf(a);
          }
        }
    __syncthreads();
  }

  #pragma unroll 1
  for (int np = 0; np < 2; ++np) {
    const float* wsrc = wd_ + ((size_t)e * D_DIM + np * 256) * F_DIM;
    f32x4 acc[4][4];
    #pragma unroll
    for (int ri = 0; ri < 4; ++ri)
      #pragma unroll
      for (int bi = 0; bi < 4; ++bi) acc[ri][bi] = fzero;

    loadW(wsrc, F_DIM, 0); writeW();
    __syncthreads();
    for (int kb = 0; kb < 4; ++kb) {
      if (kb < 3) loadW(wsrc, F_DIM, kb + 1);
      compute(&Act[0][kb * 64], 264, acc);
      __syncthreads();
      if (kb < 3) { writeW(); __syncthreads(); }
    }
    #pragma unroll
    for (int ri = 0; ri < 4; ++ri)
      #pragma unroll
      for (int bi = 0; bi < 4; ++bi)
        #pragma unroll
        for (int j = 0; j < 4; ++j) {
          int r = ri * 16 + rquad + j;
          int t = toks[r];
          if (t >= 0) {
            int c = np * 256 + wid * 64 + bi * 16 + rl;
            atomicAdd(out + (size_t)t * D_DIM + c, gts[r] * acc[ri][bi][j]);
          }
        }
  }
}

__global__ void __launch_bounds__(256, 2) shared_ffn_mfma(
    const float* __restrict__ x, const float* __restrict__ swg,
    const float* __restrict__ swu, const float* __restrict__ swd,
    float* __restrict__ out) {
  const int row0 = blockIdx.x * 32;

  __shared__ ushort Xs[32][72];
  __shared__ ushort Ws[256][72];
  __shared__ ushort Act[32][264];

  const int tid = threadIdx.x;
  const int lane = tid & 63;
  const int wid = tid >> 6;
  const int rl = lane & 15;
  const int ko = (lane >> 4) * 8;
  const int rquad = (lane >> 4) * 4;

  float4 px[2], pw[16];

  auto loadX = [&](int kb) {
    #pragma unroll
    for (int it = 0; it < 2; ++it) {
      int idx = tid + it * 256;
      int row = idx >> 4, c4 = (idx & 15) << 2;
      px[it] = *(const float4*)(x + (size_t)(row0 + row) * D_DIM + kb * 64 + c4);
    }
  };
  auto writeX = [&]() {
    #pragma unroll
    for (int it = 0; it < 2; ++it) {
      int idx = tid + it * 256;
      int row = idx >> 4, c4 = (idx & 15) << 2;
      ushort4 h; h.x = f2bf(px[it].x); h.y = f2bf(px[it].y);
      h.z = f2bf(px[it].z); h.w = f2bf(px[it].w);
      *(ushort4*)&Xs[row][c4] = h;
    }
  };
  auto loadW = [&](const float* src, int ldk, int kb) {
    #pragma unroll
    for (int it = 0; it < 16; ++it) {
      int idx = tid + it * 256;
      int row = idx >> 4, c4 = (idx & 15) << 2;
      pw[it] = *(const float4*)(src + (size_t)row * ldk + kb * 64 + c4);
    }
  };
  auto writeW = [&]() {
    #pragma unroll
    for (int it = 0; it < 16; ++it) {
      int idx = tid + it * 256;
      int row = idx >> 4, c4 = (idx & 15) << 2;
      ushort4 h; h.x = f2bf(pw[it].x); h.y = f2bf(pw[it].y);
      h.z = f2bf(pw[it].z); h.w = f2bf(pw[it].w);
      *(ushort4*)&Ws[row][c4] = h;
    }
  };
  auto compute = [&](const ushort* Ab, int lda, f32x4 (&acc)[2][4]) {
    #pragma unroll
    for (int kk = 0; kk < 2; ++kk) {
      bf16x8 a[2], b[4];
      #pragma unroll
      for (int ri = 0; ri < 2; ++ri)
        a[ri] = *(const bf16x8*)(Ab + (size_t)(ri * 16 + rl) * lda + kk * 32 + ko);
      #pragma unroll
      for (int bi = 0; bi < 4; ++bi)
        b[bi] = *(const bf16x8*)(&Ws[wid * 64 + bi * 16 + rl][kk * 32 + ko]);
      #pragma unroll
      for (int ri = 0; ri < 2; ++ri)
        #pragma unroll
        for (int bi = 0; bi < 4; ++bi)
          acc[ri][bi] = __builtin_amdgcn_mfma_f32_16x16x32_bf16(a[ri], b[bi], acc[ri][bi], 0, 0, 0);
    }
  };

  const f32x4 fzero = {0.f, 0.f, 0.f, 0.f};
  f32x4 accd[2][2][4];
  #pragma unroll
  for (int np = 0; np < 2; ++np)
    #pragma unroll
    for (int ri = 0; ri < 2; ++ri)
      #pragma unroll
      for (int bi = 0; bi < 4; ++bi) accd[np][ri][bi] = fzero;

  #pragma unroll 1
  for (int sh = 0; sh < SH_NUM; ++sh) {
    #pragma unroll 1
    for (int which = 0; which < 2; ++which) {
      const float* wsrc = (which == 0 ? swg : swu) + (size_t)sh * F_DIM * D_DIM;
      f32x4 acc[2][4];
      #pragma unroll
      for (int ri = 0; ri < 2; ++ri)
        #pragma unroll
        for (int bi = 0; bi < 4; ++bi) acc[ri][bi] = fzero;

      loadX(0); loadW(wsrc, D_DIM, 0);
      writeX(); writeW();
      __syncthreads();
      for (int kb = 0; kb < 8; ++kb) {
        if (kb < 7) { loadX(kb + 1); loadW(wsrc, D_DIM, kb + 1); }
        compute(&Xs[0][0], 72, acc);
        __syncthreads();
        if (kb < 7) { writeX(); writeW(); __syncthreads(); }
      }
      #pragma unroll
      for (int ri = 0; ri < 2; ++ri)
        #pragma unroll
        for (int bi = 0; bi < 4; ++bi)
          #pragma unroll
          for (int j = 0; j < 4; ++j) {
            int r = ri * 16 + rquad + j;
            int c = wid * 64 + bi * 16 + rl;
            if (which == 0) {
              Act[r][c] = f2bf(acc[ri][bi][j]);
            } else {
              float hg = bf2f(Act[r][c]);
              float a = hg / (1.f + __expf(-hg)) * acc[ri][bi][j];
              Act[r][c] = f2bf(a);
            }
          }
      __syncthreads();
    }
    #pragma unroll
    for (int np = 0; np < 2; ++np) {
      const float* wsrc = swd + ((size_t)sh * D_DIM + np * 256) * F_DIM;
      loadW(wsrc, F_DIM, 0); writeW();
      __syncthreads();
      for (int kb = 0; kb < 4; ++kb) {
        if (kb < 3) loadW(wsrc, F_DIM, kb + 1);
        compute(&Act[0][kb * 64], 264, accd[np]);
        __syncthreads();
        if (kb < 3) { writeW(); __syncthreads(); }
      }
    }
  }

  #pragma unroll
  for (int np = 0; np < 2; ++np)
    #pragma unroll
    for (int ri = 0; ri < 2; ++ri)
      #pragma unroll
      for (int bi = 0; bi < 4; ++bi)
        #pragma unroll
        for (int j = 0; j < 4; ++j) {
          int r = ri * 16 + rquad + j;
          int c = np * 256 + wid * 64 + bi * 16 + rl;
          out[(size_t)(row0 + r) * D_DIM + c] = 0.5f * accd[np][ri][bi][j];
        }
}

extern "C" void kernel_launch(void* const* d_in, const int* in_sizes, int n_in,
                              void* d_out, int out_size, void* d_ws, size_t ws_size,
                              hipStream_t stream) {
  const float* x    = (const float*)d_in[0];
  const float* rw   = (const float*)d_in[1];
  const float* bias = (const float*)d_in[2];
  const float* swg  = (const float*)d_in[3];
  const float* swu  = (const float*)d_in[4];
  const float* swd  = (const float*)d_in[5];
  const float* wg   = (const float*)d_in[6];
  const float* wu   = (const float*)d_in[7];
  const float* wd   = (const float*)d_in[8];
  float* out = (float*)d_out;

  const size_t small = 2 * (size_t)M_ENT * 4 + (size_t)M_ENT * 4 +
                       2 * (size_t)NCHUNK * E_NUM * 4 + 2 * (size_t)TOK_TOTAL * 4;
  const size_t need_mid = X_BF_BYTES + WT_BYTES + small;
  const size_t need_big = need_mid + EO_BYTES;

  if (ws_size >= need_mid) {
    const bool gather = (ws_size >= need_big);
    char* ws = (char*)d_ws;
    ushort* x_bf     = (ushort*)ws; ws += X_BF_BYTES;
    ushort* Wt       = (ushort*)ws; ws += WT_BYTES;
    int*   topk_i    = (int*)ws;    ws += (size_t)M_ENT * 4;
    float* topk_p    = (float*)ws;  ws += (size_t)M_ENT * 4;
    int*   entry_row = (int*)ws;    ws += (size_t)M_ENT * 4;
    int*   chunk_hist= (int*)ws;    ws += (size_t)NCHUNK * E_NUM * 4;
    int*   chunk_base= (int*)ws;    ws += (size_t)NCHUNK * E_NUM * 4;
    int*   tok_all   = (int*)ws;    ws += (size_t)TOK_TOTAL * 4;
    float* gate_all  = (float*)ws;  ws += (size_t)TOK_TOTAL * 4;
    ushort* eo       = (ushort*)ws; // only valid if gather

    convert_x<<<2048, 256, 0, stream>>>(x, x_bf);
    convert_w<<<E_TOT * 12, 256, 0, stream>>>(wg, wu, wd, swg, swu, swd, Wt);
    router_topk<<<N_TOK / 4, 256, 0, stream>>>(x, rw, bias, topk_i, topk_p);
    hipMemsetAsync(tok_all, 0xFF, (size_t)TOK_ROUTED * 4, stream);
    if (!gather) hipMemsetAsync(out, 0, (size_t)out_size * 4, stream);
    hist_kernel<<<NCHUNK, 256, 0, stream>>>(topk_i, chunk_hist);
    scan_kernel<<<1, 64, 0, stream>>>(chunk_hist, chunk_base);
    dispatch_kernel<<<NCHUNK, 256, 0, stream>>>(topk_i, topk_p, chunk_base, tok_all,
                                                gate_all, entry_row);
    init_shared_tok<<<64, 256, 0, stream>>>(tok_all, gate_all);
    const int nblk = 2 * (N_TOK / 64) + (CAP / 64) * E_NUM;
    if (gather) {
      ffn_mfma<true><<<nblk, 512, 0, stream>>>(x_bf, Wt, tok_all, gate_all, out, eo);
      gather_out<<<N_TOK / 4, 256, 0, stream>>>(eo, entry_row, topk_p, out);
    } else {
      ffn_mfma<false><<<nblk, 512, 0, stream>>>(x_bf, Wt, tok_all, gate_all, out, nullptr);
    }
  } else {
    char* ws = (char*)d_ws;
    int*   topk_i      = (int*)ws;   ws += (size_t)M_ENT * 4;
    float* topk_p      = (float*)ws; ws += (size_t)M_ENT * 4;
    int*   chunk_hist  = (int*)ws;   ws += (size_t)NCHUNK * E_NUM * 4;
    int*   chunk_base  = (int*)ws;   ws += (size_t)NCHUNK * E_NUM * 4;
    int*   expert_tok  = (int*)ws;   ws += (size_t)E_NUM * CAP * 4;
    float* expert_gate = (float*)ws; ws += (size_t)E_NUM * CAP * 4;

    router_topk<<<N_TOK / 4, 256, 0, stream>>>(x, rw, bias, topk_i, topk_p);
    hipMemsetAsync(expert_tok, 0xFF, (size_t)E_NUM * CAP * 4, stream);
    hist_kernel<<<NCHUNK, 256, 0, stream>>>(topk_i, chunk_hist);
    scan_kernel<<<1, 64, 0, stream>>>(chunk_hist, chunk_base);
    dispatch_kernel<<<NCHUNK, 256, 0, stream>>>(topk_i, topk_p, chunk_base, expert_tok,
                                                expert_gate, nullptr);
    shared_ffn_mfma<<<N_TOK / 32, 256, 0, stream>>>(x, swg, swu, swd, out);
    expert_ffn_mfma<<<(CAP / 64) * E_NUM, 256, 0, stream>>>(x, wg, wu, wd, expert_tok,
                                                            expert_gate, out);
  }
}

// Round 7
// 305.642 us; speedup vs baseline: 6.6607x; 1.2052x over previous
//
#include <hip/hip_runtime.h>
#include <hip/hip_bf16.h>
#include <math.h>

#define N_TOK 8192
#define D_DIM 512
#define F_DIM 256
#define E_NUM 64
#define SH_NUM 2
#define K_TOP 6
#define CAP   1536
#define M_ENT (N_TOK * K_TOP)   // 49152
#define NCHUNK (M_ENT / 256)    // 192

// fast-path workspace geometry (element = ushort/bf16 unless noted)
#define EW_STRIDE 393216            // shorts per expert blob (48 chunks x 8192)
#define E_TOT (E_NUM + SH_NUM)      // 66
#define X_BF_BYTES   (8388608ull)                    // 8192*512*2
#define WT_BYTES     ((size_t)E_TOT * EW_STRIDE * 2) // 51,904,512
#define TOK_ROUTED   (E_NUM * CAP)                   // 98304 entries
#define TOK_TOTAL    (TOK_ROUTED + SH_NUM * N_TOK)   // +16384
#define EO_BYTES     ((size_t)TOK_TOTAL * D_DIM * 2) // 117,440,512
#define RWT_BYTES    131072ull

#define SLOT 18432                  // shorts per ring slot (X 2048 | Wg 8192 | Wu 8192)

typedef __attribute__((ext_vector_type(8))) short bf16x8;
typedef __attribute__((ext_vector_type(8))) short short8;
typedef __attribute__((ext_vector_type(4))) float f32x4;

#define VMCNT(n) asm volatile("s_waitcnt vmcnt(" #n ")" ::: "memory")

__device__ __forceinline__ ushort f2bf(float f) {
  union { float f; unsigned u; } c; c.f = f;
  return (ushort)((c.u + 0x7FFFu + ((c.u >> 16) & 1u)) >> 16);
}
__device__ __forceinline__ float bf2f(ushort h) {
  union { unsigned u; float f; } c; c.u = ((unsigned)h) << 16;
  return c.f;
}
__device__ __forceinline__ void gload16(const void* g, void* l) {
  __builtin_amdgcn_global_load_lds(
      (const __attribute__((address_space(1))) void*)g,
      (__attribute__((address_space(3))) void*)l, 16, 0, 0);
}

// ---------------- legacy router (small-ws path) ----------------
__global__ void router_topk(const float* __restrict__ x, const float* __restrict__ rw,
                            const float* __restrict__ bias, int* __restrict__ topk_i,
                            float* __restrict__ topk_p) {
  const int wave = threadIdx.x >> 6;
  const int lane = threadIdx.x & 63;      // lane == expert id (E=64)
  const int n = blockIdx.x * 4 + wave;
  if (n >= N_TOK) return;

  const float4* xr = (const float4*)(x + (size_t)n * D_DIM);
  const float4* wr = (const float4*)(rw + (size_t)lane * D_DIM);
  float acc = 0.f;
  #pragma unroll 4
  for (int d4 = 0; d4 < D_DIM / 4; ++d4) {
    float4 xv = xr[d4]; float4 wv = wr[d4];
    acc += xv.x * wv.x + xv.y * wv.y + xv.z * wv.z + xv.w * wv.w;
  }
  float logit = acc + bias[lane];

  float m = logit;
  for (int off = 32; off > 0; off >>= 1) m = fmaxf(m, __shfl_xor(m, off));
  float p = expf(logit - m);
  float s = p;
  for (int off = 32; off > 0; off >>= 1) s += __shfl_xor(s, off);
  float prob = p / s;

  float myp = prob;
  float gsum = 0.f;
  float myg = 0.f; int myi = -1;
  for (int k = 0; k < K_TOP; ++k) {
    float bp = myp; int bi = lane;
    for (int off = 32; off > 0; off >>= 1) {
      float op = __shfl_xor(bp, off); int oi = __shfl_xor(bi, off);
      if (op > bp || (op == bp && oi < bi)) { bp = op; bi = oi; }
    }
    gsum += bp;
    if (lane == k) { myg = bp; myi = bi; }
    if (lane == bi) myp = -1.f;
  }
  if (lane < K_TOP) {
    topk_i[n * K_TOP + lane] = myi;
    topk_p[n * K_TOP + lane] = myg / (gsum + 1e-9f);
  }
}

// ---------------- fast router: transposed weights, 8 tokens/wave ----------------
// 8192 float4 entries total: e in [0,64), k4 in [0,128). MUST launch exactly 8192 threads.
__global__ void transpose_rw(const float* __restrict__ rw, float* __restrict__ rwt) {
  int idx = blockIdx.x * 256 + threadIdx.x;
  if (idx >= E_NUM * (D_DIM / 4)) return;      // guard (grid-size slip caused R6 failure)
  int e = idx >> 7, k4 = idx & 127;
  float4 v = *(const float4*)(rw + (size_t)e * D_DIM + k4 * 4);
  *(float4*)(rwt + ((size_t)k4 * 64 + e) * 4) = v;
}

__device__ __forceinline__ void softmax_topk_write(float logit, int n, int lane,
                                                   int* __restrict__ topk_i,
                                                   float* __restrict__ topk_p) {
  float m = logit;
  for (int off = 32; off > 0; off >>= 1) m = fmaxf(m, __shfl_xor(m, off));
  float p = expf(logit - m);
  float s = p;
  for (int off = 32; off > 0; off >>= 1) s += __shfl_xor(s, off);
  float prob = p / s;

  float myp = prob;
  float gsum = 0.f;
  float myg = 0.f; int myi = -1;
  #pragma unroll 1
  for (int k = 0; k < K_TOP; ++k) {
    float bp = myp; int bi = lane;
    for (int off = 32; off > 0; off >>= 1) {
      float op = __shfl_xor(bp, off); int oi = __shfl_xor(bi, off);
      if (op > bp || (op == bp && oi < bi)) { bp = op; bi = oi; }
    }
    gsum += bp;
    if (lane == k) { myg = bp; myi = bi; }
    if (lane == bi) myp = -1.f;
  }
  if (lane < K_TOP) {
    topk_i[n * K_TOP + lane] = myi;
    topk_p[n * K_TOP + lane] = myg / (gsum + 1e-9f);
  }
}

__global__ void __launch_bounds__(256) router_topk2(
    const float* __restrict__ x, const float* __restrict__ rwt,
    const float* __restrict__ bias, int* __restrict__ topk_i,
    float* __restrict__ topk_p) {
  const int wave = threadIdx.x >> 6;
  const int lane = threadIdx.x & 63;      // lane == expert id
  const int n0 = blockIdx.x * 32 + wave * 8;

  float acc[8];
  #pragma unroll
  for (int t = 0; t < 8; ++t) acc[t] = 0.f;

  const float4* wv4 = (const float4*)rwt;
  #pragma unroll 2
  for (int k4 = 0; k4 < 128; ++k4) {
    float4 w = wv4[k4 * 64 + lane];
    #pragma unroll
    for (int t = 0; t < 8; ++t) {
      float4 xv = *(const float4*)(x + (size_t)(n0 + t) * D_DIM + k4 * 4);
      acc[t] += xv.x * w.x + xv.y * w.y + xv.z * w.z + xv.w * w.w;
    }
  }
  float b = bias[lane];
  #pragma unroll 1
  for (int t = 0; t < 8; ++t)
    softmax_topk_write(acc[t] + b, n0 + t, lane, topk_i, topk_p);
}

// ---------------- per-chunk expert histogram ----------------
__global__ void hist_kernel(const int* __restrict__ topk_i, int* __restrict__ chunk_hist) {
  __shared__ int h[E_NUM];
  const int tid = threadIdx.x;
  if (tid < E_NUM) h[tid] = 0;
  __syncthreads();
  int e = topk_i[blockIdx.x * 256 + tid];
  atomicAdd(&h[e], 1);
  __syncthreads();
  if (tid < E_NUM) chunk_hist[blockIdx.x * E_NUM + tid] = h[tid];
}

// ---------------- exclusive scan over chunks, per expert ----------------
__global__ void scan_kernel(const int* __restrict__ chunk_hist, int* __restrict__ chunk_base) {
  const int e = threadIdx.x;  // 64 threads
  int run = 0;
  for (int c = 0; c < NCHUNK; ++c) {
    chunk_base[c * E_NUM + e] = run;
    run += chunk_hist[c * E_NUM + e];
  }
}

// ---------------- dispatch: slot = global stable rank within expert ----------------
__global__ void dispatch_kernel(const int* __restrict__ topk_i, const float* __restrict__ topk_p,
                                const int* __restrict__ chunk_base,
                                int* __restrict__ expert_tok, float* __restrict__ expert_gate,
                                int* __restrict__ entry_row) {
  __shared__ int eid[256];
  const int tid = threadIdx.x;
  const int m = blockIdx.x * 256 + tid;
  const int e = topk_i[m];
  eid[tid] = e;
  __syncthreads();
  int rank = 0;
  for (int t = 0; t < tid; ++t) rank += (eid[t] == e);
  int slot = chunk_base[blockIdx.x * E_NUM + e] + rank;
  int row = -1;
  if (slot < CAP) {
    expert_tok[e * CAP + slot] = m / K_TOP;
    expert_gate[e * CAP + slot] = topk_p[m];
    row = e * CAP + slot;
  }
  if (entry_row) entry_row[m] = row;
}

// ================= FAST PATH =================

// x fp32 -> bf16 row-major
__global__ void convert_x(const float* __restrict__ x, ushort* __restrict__ xb) {
  size_t idx = (size_t)blockIdx.x * 256 + threadIdx.x;
  const float4* s4 = (const float4*)(x + idx * 8);
  float4 v0 = s4[0], v1 = s4[1];
  short8 o;
  o[0] = f2bf(v0.x); o[1] = f2bf(v0.y); o[2] = f2bf(v0.z); o[3] = f2bf(v0.w);
  o[4] = f2bf(v1.x); o[5] = f2bf(v1.y); o[6] = f2bf(v1.z); o[7] = f2bf(v1.w);
  *(short8*)(xb + idx * 8) = o;
}

// weights fp32 -> bf16, pre-tiled fragment layout; fully-coalesced reads.
// blockIdx.x = e*12 + p*4 + rb  (p: 0 gate / 1 up / 2 down; rb = quarter of the matrix)
__global__ void convert_w(const float* __restrict__ wg_, const float* __restrict__ wu_,
                          const float* __restrict__ wd_, const float* __restrict__ swg,
                          const float* __restrict__ swu, const float* __restrict__ swd,
                          ushort* __restrict__ Wt) {
  int e = blockIdx.x / 12;
  int rem = blockIdx.x - e * 12;
  int p = rem >> 2, rb = rem & 3;
  const float* src;
  if (p == 0)      src = (e < E_NUM) ? wg_ + (size_t)e * 131072 : swg + (size_t)(e - E_NUM) * 131072;
  else if (p == 1) src = (e < E_NUM) ? wu_ + (size_t)e * 131072 : swu + (size_t)(e - E_NUM) * 131072;
  else             src = (e < E_NUM) ? wd_ + (size_t)e * 131072 : swd + (size_t)(e - E_NUM) * 131072;
  src += (size_t)rb * 32768;
  ushort* dst = Wt + (size_t)e * EW_STRIDE + (size_t)p * 131072;
  #pragma unroll
  for (int i = 0; i < 16; ++i) {
    int g = threadIdx.x + i * 256;              // 8-float group, contiguous reads
    const float4* s4 = (const float4*)(src + (size_t)g * 8);
    float4 v0 = s4[0], v1 = s4[1];
    short8 o;
    o[0] = f2bf(v0.x); o[1] = f2bf(v0.y); o[2] = f2bf(v0.z); o[3] = f2bf(v0.w);
    o[4] = f2bf(v1.x); o[5] = f2bf(v1.y); o[6] = f2bf(v1.z); o[7] = f2bf(v1.w);
    size_t L = (size_t)rb * 32768 + (size_t)g * 8;   // linear offset in 131072-float matrix
    size_t d;
    if (p < 2) {
      int n = (int)(L >> 9);          // row (F index), ld = 512
      int k = (int)(L & 511);
      int ci = k >> 5;
      int k8 = (k >> 3) & 3;
      d = (size_t)ci * 8192 + (size_t)(n >> 4) * 512 + k8 * 128 + (n & 15) * 8;
    } else {
      int rd = (int)(L >> 8);         // source row (D index), ld = 256
      int np = rd >> 8;               // 0/1 (which 256-col half of the down output)
      int n  = rd & 255;
      int col = (int)(L & 255);
      int kc = col >> 5;
      int k8 = (col >> 3) & 3;
      int ci = np * 8 + kc;
      d = (size_t)ci * 8192 + (size_t)(n >> 4) * 512 + k8 * 128 + (n & 15) * 8;
    }
    *(short8*)(dst + d) = o;
  }
}

// fill token lists for the two shared experts: every token, gate = 0.5
__global__ void init_shared_tok(int* __restrict__ tok_all, float* __restrict__ gate_all) {
  int i = blockIdx.x * 256 + threadIdx.x;
  tok_all[TOK_ROUTED + i] = i & (N_TOK - 1);
  gate_all[TOK_ROUTED + i] = 0.5f;
}

// Unified FFN: 64-token tile x one expert, 512 threads (8 waves, 2 row x 4 col),
// fused gate+up, 3-slot ring with counted vmcnt.
// GATHER=true: epilogue = plain bf16 stores of raw expert output into expert_out.
// GATHER=false: epilogue = gated fp32 atomicAdd into out (fallback).
template <bool GATHER>
__global__ void __launch_bounds__(512, 1) ffn_mfma(
    const ushort* __restrict__ xb, const ushort* __restrict__ Wt,
    const int* __restrict__ tok_all, const float* __restrict__ gate_all,
    float* __restrict__ out, ushort* __restrict__ expert_out) {
  int e, tbase;
  if (blockIdx.x < 2 * (N_TOK / 64)) {          // shared tiles first (always full)
    int sid = blockIdx.x;
    int sh = sid & 1, mt = sid >> 1;
    e = E_NUM + sh;
    tbase = TOK_ROUTED + sh * N_TOK + mt * 64;
  } else {
    int rb = blockIdx.x - 2 * (N_TOK / 64);
    e = rb & (E_NUM - 1);
    int mt = rb >> 6;
    tbase = e * CAP + mt * 64;
    if (tok_all[tbase] < 0) return;             // contiguous fill -> empty tile
  }
  const ushort* wbase = Wt + (size_t)e * EW_STRIDE;

  __shared__ ushort RING[3 * SLOT];   // 108 KB: per slot X[2048] Wg[8192] Wu[8192]
  __shared__ ushort Act[16384];       // 32 KB: 64tok x 256f, fragment-tiled
  __shared__ int   toks[64];
  __shared__ float gts[64];

  const int tid = threadIdx.x;
  const int lane = tid & 63;
  const int wid = tid >> 6;        // 0..7
  const int wr = wid >> 2;         // 0..1  (row half: 32 tokens)
  const int wc = wid & 3;          // 0..3  (col quarter)
  const int rl = lane & 15;
  const int hi = lane >> 4;

  if (tid < 64) {
    int t = tok_all[tbase + tid];
    toks[tid] = t;
    gts[tid] = (t >= 0) ? gate_all[tbase + tid] : 0.f;
  }
  __syncthreads();

  // waves 0-3 stage the X tile (subtile = wid): per-lane source row
  int stok = 0;
  if (wid < 4) { int t = toks[wid * 16 + rl]; stok = (t < 0) ? 0 : t; }
  const ushort* xsrc = xb + (size_t)stok * D_DIM + hi * 8;

  auto stage_gu = [&](int sl, int kc) {
    ushort* dst = RING + sl * SLOT;
    if (wid < 4)
      gload16(xsrc + kc * 32, dst + wid * 512);
    #pragma unroll
    for (int i = 0; i < 2; ++i) {
      int s = wid * 2 + i;
      gload16(wbase + kc * 8192 + s * 512 + lane * 8, dst + 2048 + s * 512);
      gload16(wbase + 131072 + kc * 8192 + s * 512 + lane * 8, dst + 10240 + s * 512);
    }
  };
  auto stage_dn = [&](int sl, int kc) {
    ushort* dst = RING + sl * SLOT;
    #pragma unroll
    for (int i = 0; i < 4; ++i) {
      int s = wid * 4 + i;
      gload16(wbase + 262144 + (s >> 4) * 65536 + kc * 8192 + (s & 15) * 512 + lane * 8,
              dst + s * 512);
    }
  };

  const f32x4 fzero = {0.f, 0.f, 0.f, 0.f};
  f32x4 accg[2][4], accu[2][4];
  #pragma unroll
  for (int ri = 0; ri < 2; ++ri)
    #pragma unroll
    for (int bi = 0; bi < 4; ++bi) { accg[ri][bi] = fzero; accu[ri][bi] = fzero; }

  // ---- fused gate+up: 16 K-steps of 32 ----
  stage_gu(0, 0); stage_gu(1, 1);
  {
    int sl_c = 0, sl_n = 2;
    #pragma unroll 1
    for (int kc = 0; kc < 16; ++kc) {
      if (kc < 14) { stage_gu(sl_n, kc + 2); sl_n = (sl_n == 2) ? 0 : sl_n + 1; }
      if (kc < 14)      { if (wid < 4) VMCNT(10); else VMCNT(8); }
      else if (kc == 14){ if (wid < 4) VMCNT(5);  else VMCNT(4); }
      else              VMCNT(0);
      __builtin_amdgcn_s_barrier();
      __builtin_amdgcn_sched_barrier(0);
      {
        const ushort* base = RING + sl_c * SLOT;
        bf16x8 a[2], bg[4], bu[4];
        #pragma unroll
        for (int ri = 0; ri < 2; ++ri)
          a[ri] = *(const bf16x8*)(base + (wr * 2 + ri) * 512 + lane * 8);
        #pragma unroll
        for (int bi = 0; bi < 4; ++bi) {
          bg[bi] = *(const bf16x8*)(base + 2048 + (wc * 4 + bi) * 512 + lane * 8);
          bu[bi] = *(const bf16x8*)(base + 10240 + (wc * 4 + bi) * 512 + lane * 8);
        }
        __builtin_amdgcn_s_setprio(1);
        #pragma unroll
        for (int ri = 0; ri < 2; ++ri)
          #pragma unroll
          for (int bi = 0; bi < 4; ++bi) {
            accg[ri][bi] = __builtin_amdgcn_mfma_f32_16x16x32_bf16(a[ri], bg[bi], accg[ri][bi], 0, 0, 0);
            accu[ri][bi] = __builtin_amdgcn_mfma_f32_16x16x32_bf16(a[ri], bu[bi], accu[ri][bi], 0, 0, 0);
          }
        __builtin_amdgcn_s_setprio(0);
      }
      sl_c = (sl_c == 2) ? 0 : sl_c + 1;
      __builtin_amdgcn_s_barrier();
    }
  }

  // ---- silu(g)*u in-register -> Act (fragment-tiled bf16) ----
  #pragma unroll
  for (int ri = 0; ri < 2; ++ri)
    #pragma unroll
    for (int bi = 0; bi < 4; ++bi) {
      int st = (wr * 2 + ri) * 8 + wc * 2 + (bi >> 1);
      int base = st * 512 + ((bi & 1) * 2 + (rl >> 3)) * 128 + (rl & 7);
      #pragma unroll
      for (int j = 0; j < 4; ++j) {
        float g = accg[ri][bi][j], u = accu[ri][bi][j];
        Act[base + (hi * 4 + j) * 8] = f2bf(g / (1.f + __expf(-g)) * u);
      }
    }

  // ---- down: out[64 x 512], 8 K-steps of 32 over F ----
  f32x4 accd[2][8];
  #pragma unroll
  for (int ri = 0; ri < 2; ++ri)
    #pragma unroll
    for (int bj = 0; bj < 8; ++bj) accd[ri][bj] = fzero;

  stage_dn(0, 0); stage_dn(1, 1);
  asm volatile("s_waitcnt lgkmcnt(0)" ::: "memory");
  __builtin_amdgcn_s_barrier();
  __builtin_amdgcn_sched_barrier(0);
  {
    int sl_c = 0, sl_n = 2;
    #pragma unroll 1
    for (int kc = 0; kc < 8; ++kc) {
      if (kc < 6) { stage_dn(sl_n, kc + 2); sl_n = (sl_n == 2) ? 0 : sl_n + 1; }
      if (kc < 6)       VMCNT(8);
      else if (kc == 6) VMCNT(4);
      else              VMCNT(0);
      __builtin_amdgcn_s_barrier();
      __builtin_amdgcn_sched_barrier(0);
      {
        const ushort* base = RING + sl_c * SLOT;
        bf16x8 a[2], b[8];
        #pragma unroll
        for (int ri = 0; ri < 2; ++ri)
          a[ri] = *(const bf16x8*)(Act + ((wr * 2 + ri) * 8 + kc) * 512 + lane * 8);
        #pragma unroll
        for (int bj = 0; bj < 8; ++bj)
          b[bj] = *(const bf16x8*)(base + (wc * 8 + bj) * 512 + lane * 8);
        __builtin_amdgcn_s_setprio(1);
        #pragma unroll
        for (int ri = 0; ri < 2; ++ri)
          #pragma unroll
          for (int bj = 0; bj < 8; ++bj)
            accd[ri][bj] = __builtin_amdgcn_mfma_f32_16x16x32_bf16(a[ri], b[bj], accd[ri][bj], 0, 0, 0);
        __builtin_amdgcn_s_setprio(0);
      }
      sl_c = (sl_c == 2) ? 0 : sl_c + 1;
      __builtin_amdgcn_s_barrier();
    }
  }

  // ---- epilogue ----
  if (GATHER) {
    // raw (un-gated) bf16 rows into expert_out; gather kernel applies gates.
    #pragma unroll
    for (int ri = 0; ri < 2; ++ri)
      #pragma unroll
      for (int j = 0; j < 4; ++j) {
        int r = wr * 32 + ri * 16 + hi * 4 + j;
        if (toks[r] < 0) continue;
        ushort* erow = expert_out + (size_t)(tbase + r) * D_DIM + wc * 128 + rl;
        #pragma unroll
        for (int bj = 0; bj < 8; ++bj)
          erow[bj * 16] = f2bf(accd[ri][bj][j]);
      }
  } else {
    #pragma unroll
    for (int ri = 0; ri < 2; ++ri)
      #pragma unroll
      for (int j = 0; j < 4; ++j) {
        int r = wr * 32 + ri * 16 + hi * 4 + j;
        int t = toks[r];
        if (t < 0) continue;
        float gt = gts[r];
        float* orow = out + (size_t)t * D_DIM + wc * 128 + rl;
        #pragma unroll
        for (int bj = 0; bj < 8; ++bj)
          atomicAdd(orow + bj * 16, gt * accd[ri][bj][j]);
      }
  }
}

// ---------------- gather combine: one wave per token ----------------
__global__ void __launch_bounds__(256) gather_out(
    const ushort* __restrict__ eo, const int* __restrict__ entry_row,
    const float* __restrict__ topk_p, float* __restrict__ out) {
  const int t = blockIdx.x * 4 + (threadIdx.x >> 6);
  const int lane = threadIdx.x & 63;
  const int base = t * K_TOP;

  float acc[8];
  #pragma unroll
  for (int j = 0; j < 8; ++j) acc[j] = 0.f;

  #pragma unroll
  for (int k = 0; k < K_TOP; ++k) {
    int row = entry_row[base + k];
    if (row >= 0) {
      float g = topk_p[base + k];
      bf16x8 v = *(const bf16x8*)(eo + (size_t)row * D_DIM + lane * 8);
      #pragma unroll
      for (int j = 0; j < 8; ++j) acc[j] += g * bf2f((ushort)v[j]);
    }
  }
  #pragma unroll
  for (int sh = 0; sh < SH_NUM; ++sh) {
    int row = TOK_ROUTED + sh * N_TOK + t;
    bf16x8 v = *(const bf16x8*)(eo + (size_t)row * D_DIM + lane * 8);
    #pragma unroll
    for (int j = 0; j < 8; ++j) acc[j] += 0.5f * bf2f((ushort)v[j]);
  }
  float4* o = (float4*)(out + (size_t)t * D_DIM + lane * 8);
  o[0] = make_float4(acc[0], acc[1], acc[2], acc[3]);
  o[1] = make_float4(acc[4], acc[5], acc[6], acc[7]);
}

// ================= LEGACY PATH (round-2, used when ws tiny) =================

__global__ void __launch_bounds__(256, 2) expert_ffn_mfma(
    const float* __restrict__ x, const float* __restrict__ wg_,
    const float* __restrict__ wu_, const float* __restrict__ wd_,
    const int* __restrict__ expert_tok, const float* __restrict__ expert_gate,
    float* __restrict__ out) {
  const int e = blockIdx.x & (E_NUM - 1);
  const int mt = blockIdx.x >> 6;
  const int s0 = mt * 64;
  if (expert_tok[e * CAP + s0] < 0) return;

  __shared__ ushort Xs[64][72];
  __shared__ ushort Ws[256][72];
  __shared__ ushort Act[64][264];
  __shared__ int   toks[64];
  __shared__ float gts[64];

  const int tid = threadIdx.x;
  const int lane = tid & 63;
  const int wid = tid >> 6;
  const int rl = lane & 15;
  const int ko = (lane >> 4) * 8;
  const int rquad = (lane >> 4) * 4;

  if (tid < 64) {
    int t = expert_tok[e * CAP + s0 + tid];
    toks[tid] = t;
    gts[tid] = (t >= 0) ? expert_gate[e * CAP + s0 + tid] : 0.f;
  }
  __syncthreads();

  float4 px[4], pw[16];

  auto loadX = [&](int kb) {
    #pragma unroll
    for (int it = 0; it < 4; ++it) {
      int idx = tid + it * 256;
      int row = idx >> 4, c4 = (idx & 15) << 2;
      int t = toks[row];
      px[it] = (t >= 0) ? *(const float4*)(x + (size_t)t * D_DIM + kb * 64 + c4)
                        : make_float4(0.f, 0.f, 0.f, 0.f);
    }
  };
  auto writeX = [&]() {
    #pragma unroll
    for (int it = 0; it < 4; ++it) {
      int idx = tid + it * 256;
      int row = idx >> 4, c4 = (idx & 15) << 2;
      ushort4 h; h.x = f2bf(px[it].x); h.y = f2bf(px[it].y);
      h.z = f2bf(px[it].z); h.w = f2bf(px[it].w);
      *(ushort4*)&Xs[row][c4] = h;
    }
  };
  auto loadW = [&](const float* src, int ldk, int kb) {
    #pragma unroll
    for (int it = 0; it < 16; ++it) {
      int idx = tid + it * 256;
      int row = idx >> 4, c4 = (idx & 15) << 2;
      pw[it] = *(const float4*)(src + (size_t)row * ldk + kb * 64 + c4);
    }
  };
  auto writeW = [&]() {
    #pragma unroll
    for (int it = 0; it < 16; ++it) {
      int idx = tid + it * 256;
      int row = idx >> 4, c4 = (idx & 15) << 2;
      ushort4 h; h.x = f2bf(pw[it].x); h.y = f2bf(pw[it].y);
      h.z = f2bf(pw[it].z); h.w = f2bf(pw[it].w);
      *(ushort4*)&Ws[row][c4] = h;
    }
  };
  auto compute = [&](const ushort* Ab, int lda, f32x4 (&acc)[4][4]) {
    #pragma unroll
    for (int kk = 0; kk < 2; ++kk) {
      bf16x8 a[4], b[4];
      #pragma unroll
      for (int ri = 0; ri < 4; ++ri)
        a[ri] = *(const bf16x8*)(Ab + (size_t)(ri * 16 + rl) * lda + kk * 32 + ko);
      #pragma unroll
      for (int bi = 0; bi < 4; ++bi)
        b[bi] = *(const bf16x8*)(&Ws[wid * 64 + bi * 16 + rl][kk * 32 + ko]);
      #pragma unroll
      for (int ri = 0; ri < 4; ++ri)
        #pragma unroll
        for (int bi = 0; bi < 4; ++bi)
          acc[ri][bi] = __builtin_amdgcn_mfma_f32_16x16x32_bf16(a[ri], b[bi], acc[ri][bi], 0, 0, 0);
    }
  };

  const f32x4 fzero = {0.f, 0.f, 0.f, 0.f};

  #pragma unroll 1
  for (int which = 0; which < 2; ++which) {
    const float* wsrc = (which == 0 ? wg_ : wu_) + (size_t)e * F_DIM * D_DIM;
    f32x4 acc[4][4];
    #pragma unroll
    for (int ri = 0; ri < 4; ++ri)
      #pragma unroll
      for (int bi = 0; bi < 4; ++bi) acc[ri][bi] = fzero;

    loadX(0); loadW(wsrc, D_DIM, 0);
    writeX(); writeW();
    __syncthreads();
    for (int kb = 0; kb < 8; ++kb) {
      if (kb < 7) { loadX(kb + 1); loadW(wsrc, D_DIM, kb + 1); }
      compute(&Xs[0][0], 72, acc);
      __syncthreads();
      if (kb < 7) { writeX(); writeW(); __syncthreads(); }
    }
    #pragma unroll
    for (int ri = 0; ri < 4; ++ri)
      #pragma unroll
      for (int bi = 0; bi < 4; ++bi)
        #pragma unroll
        for (int j = 0; j < 4; ++j) {
          int r = ri * 16 + rquad + j;
          int c = wid * 64 + bi * 16 + rl;
          if (which == 0) {
            Act[r][c] = f2bf(acc[ri][bi][j]);
          } else {
            float hg = bf2f(Act[r][c]);
            float a = hg / (1.f + __expf(-hg)) * acc[ri][bi][j];
            Act[r][c] = f2bf(a);
          }
        }
    __syncthreads();
  }

  #pragma unroll 1
  for (int np = 0; np < 2; ++np) {
    const float* wsrc = wd_ + ((size_t)e * D_DIM + np * 256) * F_DIM;
    f32x4 acc[4][4];
    #pragma unroll
    for (int ri = 0; ri < 4; ++ri)
      #pragma unroll
      for (int bi = 0; bi < 4; ++bi) acc[ri][bi] = fzero;

    loadW(wsrc, F_DIM, 0); writeW();
    __syncthreads();
    for (int kb = 0; kb < 4; ++kb) {
      if (kb < 3) loadW(wsrc, F_DIM, kb + 1);
      compute(&Act[0][kb * 64], 264, acc);
      __syncthreads();
      if (kb < 3) { writeW(); __syncthreads(); }
    }
    #pragma unroll
    for (int ri = 0; ri < 4; ++ri)
      #pragma unroll
      for (int bi = 0; bi < 4; ++bi)
        #pragma unroll
        for (int j = 0; j < 4; ++j) {
          int r = ri * 16 + rquad + j;
          int t = toks[r];
          if (t >= 0) {
            int c = np * 256 + wid * 64 + bi * 16 + rl;
            atomicAdd(out + (size_t)t * D_DIM + c, gts[r] * acc[ri][bi][j]);
          }
        }
  }
}

__global__ void __launch_bounds__(256, 2) shared_ffn_mfma(
    const float* __restrict__ x, const float* __restrict__ swg,
    const float* __restrict__ swu, const float* __restrict__ swd,
    float* __restrict__ out) {
  const int row0 = blockIdx.x * 32;

  __shared__ ushort Xs[32][72];
  __shared__ ushort Ws[256][72];
  __shared__ ushort Act[32][264];

  const int tid = threadIdx.x;
  const int lane = tid & 63;
  const int wid = tid >> 6;
  const int rl = lane & 15;
  const int ko = (lane >> 4) * 8;
  const int rquad = (lane >> 4) * 4;

  float4 px[2], pw[16];

  auto loadX = [&](int kb) {
    #pragma unroll
    for (int it = 0; it < 2; ++it) {
      int idx = tid + it * 256;
      int row = idx >> 4, c4 = (idx & 15) << 2;
      px[it] = *(const float4*)(x + (size_t)(row0 + row) * D_DIM + kb * 64 + c4);
    }
  };
  auto writeX = [&]() {
    #pragma unroll
    for (int it = 0; it < 2; ++it) {
      int idx = tid + it * 256;
      int row = idx >> 4, c4 = (idx & 15) << 2;
      ushort4 h; h.x = f2bf(px[it].x); h.y = f2bf(px[it].y);
      h.z = f2bf(px[it].z); h.w = f2bf(px[it].w);
      *(ushort4*)&Xs[row][c4] = h;
    }
  };
  auto loadW = [&](const float* src, int ldk, int kb) {
    #pragma unroll
    for (int it = 0; it < 16; ++it) {
      int idx = tid + it * 256;
      int row = idx >> 4, c4 = (idx & 15) << 2;
      pw[it] = *(const float4*)(src + (size_t)row * ldk + kb * 64 + c4);
    }
  };
  auto writeW = [&]() {
    #pragma unroll
    for (int it = 0; it < 16; ++it) {
      int idx = tid + it * 256;
      int row = idx >> 4, c4 = (idx & 15) << 2;
      ushort4 h; h.x = f2bf(pw[it].x); h.y = f2bf(pw[it].y);
      h.z = f2bf(pw[it].z); h.w = f2bf(pw[it].w);
      *(ushort4*)&Ws[row][c4] = h;
    }
  };
  auto compute = [&](const ushort* Ab, int lda, f32x4 (&acc)[2][4]) {
    #pragma unroll
    for (int kk = 0; kk < 2; ++kk) {
      bf16x8 a[2], b[4];
      #pragma unroll
      for (int ri = 0; ri < 2; ++ri)
        a[ri] = *(const bf16x8*)(Ab + (size_t)(ri * 16 + rl) * lda + kk * 32 + ko);
      #pragma unroll
      for (int bi = 0; bi < 4; ++bi)
        b[bi] = *(const bf16x8*)(&Ws[wid * 64 + bi * 16 + rl][kk * 32 + ko]);
      #pragma unroll
      for (int ri = 0; ri < 2; ++ri)
        #pragma unroll
        for (int bi = 0; bi < 4; ++bi)
          acc[ri][bi] = __builtin_amdgcn_mfma_f32_16x16x32_bf16(a[ri], b[bi], acc[ri][bi], 0, 0, 0);
    }
  };

  const f32x4 fzero = {0.f, 0.f, 0.f, 0.f};
  f32x4 accd[2][2][4];
  #pragma unroll
  for (int np = 0; np < 2; ++np)
    #pragma unroll
    for (int ri = 0; ri < 2; ++ri)
      #pragma unroll
      for (int bi = 0; bi < 4; ++bi) accd[np][ri][bi] = fzero;

  #pragma unroll 1
  for (int sh = 0; sh < SH_NUM; ++sh) {
    #pragma unroll 1
    for (int which = 0; which < 2; ++which) {
      const float* wsrc = (which == 0 ? swg : swu) + (size_t)sh * F_DIM * D_DIM;
      f32x4 acc[2][4];
      #pragma unroll
      for (int ri = 0; ri < 2; ++ri)
        #pragma unroll
        for (int bi = 0; bi < 4; ++bi) acc[ri][bi] = fzero;

      loadX(0); loadW(wsrc, D_DIM, 0);
      writeX(); writeW();
      __syncthreads();
      for (int kb = 0; kb < 8; ++kb) {
        if (kb < 7) { loadX(kb + 1); loadW(wsrc, D_DIM, kb + 1); }
        compute(&Xs[0][0], 72, acc);
        __syncthreads();
        if (kb < 7) { writeX(); writeW(); __syncthreads(); }
      }
      #pragma unroll
      for (int ri = 0; ri < 2; ++ri)
        #pragma unroll
        for (int bi = 0; bi < 4; ++bi)
          #pragma unroll
          for (int j = 0; j < 4; ++j) {
            int r = ri * 16 + rquad + j;
            int c = wid * 64 + bi * 16 + rl;
            if (which == 0) {
              Act[r][c] = f2bf(acc[ri][bi][j]);
            } else {
              float hg = bf2f(Act[r][c]);
              float a = hg / (1.f + __expf(-hg)) * acc[ri][bi][j];
              Act[r][c] = f2bf(a);
            }
          }
      __syncthreads();
    }
    #pragma unroll
    for (int np = 0; np < 2; ++np) {
      const float* wsrc = swd + ((size_t)sh * D_DIM + np * 256) * F_DIM;
      loadW(wsrc, F_DIM, 0); writeW();
      __syncthreads();
      for (int kb = 0; kb < 4; ++kb) {
        if (kb < 3) loadW(wsrc, F_DIM, kb + 1);
        compute(&Act[0][kb * 64], 264, accd[np]);
        __syncthreads();
        if (kb < 3) { writeW(); __syncthreads(); }
      }
    }
  }

  #pragma unroll
  for (int np = 0; np < 2; ++np)
    #pragma unroll
    for (int ri = 0; ri < 2; ++ri)
      #pragma unroll
      for (int bi = 0; bi < 4; ++bi)
        #pragma unroll
        for (int j = 0; j < 4; ++j) {
          int r = ri * 16 + rquad + j;
          int c = np * 256 + wid * 64 + bi * 16 + rl;
          out[(size_t)(row0 + r) * D_DIM + c] = 0.5f * accd[np][ri][bi][j];
        }
}

extern "C" void kernel_launch(void* const* d_in, const int* in_sizes, int n_in,
                              void* d_out, int out_size, void* d_ws, size_t ws_size,
                              hipStream_t stream) {
  const float* x    = (const float*)d_in[0];
  const float* rw   = (const float*)d_in[1];
  const float* bias = (const float*)d_in[2];
  const float* swg  = (const float*)d_in[3];
  const float* swu  = (const float*)d_in[4];
  const float* swd  = (const float*)d_in[5];
  const float* wg   = (const float*)d_in[6];
  const float* wu   = (const float*)d_in[7];
  const float* wd   = (const float*)d_in[8];
  float* out = (float*)d_out;

  const size_t small = 2 * (size_t)M_ENT * 4 + (size_t)M_ENT * 4 +
                       2 * (size_t)NCHUNK * E_NUM * 4 + 2 * (size_t)TOK_TOTAL * 4 +
                       RWT_BYTES;
  const size_t need_mid = X_BF_BYTES + WT_BYTES + small;
  const size_t need_big = need_mid + EO_BYTES;

  if (ws_size >= need_mid) {
    const bool gather = (ws_size >= need_big);
    char* ws = (char*)d_ws;
    ushort* x_bf     = (ushort*)ws; ws += X_BF_BYTES;
    ushort* Wt       = (ushort*)ws; ws += WT_BYTES;
    int*   topk_i    = (int*)ws;    ws += (size_t)M_ENT * 4;
    float* topk_p    = (float*)ws;  ws += (size_t)M_ENT * 4;
    int*   entry_row = (int*)ws;    ws += (size_t)M_ENT * 4;
    int*   chunk_hist= (int*)ws;    ws += (size_t)NCHUNK * E_NUM * 4;
    int*   chunk_base= (int*)ws;    ws += (size_t)NCHUNK * E_NUM * 4;
    int*   tok_all   = (int*)ws;    ws += (size_t)TOK_TOTAL * 4;
    float* gate_all  = (float*)ws;  ws += (size_t)TOK_TOTAL * 4;
    float* rwt       = (float*)ws;  ws += RWT_BYTES;
    ushort* eo       = (ushort*)ws; // only valid if gather

    transpose_rw<<<32, 256, 0, stream>>>(rw, rwt);
    convert_x<<<2048, 256, 0, stream>>>(x, x_bf);
    convert_w<<<E_TOT * 12, 256, 0, stream>>>(wg, wu, wd, swg, swu, swd, Wt);
    router_topk2<<<256, 256, 0, stream>>>(x, rwt, bias, topk_i, topk_p);
    hipMemsetAsync(tok_all, 0xFF, (size_t)TOK_ROUTED * 4, stream);
    if (!gather) hipMemsetAsync(out, 0, (size_t)out_size * 4, stream);
    hist_kernel<<<NCHUNK, 256, 0, stream>>>(topk_i, chunk_hist);
    scan_kernel<<<1, 64, 0, stream>>>(chunk_hist, chunk_base);
    dispatch_kernel<<<NCHUNK, 256, 0, stream>>>(topk_i, topk_p, chunk_base, tok_all,
                                                gate_all, entry_row);
    init_shared_tok<<<64, 256, 0, stream>>>(tok_all, gate_all);
    const int nblk = 2 * (N_TOK / 64) + (CAP / 64) * E_NUM;
    if (gather) {
      ffn_mfma<true><<<nblk, 512, 0, stream>>>(x_bf, Wt, tok_all, gate_all, out, eo);
      gather_out<<<N_TOK / 4, 256, 0, stream>>>(eo, entry_row, topk_p, out);
    } else {
      ffn_mfma<false><<<nblk, 512, 0, stream>>>(x_bf, Wt, tok_all, gate_all, out, nullptr);
    }
  } else {
    char* ws = (char*)d_ws;
    int*   topk_i      = (int*)ws;   ws += (size_t)M_ENT * 4;
    float* topk_p      = (float*)ws; ws += (size_t)M_ENT * 4;
    int*   chunk_hist  = (int*)ws;   ws += (size_t)NCHUNK * E_NUM * 4;
    int*   chunk_base  = (int*)ws;   ws += (size_t)NCHUNK * E_NUM * 4;
    int*   expert_tok  = (int*)ws;   ws += (size_t)E_NUM * CAP * 4;
    float* expert_gate = (float*)ws; ws += (size_t)E_NUM * CAP * 4;

    router_topk<<<N_TOK / 4, 256, 0, stream>>>(x, rw, bias, topk_i, topk_p);
    hipMemsetAsync(expert_tok, 0xFF, (size_t)E_NUM * CAP * 4, stream);
    hist_kernel<<<NCHUNK, 256, 0, stream>>>(topk_i, chunk_hist);
    scan_kernel<<<1, 64, 0, stream>>>(chunk_hist, chunk_base);
    dispatch_kernel<<<NCHUNK, 256, 0, stream>>>(topk_i, topk_p, chunk_base, expert_tok,
                                                expert_gate, nullptr);
    shared_ffn_mfma<<<N_TOK / 32, 256, 0, stream>>>(x, swg, swu, swd, out);
    expert_ffn_mfma<<<(CAP / 64) * E_NUM, 256, 0, stream>>>(x, wg, wu, wd, expert_tok,
                                                            expert_gate, out);
  }
}

// Round 9
// 283.800 us; speedup vs baseline: 7.1733x; 1.0770x over previous
//
#include <hip/hip_runtime.h>
#include <hip/hip_bf16.h>
#include <math.h>

#define N_TOK 8192
#define D_DIM 512
#define F_DIM 256
#define E_NUM 64
#define SH_NUM 2
#define K_TOP 6
#define CAP   1536
#define M_ENT (N_TOK * K_TOP)   // 49152
#define NCHUNK (M_ENT / 256)    // 192

// fast-path workspace geometry (element = ushort/bf16 unless noted)
#define EW_STRIDE 393216            // shorts per expert blob (48 chunks x 8192)
#define E_TOT (E_NUM + SH_NUM)      // 66
#define X_BF_BYTES   (8388608ull)                    // 8192*512*2
#define WT_BYTES     ((size_t)E_TOT * EW_STRIDE * 2) // 51,904,512
#define TOK_ROUTED   (E_NUM * CAP)                   // 98304 entries
#define TOK_TOTAL    (TOK_ROUTED + SH_NUM * N_TOK)   // +16384
#define EO_BYTES     ((size_t)TOK_TOTAL * D_DIM * 2) // 117,440,512
#define RWT_BYTES    131072ull

#define SLOT 18432                  // shorts per ring slot (X 2048 | Wg 8192 | Wu 8192)

typedef __attribute__((ext_vector_type(8))) short bf16x8;
typedef __attribute__((ext_vector_type(8))) short short8;
typedef __attribute__((ext_vector_type(4))) float f32x4;

#define VMCNT(n) asm volatile("s_waitcnt vmcnt(" #n ")" ::: "memory")

__device__ __forceinline__ ushort f2bf(float f) {
  union { float f; unsigned u; } c; c.f = f;
  return (ushort)((c.u + 0x7FFFu + ((c.u >> 16) & 1u)) >> 16);
}
__device__ __forceinline__ float bf2f(ushort h) {
  union { unsigned u; float f; } c; c.u = ((unsigned)h) << 16;
  return c.f;
}
__device__ __forceinline__ void gload16(const void* g, void* l) {
  __builtin_amdgcn_global_load_lds(
      (const __attribute__((address_space(1))) void*)g,
      (__attribute__((address_space(3))) void*)l, 16, 0, 0);
}

// ---------------- legacy router (small-ws path) ----------------
__global__ void router_topk(const float* __restrict__ x, const float* __restrict__ rw,
                            const float* __restrict__ bias, int* __restrict__ topk_i,
                            float* __restrict__ topk_p) {
  const int wave = threadIdx.x >> 6;
  const int lane = threadIdx.x & 63;      // lane == expert id (E=64)
  const int n = blockIdx.x * 4 + wave;
  if (n >= N_TOK) return;

  const float4* xr = (const float4*)(x + (size_t)n * D_DIM);
  const float4* wr = (const float4*)(rw + (size_t)lane * D_DIM);
  float acc = 0.f;
  #pragma unroll 4
  for (int d4 = 0; d4 < D_DIM / 4; ++d4) {
    float4 xv = xr[d4]; float4 wv = wr[d4];
    acc += xv.x * wv.x + xv.y * wv.y + xv.z * wv.z + xv.w * wv.w;
  }
  float logit = acc + bias[lane];

  float m = logit;
  for (int off = 32; off > 0; off >>= 1) m = fmaxf(m, __shfl_xor(m, off));
  float p = expf(logit - m);
  float s = p;
  for (int off = 32; off > 0; off >>= 1) s += __shfl_xor(s, off);
  float prob = p / s;

  float myp = prob;
  float gsum = 0.f;
  float myg = 0.f; int myi = -1;
  for (int k = 0; k < K_TOP; ++k) {
    float bp = myp; int bi = lane;
    for (int off = 32; off > 0; off >>= 1) {
      float op = __shfl_xor(bp, off); int oi = __shfl_xor(bi, off);
      if (op > bp || (op == bp && oi < bi)) { bp = op; bi = oi; }
    }
    gsum += bp;
    if (lane == k) { myg = bp; myi = bi; }
    if (lane == bi) myp = -1.f;
  }
  if (lane < K_TOP) {
    topk_i[n * K_TOP + lane] = myi;
    topk_p[n * K_TOP + lane] = myg / (gsum + 1e-9f);
  }
}

// ---------------- fast router: transposed weights, 8 tokens/wave ----------------
__global__ void transpose_rw(const float* __restrict__ rw, float* __restrict__ rwt) {
  int idx = blockIdx.x * 256 + threadIdx.x;
  if (idx >= E_NUM * (D_DIM / 4)) return;
  int e = idx >> 7, k4 = idx & 127;
  float4 v = *(const float4*)(rw + (size_t)e * D_DIM + k4 * 4);
  *(float4*)(rwt + ((size_t)k4 * 64 + e) * 4) = v;
}

__device__ __forceinline__ void softmax_topk_write(float logit, int n, int lane,
                                                   int* __restrict__ topk_i,
                                                   float* __restrict__ topk_p) {
  float m = logit;
  for (int off = 32; off > 0; off >>= 1) m = fmaxf(m, __shfl_xor(m, off));
  float p = expf(logit - m);
  float s = p;
  for (int off = 32; off > 0; off >>= 1) s += __shfl_xor(s, off);
  float prob = p / s;

  float myp = prob;
  float gsum = 0.f;
  float myg = 0.f; int myi = -1;
  #pragma unroll 1
  for (int k = 0; k < K_TOP; ++k) {
    float bp = myp; int bi = lane;
    for (int off = 32; off > 0; off >>= 1) {
      float op = __shfl_xor(bp, off); int oi = __shfl_xor(bi, off);
      if (op > bp || (op == bp && oi < bi)) { bp = op; bi = oi; }
    }
    gsum += bp;
    if (lane == k) { myg = bp; myi = bi; }
    if (lane == bi) myp = -1.f;
  }
  if (lane < K_TOP) {
    topk_i[n * K_TOP + lane] = myi;
    topk_p[n * K_TOP + lane] = myg / (gsum + 1e-9f);
  }
}

__global__ void __launch_bounds__(256) router_topk2(
    const float* __restrict__ x, const float* __restrict__ rwt,
    const float* __restrict__ bias, int* __restrict__ topk_i,
    float* __restrict__ topk_p) {
  const int wave = threadIdx.x >> 6;
  const int lane = threadIdx.x & 63;      // lane == expert id
  const int n0 = blockIdx.x * 32 + wave * 8;

  float acc[8];
  #pragma unroll
  for (int t = 0; t < 8; ++t) acc[t] = 0.f;

  const float4* wv4 = (const float4*)rwt;
  #pragma unroll 2
  for (int k4 = 0; k4 < 128; ++k4) {
    float4 w = wv4[k4 * 64 + lane];
    #pragma unroll
    for (int t = 0; t < 8; ++t) {
      float4 xv = *(const float4*)(x + (size_t)(n0 + t) * D_DIM + k4 * 4);
      acc[t] += xv.x * w.x + xv.y * w.y + xv.z * w.z + xv.w * w.w;
    }
  }
  float b = bias[lane];
  #pragma unroll 1
  for (int t = 0; t < 8; ++t)
    softmax_topk_write(acc[t] + b, n0 + t, lane, topk_i, topk_p);
}

// ---------------- per-chunk expert histogram ----------------
__global__ void hist_kernel(const int* __restrict__ topk_i, int* __restrict__ chunk_hist) {
  __shared__ int h[E_NUM];
  const int tid = threadIdx.x;
  if (tid < E_NUM) h[tid] = 0;
  __syncthreads();
  int e = topk_i[blockIdx.x * 256 + tid];
  atomicAdd(&h[e], 1);
  __syncthreads();
  if (tid < E_NUM) chunk_hist[blockIdx.x * E_NUM + tid] = h[tid];
}

// ---------------- exclusive scan over chunks, per expert ----------------
__global__ void scan_kernel(const int* __restrict__ chunk_hist, int* __restrict__ chunk_base) {
  const int e = threadIdx.x;  // 64 threads
  int run = 0;
  for (int c = 0; c < NCHUNK; ++c) {
    chunk_base[c * E_NUM + e] = run;
    run += chunk_hist[c * E_NUM + e];
  }
}

// ---------------- dispatch: slot = global stable rank within expert ----------------
__global__ void dispatch_kernel(const int* __restrict__ topk_i, const float* __restrict__ topk_p,
                                const int* __restrict__ chunk_base,
                                int* __restrict__ expert_tok, float* __restrict__ expert_gate,
                                int* __restrict__ entry_row) {
  __shared__ int eid[256];
  const int tid = threadIdx.x;
  const int m = blockIdx.x * 256 + tid;
  const int e = topk_i[m];
  eid[tid] = e;
  __syncthreads();
  int rank = 0;
  for (int t = 0; t < tid; ++t) rank += (eid[t] == e);
  int slot = chunk_base[blockIdx.x * E_NUM + e] + rank;
  int row = -1;
  if (slot < CAP) {
    expert_tok[e * CAP + slot] = m / K_TOP;
    expert_gate[e * CAP + slot] = topk_p[m];
    row = e * CAP + slot;
  }
  if (entry_row) entry_row[m] = row;
}

// ================= FAST PATH =================

// x fp32 -> bf16 row-major
__global__ void convert_x(const float* __restrict__ x, ushort* __restrict__ xb) {
  size_t idx = (size_t)blockIdx.x * 256 + threadIdx.x;
  const float4* s4 = (const float4*)(x + idx * 8);
  float4 v0 = s4[0], v1 = s4[1];
  short8 o;
  o[0] = f2bf(v0.x); o[1] = f2bf(v0.y); o[2] = f2bf(v0.z); o[3] = f2bf(v0.w);
  o[4] = f2bf(v1.x); o[5] = f2bf(v1.y); o[6] = f2bf(v1.z); o[7] = f2bf(v1.w);
  *(short8*)(xb + idx * 8) = o;
}

// weights fp32 -> bf16, pre-tiled fragment layout.
// DEST-LINEAR version: iterate destination linearly (contiguous 16B writes per lane),
// gather-read source (4-lane groups cover full 128B source lines).
// blockIdx.x = e*12 + p*4 + q  (p: 0 gate / 1 up / 2 down; q = quarter of the blob)
__global__ void convert_w(const float* __restrict__ wg_, const float* __restrict__ wu_,
                          const float* __restrict__ wd_, const float* __restrict__ swg,
                          const float* __restrict__ swu, const float* __restrict__ swd,
                          ushort* __restrict__ Wt) {
  int e = blockIdx.x / 12;
  int rem = blockIdx.x - e * 12;
  int p = rem >> 2, q = rem & 3;
  const float* src;
  if (p == 0)      src = (e < E_NUM) ? wg_ + (size_t)e * 131072 : swg + (size_t)(e - E_NUM) * 131072;
  else if (p == 1) src = (e < E_NUM) ? wu_ + (size_t)e * 131072 : swu + (size_t)(e - E_NUM) * 131072;
  else             src = (e < E_NUM) ? wd_ + (size_t)e * 131072 : swd + (size_t)(e - E_NUM) * 131072;
  ushort* dst = Wt + (size_t)e * EW_STRIDE + (size_t)p * 131072;
  #pragma unroll
  for (int i = 0; i < 16; ++i) {
    int d = q * 32768 + i * 2048 + threadIdx.x * 8;   // dest short index, 8-aligned
    int ci = d >> 13;                 // chunk (8192 shorts)
    int r  = d & 8191;
    int nt = r >> 9;                  // subtile (512 shorts)
    int rr = r & 511;
    int k8 = rr >> 7;                 // 0..3
    int n  = nt * 16 + ((rr >> 3) & 15);
    size_t srcidx;
    if (p < 2) {
      srcidx = (size_t)n * 512 + ci * 32 + k8 * 8;
    } else {
      int np = ci >> 3, kc = ci & 7;
      srcidx = (size_t)(np * 256 + n) * 256 + kc * 32 + k8 * 8;
    }
    const float4* s4 = (const float4*)(src + srcidx);
    float4 v0 = s4[0], v1 = s4[1];
    short8 o;
    o[0] = f2bf(v0.x); o[1] = f2bf(v0.y); o[2] = f2bf(v0.z); o[3] = f2bf(v0.w);
    o[4] = f2bf(v1.x); o[5] = f2bf(v1.y); o[6] = f2bf(v1.z); o[7] = f2bf(v1.w);
    *(short8*)(dst + d) = o;
  }
}

// fill token lists for the two shared experts: every token, gate = 0.5
__global__ void init_shared_tok(int* __restrict__ tok_all, float* __restrict__ gate_all) {
  int i = blockIdx.x * 256 + threadIdx.x;
  tok_all[TOK_ROUTED + i] = i & (N_TOK - 1);
  gate_all[TOK_ROUTED + i] = 0.5f;
}

// Unified FFN: 64-token tile x one expert, 512 threads (8 waves, 2 row x 4 col),
// fused gate+up, 3-slot ring with counted vmcnt.
// XCD-aware decode: all tiles of expert e run on XCD (e&7), expert-major order,
// so concurrent blocks on an XCD share ~2 experts' weights (fits 4MB L2).
// Grid MUST be 1792 = 8 * 224.
template <bool GATHER>
__global__ void __launch_bounds__(512, 1) ffn_mfma(
    const ushort* __restrict__ xb, const ushort* __restrict__ Wt,
    const int* __restrict__ tok_all, const float* __restrict__ gate_all,
    float* __restrict__ out, ushort* __restrict__ expert_out) {
  int e, tbase;
  {
    int xcd = blockIdx.x & 7;        // HW round-robin blockIdx -> XCD
    int j = blockIdx.x >> 3;         // 0..223 within this XCD class
    if (j < 192) {                   // routed: 8 experts x 24 tiles per class
      int ec = j / 24;
      int mt = j - ec * 24;
      e = ec * 8 + xcd;
      tbase = e * CAP + mt * 64;
      if (tok_all[tbase] < 0) return;   // contiguous fill -> empty tile
    } else {                         // shared: 32 tiles per class
      int s = xcd * 32 + (j - 192);  // 0..255
      int sh = s & 1, mt = s >> 1;
      e = E_NUM + sh;
      tbase = TOK_ROUTED + sh * N_TOK + mt * 64;
    }
  }
  const ushort* wbase = Wt + (size_t)e * EW_STRIDE;

  __shared__ ushort RING[3 * SLOT];   // 108 KB: per slot X[2048] Wg[8192] Wu[8192]
  __shared__ ushort Act[16384];       // 32 KB: 64tok x 256f, fragment-tiled
  __shared__ int   toks[64];
  __shared__ float gts[64];

  const int tid = threadIdx.x;
  const int lane = tid & 63;
  const int wid = tid >> 6;        // 0..7
  const int wr = wid >> 2;         // 0..1  (row half: 32 tokens)
  const int wc = wid & 3;          // 0..3  (col quarter)
  const int rl = lane & 15;
  const int hi = lane >> 4;

  if (tid < 64) {
    int t = tok_all[tbase + tid];
    toks[tid] = t;
    gts[tid] = (t >= 0) ? gate_all[tbase + tid] : 0.f;
  }
  __syncthreads();

  // waves 0-3 stage the X tile (subtile = wid): per-lane source row
  int stok = 0;
  if (wid < 4) { int t = toks[wid * 16 + rl]; stok = (t < 0) ? 0 : t; }
  const ushort* xsrc = xb + (size_t)stok * D_DIM + hi * 8;

  auto stage_gu = [&](int sl, int kc) {
    ushort* dst = RING + sl * SLOT;
    if (wid < 4)
      gload16(xsrc + kc * 32, dst + wid * 512);
    #pragma unroll
    for (int i = 0; i < 2; ++i) {
      int s = wid * 2 + i;
      gload16(wbase + kc * 8192 + s * 512 + lane * 8, dst + 2048 + s * 512);
      gload16(wbase + 131072 + kc * 8192 + s * 512 + lane * 8, dst + 10240 + s * 512);
    }
  };
  auto stage_dn = [&](int sl, int kc) {
    ushort* dst = RING + sl * SLOT;
    #pragma unroll
    for (int i = 0; i < 4; ++i) {
      int s = wid * 4 + i;
      gload16(wbase + 262144 + (s >> 4) * 65536 + kc * 8192 + (s & 15) * 512 + lane * 8,
              dst + s * 512);
    }
  };

  const f32x4 fzero = {0.f, 0.f, 0.f, 0.f};
  f32x4 accg[2][4], accu[2][4];
  #pragma unroll
  for (int ri = 0; ri < 2; ++ri)
    #pragma unroll
    for (int bi = 0; bi < 4; ++bi) { accg[ri][bi] = fzero; accu[ri][bi] = fzero; }

  // ---- fused gate+up: 16 K-steps of 32 ----
  stage_gu(0, 0); stage_gu(1, 1);
  {
    int sl_c = 0, sl_n = 2;
    #pragma unroll 1
    for (int kc = 0; kc < 16; ++kc) {
      if (kc < 14) { stage_gu(sl_n, kc + 2); sl_n = (sl_n == 2) ? 0 : sl_n + 1; }
      if (kc < 14)      { if (wid < 4) VMCNT(10); else VMCNT(8); }
      else if (kc == 14){ if (wid < 4) VMCNT(5);  else VMCNT(4); }
      else              VMCNT(0);
      __builtin_amdgcn_s_barrier();
      __builtin_amdgcn_sched_barrier(0);
      {
        const ushort* base = RING + sl_c * SLOT;
        bf16x8 a[2], bg[4], bu[4];
        #pragma unroll
        for (int ri = 0; ri < 2; ++ri)
          a[ri] = *(const bf16x8*)(base + (wr * 2 + ri) * 512 + lane * 8);
        #pragma unroll
        for (int bi = 0; bi < 4; ++bi) {
          bg[bi] = *(const bf16x8*)(base + 2048 + (wc * 4 + bi) * 512 + lane * 8);
          bu[bi] = *(const bf16x8*)(base + 10240 + (wc * 4 + bi) * 512 + lane * 8);
        }
        __builtin_amdgcn_s_setprio(1);
        #pragma unroll
        for (int ri = 0; ri < 2; ++ri)
          #pragma unroll
          for (int bi = 0; bi < 4; ++bi) {
            accg[ri][bi] = __builtin_amdgcn_mfma_f32_16x16x32_bf16(a[ri], bg[bi], accg[ri][bi], 0, 0, 0);
            accu[ri][bi] = __builtin_amdgcn_mfma_f32_16x16x32_bf16(a[ri], bu[bi], accu[ri][bi], 0, 0, 0);
          }
        __builtin_amdgcn_s_setprio(0);
      }
      sl_c = (sl_c == 2) ? 0 : sl_c + 1;
      __builtin_amdgcn_s_barrier();
    }
  }

  // ---- silu(g)*u in-register -> Act (fragment-tiled bf16) ----
  #pragma unroll
  for (int ri = 0; ri < 2; ++ri)
    #pragma unroll
    for (int bi = 0; bi < 4; ++bi) {
      int st = (wr * 2 + ri) * 8 + wc * 2 + (bi >> 1);
      int base = st * 512 + ((bi & 1) * 2 + (rl >> 3)) * 128 + (rl & 7);
      #pragma unroll
      for (int j = 0; j < 4; ++j) {
        float g = accg[ri][bi][j], u = accu[ri][bi][j];
        Act[base + (hi * 4 + j) * 8] = f2bf(g / (1.f + __expf(-g)) * u);
      }
    }

  // ---- down: out[64 x 512], 8 K-steps of 32 over F ----
  f32x4 accd[2][8];
  #pragma unroll
  for (int ri = 0; ri < 2; ++ri)
    #pragma unroll
    for (int bj = 0; bj < 8; ++bj) accd[ri][bj] = fzero;

  stage_dn(0, 0); stage_dn(1, 1);
  asm volatile("s_waitcnt lgkmcnt(0)" ::: "memory");
  __builtin_amdgcn_s_barrier();
  __builtin_amdgcn_sched_barrier(0);
  {
    int sl_c = 0, sl_n = 2;
    #pragma unroll 1
    for (int kc = 0; kc < 8; ++kc) {
      if (kc < 6) { stage_dn(sl_n, kc + 2); sl_n = (sl_n == 2) ? 0 : sl_n + 1; }
      if (kc < 6)       VMCNT(8);
      else if (kc == 6) VMCNT(4);
      else              VMCNT(0);
      __builtin_amdgcn_s_barrier();
      __builtin_amdgcn_sched_barrier(0);
      {
        const ushort* base = RING + sl_c * SLOT;
        bf16x8 a[2], b[8];
        #pragma unroll
        for (int ri = 0; ri < 2; ++ri)
          a[ri] = *(const bf16x8*)(Act + ((wr * 2 + ri) * 8 + kc) * 512 + lane * 8);
        #pragma unroll
        for (int bj = 0; bj < 8; ++bj)
          b[bj] = *(const bf16x8*)(base + (wc * 8 + bj) * 512 + lane * 8);
        __builtin_amdgcn_s_setprio(1);
        #pragma unroll
        for (int ri = 0; ri < 2; ++ri)
          #pragma unroll
          for (int bj = 0; bj < 8; ++bj)
            accd[ri][bj] = __builtin_amdgcn_mfma_f32_16x16x32_bf16(a[ri], b[bj], accd[ri][bj], 0, 0, 0);
        __builtin_amdgcn_s_setprio(0);
      }
      sl_c = (sl_c == 2) ? 0 : sl_c + 1;
      __builtin_amdgcn_s_barrier();
    }
  }

  // ---- epilogue ----
  if (GATHER) {
    #pragma unroll
    for (int ri = 0; ri < 2; ++ri)
      #pragma unroll
      for (int j = 0; j < 4; ++j) {
        int r = wr * 32 + ri * 16 + hi * 4 + j;
        if (toks[r] < 0) continue;
        ushort* erow = expert_out + (size_t)(tbase + r) * D_DIM + wc * 128 + rl;
        #pragma unroll
        for (int bj = 0; bj < 8; ++bj)
          erow[bj * 16] = f2bf(accd[ri][bj][j]);
      }
  } else {
    #pragma unroll
    for (int ri = 0; ri < 2; ++ri)
      #pragma unroll
      for (int j = 0; j < 4; ++j) {
        int r = wr * 32 + ri * 16 + hi * 4 + j;
        int t = toks[r];
        if (t < 0) continue;
        float gt = gts[r];
        float* orow = out + (size_t)t * D_DIM + wc * 128 + rl;
        #pragma unroll
        for (int bj = 0; bj < 8; ++bj)
          atomicAdd(orow + bj * 16, gt * accd[ri][bj][j]);
      }
  }
}

// ---------------- gather combine: one wave per token ----------------
__global__ void __launch_bounds__(256) gather_out(
    const ushort* __restrict__ eo, const int* __restrict__ entry_row,
    const float* __restrict__ topk_p, float* __restrict__ out) {
  const int t = blockIdx.x * 4 + (threadIdx.x >> 6);
  const int lane = threadIdx.x & 63;
  const int base = t * K_TOP;

  float acc[8];
  #pragma unroll
  for (int j = 0; j < 8; ++j) acc[j] = 0.f;

  #pragma unroll
  for (int k = 0; k < K_TOP; ++k) {
    int row = entry_row[base + k];
    if (row >= 0) {
      float g = topk_p[base + k];
      bf16x8 v = *(const bf16x8*)(eo + (size_t)row * D_DIM + lane * 8);
      #pragma unroll
      for (int j = 0; j < 8; ++j) acc[j] += g * bf2f((ushort)v[j]);
    }
  }
  #pragma unroll
  for (int sh = 0; sh < SH_NUM; ++sh) {
    int row = TOK_ROUTED + sh * N_TOK + t;
    bf16x8 v = *(const bf16x8*)(eo + (size_t)row * D_DIM + lane * 8);
    #pragma unroll
    for (int j = 0; j < 8; ++j) acc[j] += 0.5f * bf2f((ushort)v[j]);
  }
  float4* o = (float4*)(out + (size_t)t * D_DIM + lane * 8);
  o[0] = make_float4(acc[0], acc[1], acc[2], acc[3]);
  o[1] = make_float4(acc[4], acc[5], acc[6], acc[7]);
}

// ================= LEGACY PATH (round-2, used when ws tiny) =================

__global__ void __launch_bounds__(256, 2) expert_ffn_mfma(
    const float* __restrict__ x, const float* __restrict__ wg_,
    const float* __restrict__ wu_, const float* __restrict__ wd_,
    const int* __restrict__ expert_tok, const float* __restrict__ expert_gate,
    float* __restrict__ out) {
  const int e = blockIdx.x & (E_NUM - 1);
  const int mt = blockIdx.x >> 6;
  const int s0 = mt * 64;
  if (expert_tok[e * CAP + s0] < 0) return;

  __shared__ ushort Xs[64][72];
  __shared__ ushort Ws[256][72];
  __shared__ ushort Act[64][264];
  __shared__ int   toks[64];
  __shared__ float gts[64];

  const int tid = threadIdx.x;
  const int lane = tid & 63;
  const int wid = tid >> 6;
  const int rl = lane & 15;
  const int ko = (lane >> 4) * 8;
  const int rquad = (lane >> 4) * 4;

  if (tid < 64) {
    int t = expert_tok[e * CAP + s0 + tid];
    toks[tid] = t;
    gts[tid] = (t >= 0) ? expert_gate[e * CAP + s0 + tid] : 0.f;
  }
  __syncthreads();

  float4 px[4], pw[16];

  auto loadX = [&](int kb) {
    #pragma unroll
    for (int it = 0; it < 4; ++it) {
      int idx = tid + it * 256;
      int row = idx >> 4, c4 = (idx & 15) << 2;
      int t = toks[row];
      px[it] = (t >= 0) ? *(const float4*)(x + (size_t)t * D_DIM + kb * 64 + c4)
                        : make_float4(0.f, 0.f, 0.f, 0.f);
    }
  };
  auto writeX = [&]() {
    #pragma unroll
    for (int it = 0; it < 4; ++it) {
      int idx = tid + it * 256;
      int row = idx >> 4, c4 = (idx & 15) << 2;
      ushort4 h; h.x = f2bf(px[it].x); h.y = f2bf(px[it].y);
      h.z = f2bf(px[it].z); h.w = f2bf(px[it].w);
      *(ushort4*)&Xs[row][c4] = h;
    }
  };
  auto loadW = [&](const float* src, int ldk, int kb) {
    #pragma unroll
    for (int it = 0; it < 16; ++it) {
      int idx = tid + it * 256;
      int row = idx >> 4, c4 = (idx & 15) << 2;
      pw[it] = *(const float4*)(src + (size_t)row * ldk + kb * 64 + c4);
    }
  };
  auto writeW = [&]() {
    #pragma unroll
    for (int it = 0; it < 16; ++it) {
      int idx = tid + it * 256;
      int row = idx >> 4, c4 = (idx & 15) << 2;
      ushort4 h; h.x = f2bf(pw[it].x); h.y = f2bf(pw[it].y);
      h.z = f2bf(pw[it].z); h.w = f2bf(pw[it].w);
      *(ushort4*)&Ws[row][c4] = h;
    }
  };
  auto compute = [&](const ushort* Ab, int lda, f32x4 (&acc)[4][4]) {
    #pragma unroll
    for (int kk = 0; kk < 2; ++kk) {
      bf16x8 a[4], b[4];
      #pragma unroll
      for (int ri = 0; ri < 4; ++ri)
        a[ri] = *(const bf16x8*)(Ab + (size_t)(ri * 16 + rl) * lda + kk * 32 + ko);
      #pragma unroll
      for (int bi = 0; bi < 4; ++bi)
        b[bi] = *(const bf16x8*)(&Ws[wid * 64 + bi * 16 + rl][kk * 32 + ko]);
      #pragma unroll
      for (int ri = 0; ri < 4; ++ri)
        #pragma unroll
        for (int bi = 0; bi < 4; ++bi)
          acc[ri][bi] = __builtin_amdgcn_mfma_f32_16x16x32_bf16(a[ri], b[bi], acc[ri][bi], 0, 0, 0);
    }
  };

  const f32x4 fzero = {0.f, 0.f, 0.f, 0.f};

  #pragma unroll 1
  for (int which = 0; which < 2; ++which) {
    const float* wsrc = (which == 0 ? wg_ : wu_) + (size_t)e * F_DIM * D_DIM;
    f32x4 acc[4][4];
    #pragma unroll
    for (int ri = 0; ri < 4; ++ri)
      #pragma unroll
      for (int bi = 0; bi < 4; ++bi) acc[ri][bi] = fzero;

    loadX(0); loadW(wsrc, D_DIM, 0);
    writeX(); writeW();
    __syncthreads();
    for (int kb = 0; kb < 8; ++kb) {
      if (kb < 7) { loadX(kb + 1); loadW(wsrc, D_DIM, kb + 1); }
      compute(&Xs[0][0], 72, acc);
      __syncthreads();
      if (kb < 7) { writeX(); writeW(); __syncthreads(); }
    }
    #pragma unroll
    for (int ri = 0; ri < 4; ++ri)
      #pragma unroll
      for (int bi = 0; bi < 4; ++bi)
        #pragma unroll
        for (int j = 0; j < 4; ++j) {
          int r = ri * 16 + rquad + j;
          int c = wid * 64 + bi * 16 + rl;
          if (which == 0) {
            Act[r][c] = f2bf(acc[ri][bi][j]);
          } else {
            float hg = bf2f(Act[r][c]);
            float a = hg / (1.f + __expf(-hg)) * acc[ri][bi][j];
            Act[r][c] = f2bf(a);
          }
        }
    __syncthreads();
  }

  #pragma unroll 1
  for (int np = 0; np < 2; ++np) {
    const float* wsrc = wd_ + ((size_t)e * D_DIM + np * 256) * F_DIM;
    f32x4 acc[4][4];
    #pragma unroll
    for (int ri = 0; ri < 4; ++ri)
      #pragma unroll
      for (int bi = 0; bi < 4; ++bi) acc[ri][bi] = fzero;

    loadW(wsrc, F_DIM, 0); writeW();
    __syncthreads();
    for (int kb = 0; kb < 4; ++kb) {
      if (kb < 3) loadW(wsrc, F_DIM, kb + 1);
      compute(&Act[0][kb * 64], 264, acc);
      __syncthreads();
      if (kb < 3) { writeW(); __syncthreads(); }
    }
    #pragma unroll
    for (int ri = 0; ri < 4; ++ri)
      #pragma unroll
      for (int bi = 0; bi < 4; ++bi)
        #pragma unroll
        for (int j = 0; j < 4; ++j) {
          int r = ri * 16 + rquad + j;
          int t = toks[r];
          if (t >= 0) {
            int c = np * 256 + wid * 64 + bi * 16 + rl;
            atomicAdd(out + (size_t)t * D_DIM + c, gts[r] * acc[ri][bi][j]);
          }
        }
  }
}

__global__ void __launch_bounds__(256, 2) shared_ffn_mfma(
    const float* __restrict__ x, const float* __restrict__ swg,
    const float* __restrict__ swu, const float* __restrict__ swd,
    float* __restrict__ out) {
  const int row0 = blockIdx.x * 32;

  __shared__ ushort Xs[32][72];
  __shared__ ushort Ws[256][72];
  __shared__ ushort Act[32][264];

  const int tid = threadIdx.x;
  const int lane = tid & 63;
  const int wid = tid >> 6;
  const int rl = lane & 15;
  const int ko = (lane >> 4) * 8;
  const int rquad = (lane >> 4) * 4;

  float4 px[2], pw[16];

  auto loadX = [&](int kb) {
    #pragma unroll
    for (int it = 0; it < 2; ++it) {
      int idx = tid + it * 256;
      int row = idx >> 4, c4 = (idx & 15) << 2;
      px[it] = *(const float4*)(x + (size_t)(row0 + row) * D_DIM + kb * 64 + c4);
    }
  };
  auto writeX = [&]() {
    #pragma unroll
    for (int it = 0; it < 2; ++it) {
      int idx = tid + it * 256;
      int row = idx >> 4, c4 = (idx & 15) << 2;
      ushort4 h; h.x = f2bf(px[it].x); h.y = f2bf(px[it].y);
      h.z = f2bf(px[it].z); h.w = f2bf(px[it].w);
      *(ushort4*)&Xs[row][c4] = h;
    }
  };
  auto loadW = [&](const float* src, int ldk, int kb) {
    #pragma unroll
    for (int it = 0; it < 16; ++it) {
      int idx = tid + it * 256;
      int row = idx >> 4, c4 = (idx & 15) << 2;
      pw[it] = *(const float4*)(src + (size_t)row * ldk + kb * 64 + c4);
    }
  };
  auto writeW = [&]() {
    #pragma unroll
    for (int it = 0; it < 16; ++it) {
      int idx = tid + it * 256;
      int row = idx >> 4, c4 = (idx & 15) << 2;
      ushort4 h; h.x = f2bf(pw[it].x); h.y = f2bf(pw[it].y);
      h.z = f2bf(pw[it].z); h.w = f2bf(pw[it].w);
      *(ushort4*)&Ws[row][c4] = h;
    }
  };
  auto compute = [&](const ushort* Ab, int lda, f32x4 (&acc)[2][4]) {
    #pragma unroll
    for (int kk = 0; kk < 2; ++kk) {
      bf16x8 a[2], b[4];
      #pragma unroll
      for (int ri = 0; ri < 2; ++ri)
        a[ri] = *(const bf16x8*)(Ab + (size_t)(ri * 16 + rl) * lda + kk * 32 + ko);
      #pragma unroll
      for (int bi = 0; bi < 4; ++bi)
        b[bi] = *(const bf16x8*)(&Ws[wid * 64 + bi * 16 + rl][kk * 32 + ko]);
      #pragma unroll
      for (int ri = 0; ri < 2; ++ri)
        #pragma unroll
        for (int bi = 0; bi < 4; ++bi)
          acc[ri][bi] = __builtin_amdgcn_mfma_f32_16x16x32_bf16(a[ri], b[bi], acc[ri][bi], 0, 0, 0);
    }
  };

  const f32x4 fzero = {0.f, 0.f, 0.f, 0.f};
  f32x4 accd[2][2][4];
  #pragma unroll
  for (int np = 0; np < 2; ++np)
    #pragma unroll
    for (int ri = 0; ri < 2; ++ri)
      #pragma unroll
      for (int bi = 0; bi < 4; ++bi) accd[np][ri][bi] = fzero;

  #pragma unroll 1
  for (int sh = 0; sh < SH_NUM; ++sh) {
    #pragma unroll 1
    for (int which = 0; which < 2; ++which) {
      const float* wsrc = (which == 0 ? swg : swu) + (size_t)sh * F_DIM * D_DIM;
      f32x4 acc[2][4];
      #pragma unroll
      for (int ri = 0; ri < 2; ++ri)
        #pragma unroll
        for (int bi = 0; bi < 4; ++bi) acc[ri][bi] = fzero;

      loadX(0); loadW(wsrc, D_DIM, 0);
      writeX(); writeW();
      __syncthreads();
      for (int kb = 0; kb < 8; ++kb) {
        if (kb < 7) { loadX(kb + 1); loadW(wsrc, D_DIM, kb + 1); }
        compute(&Xs[0][0], 72, acc);
        __syncthreads();
        if (kb < 7) { writeX(); writeW(); __syncthreads(); }
      }
      #pragma unroll
      for (int ri = 0; ri < 2; ++ri)
        #pragma unroll
        for (int bi = 0; bi < 4; ++bi)
          #pragma unroll
          for (int j = 0; j < 4; ++j) {
            int r = ri * 16 + rquad + j;
            int c = wid * 64 + bi * 16 + rl;
            if (which == 0) {
              Act[r][c] = f2bf(acc[ri][bi][j]);
            } else {
              float hg = bf2f(Act[r][c]);
              float a = hg / (1.f + __expf(-hg)) * acc[ri][bi][j];
              Act[r][c] = f2bf(a);
            }
          }
      __syncthreads();
    }
    #pragma unroll
    for (int np = 0; np < 2; ++np) {
      const float* wsrc = swd + ((size_t)sh * D_DIM + np * 256) * F_DIM;
      loadW(wsrc, F_DIM, 0); writeW();
      __syncthreads();
      for (int kb = 0; kb < 4; ++kb) {
        if (kb < 3) loadW(wsrc, F_DIM, kb + 1);
        compute(&Act[0][kb * 64], 264, accd[np]);
        __syncthreads();
        if (kb < 3) { writeW(); __syncthreads(); }
      }
    }
  }

  #pragma unroll
  for (int np = 0; np < 2; ++np)
    #pragma unroll
    for (int ri = 0; ri < 2; ++ri)
      #pragma unroll
      for (int bi = 0; bi < 4; ++bi)
        #pragma unroll
        for (int j = 0; j < 4; ++j) {
          int r = ri * 16 + rquad + j;
          int c = np * 256 + wid * 64 + bi * 16 + rl;
          out[(size_t)(row0 + r) * D_DIM + c] = 0.5f * accd[np][ri][bi][j];
        }
}

extern "C" void kernel_launch(void* const* d_in, const int* in_sizes, int n_in,
                              void* d_out, int out_size, void* d_ws, size_t ws_size,
                              hipStream_t stream) {
  const float* x    = (const float*)d_in[0];
  const float* rw   = (const float*)d_in[1];
  const float* bias = (const float*)d_in[2];
  const float* swg  = (const float*)d_in[3];
  const float* swu  = (const float*)d_in[4];
  const float* swd  = (const float*)d_in[5];
  const float* wg   = (const float*)d_in[6];
  const float* wu   = (const float*)d_in[7];
  const float* wd   = (const float*)d_in[8];
  float* out = (float*)d_out;

  const size_t small = 2 * (size_t)M_ENT * 4 + (size_t)M_ENT * 4 +
                       2 * (size_t)NCHUNK * E_NUM * 4 + 2 * (size_t)TOK_TOTAL * 4 +
                       RWT_BYTES;
  const size_t need_mid = X_BF_BYTES + WT_BYTES + small;
  const size_t need_big = need_mid + EO_BYTES;

  if (ws_size >= need_mid) {
    const bool gather = (ws_size >= need_big);
    char* ws = (char*)d_ws;
    ushort* x_bf     = (ushort*)ws; ws += X_BF_BYTES;
    ushort* Wt       = (ushort*)ws; ws += WT_BYTES;
    int*   topk_i    = (int*)ws;    ws += (size_t)M_ENT * 4;
    float* topk_p    = (float*)ws;  ws += (size_t)M_ENT * 4;
    int*   entry_row = (int*)ws;    ws += (size_t)M_ENT * 4;
    int*   chunk_hist= (int*)ws;    ws += (size_t)NCHUNK * E_NUM * 4;
    int*   chunk_base= (int*)ws;    ws += (size_t)NCHUNK * E_NUM * 4;
    int*   tok_all   = (int*)ws;    ws += (size_t)TOK_TOTAL * 4;
    float* gate_all  = (float*)ws;  ws += (size_t)TOK_TOTAL * 4;
    float* rwt       = (float*)ws;  ws += RWT_BYTES;
    ushort* eo       = (ushort*)ws; // only valid if gather

    transpose_rw<<<32, 256, 0, stream>>>(rw, rwt);
    convert_x<<<2048, 256, 0, stream>>>(x, x_bf);
    convert_w<<<E_TOT * 12, 256, 0, stream>>>(wg, wu, wd, swg, swu, swd, Wt);
    router_topk2<<<256, 256, 0, stream>>>(x, rwt, bias, topk_i, topk_p);
    hipMemsetAsync(tok_all, 0xFF, (size_t)TOK_ROUTED * 4, stream);
    if (!gather) hipMemsetAsync(out, 0, (size_t)out_size * 4, stream);
    hist_kernel<<<NCHUNK, 256, 0, stream>>>(topk_i, chunk_hist);
    scan_kernel<<<1, 64, 0, stream>>>(chunk_hist, chunk_base);
    dispatch_kernel<<<NCHUNK, 256, 0, stream>>>(topk_i, topk_p, chunk_base, tok_all,
                                                gate_all, entry_row);
    init_shared_tok<<<64, 256, 0, stream>>>(tok_all, gate_all);
    const int nblk = 2 * (N_TOK / 64) + (CAP / 64) * E_NUM;   // 1792 = 8*224
    if (gather) {
      ffn_mfma<true><<<nblk, 512, 0, stream>>>(x_bf, Wt, tok_all, gate_all, out, eo);
      gather_out<<<N_TOK / 4, 256, 0, stream>>>(eo, entry_row, topk_p, out);
    } else {
      ffn_mfma<false><<<nblk, 512, 0, stream>>>(x_bf, Wt, tok_all, gate_all, out, nullptr);
    }
  } else {
    char* ws = (char*)d_ws;
    int*   topk_i      = (int*)ws;   ws += (size_t)M_ENT * 4;
    float* topk_p      = (float*)ws; ws += (size_t)M_ENT * 4;
    int*   chunk_hist  = (int*)ws;   ws += (size_t)NCHUNK * E_NUM * 4;
    int*   chunk_base  = (int*)ws;   ws += (size_t)NCHUNK * E_NUM * 4;
    int*   expert_tok  = (int*)ws;   ws += (size_t)E_NUM * CAP * 4;
    float* expert_gate = (float*)ws; ws += (size_t)E_NUM * CAP * 4;

    router_topk<<<N_TOK / 4, 256, 0, stream>>>(x, rw, bias, topk_i, topk_p);
    hipMemsetAsync(expert_tok, 0xFF, (size_t)E_NUM * CAP * 4, stream);
    hist_kernel<<<NCHUNK, 256, 0, stream>>>(topk_i, chunk_hist);
    scan_kernel<<<1, 64, 0, stream>>>(chunk_hist, chunk_base);
    dispatch_kernel<<<NCHUNK, 256, 0, stream>>>(topk_i, topk_p, chunk_base, expert_tok,
                                                expert_gate, nullptr);
    shared_ffn_mfma<<<N_TOK / 32, 256, 0, stream>>>(x, swg, swu, swd, out);
    expert_ffn_mfma<<<(CAP / 64) * E_NUM, 256, 0, stream>>>(x, wg, wu, wd, expert_tok,
                                                            expert_gate, out);
  }
}

// Round 10
// 262.109 us; speedup vs baseline: 7.7669x; 1.0828x over previous
//
#include <hip/hip_runtime.h>
#include <hip/hip_bf16.h>
#include <math.h>

#define N_TOK 8192
#define D_DIM 512
#define F_DIM 256
#define E_NUM 64
#define SH_NUM 2
#define K_TOP 6
#define CAP   1536
#define M_ENT (N_TOK * K_TOP)   // 49152
#define NCHUNK (M_ENT / 256)    // 192

#define EW_STRIDE 393216            // shorts per expert blob (48 chunks x 8192)
#define E_TOT (E_NUM + SH_NUM)      // 66
#define X_BF_BYTES   (8388608ull)
#define WT_BYTES     ((size_t)E_TOT * EW_STRIDE * 2)
#define TOK_ROUTED   (E_NUM * CAP)                   // 98304
#define TOK_TOTAL    (TOK_ROUTED + SH_NUM * N_TOK)   // 114688
#define EO_BYTES     ((size_t)TOK_TOTAL * D_DIM * 2)
#define RWT_BYTES    131072ull

// ffn v3: BM=128 tile. slot = X[0,4096) | Wg[4096,12288) | Wu[12288,20480) shorts
#define SLOT 20480

typedef __attribute__((ext_vector_type(8))) short bf16x8;
typedef __attribute__((ext_vector_type(8))) short short8;
typedef __attribute__((ext_vector_type(4))) float f32x4;

#define VMCNT(n) asm volatile("s_waitcnt vmcnt(" #n ")" ::: "memory")

__device__ __forceinline__ ushort f2bf(float f) {
  union { float f; unsigned u; } c; c.f = f;
  return (ushort)((c.u + 0x7FFFu + ((c.u >> 16) & 1u)) >> 16);
}
__device__ __forceinline__ float bf2f(ushort h) {
  union { unsigned u; float f; } c; c.u = ((unsigned)h) << 16;
  return c.f;
}
__device__ __forceinline__ void gload16(const void* g, void* l) {
  __builtin_amdgcn_global_load_lds(
      (const __attribute__((address_space(1))) void*)g,
      (__attribute__((address_space(3))) void*)l, 16, 0, 0);
}

// ---------------- legacy router (small-ws path) ----------------
__global__ void router_topk(const float* __restrict__ x, const float* __restrict__ rw,
                            const float* __restrict__ bias, int* __restrict__ topk_i,
                            float* __restrict__ topk_p) {
  const int wave = threadIdx.x >> 6;
  const int lane = threadIdx.x & 63;
  const int n = blockIdx.x * 4 + wave;
  if (n >= N_TOK) return;

  const float4* xr = (const float4*)(x + (size_t)n * D_DIM);
  const float4* wr = (const float4*)(rw + (size_t)lane * D_DIM);
  float acc = 0.f;
  #pragma unroll 4
  for (int d4 = 0; d4 < D_DIM / 4; ++d4) {
    float4 xv = xr[d4]; float4 wv = wr[d4];
    acc += xv.x * wv.x + xv.y * wv.y + xv.z * wv.z + xv.w * wv.w;
  }
  float logit = acc + bias[lane];

  float m = logit;
  for (int off = 32; off > 0; off >>= 1) m = fmaxf(m, __shfl_xor(m, off));
  float p = expf(logit - m);
  float s = p;
  for (int off = 32; off > 0; off >>= 1) s += __shfl_xor(s, off);
  float prob = p / s;

  float myp = prob;
  float gsum = 0.f;
  float myg = 0.f; int myi = -1;
  for (int k = 0; k < K_TOP; ++k) {
    float bp = myp; int bi = lane;
    for (int off = 32; off > 0; off >>= 1) {
      float op = __shfl_xor(bp, off); int oi = __shfl_xor(bi, off);
      if (op > bp || (op == bp && oi < bi)) { bp = op; bi = oi; }
    }
    gsum += bp;
    if (lane == k) { myg = bp; myi = bi; }
    if (lane == bi) myp = -1.f;
  }
  if (lane < K_TOP) {
    topk_i[n * K_TOP + lane] = myi;
    topk_p[n * K_TOP + lane] = myg / (gsum + 1e-9f);
  }
}

__device__ __forceinline__ void softmax_topk_write(float logit, int n, int lane,
                                                   int* __restrict__ topk_i,
                                                   float* __restrict__ topk_p) {
  float m = logit;
  for (int off = 32; off > 0; off >>= 1) m = fmaxf(m, __shfl_xor(m, off));
  float p = expf(logit - m);
  float s = p;
  for (int off = 32; off > 0; off >>= 1) s += __shfl_xor(s, off);
  float prob = p / s;

  float myp = prob;
  float gsum = 0.f;
  float myg = 0.f; int myi = -1;
  #pragma unroll 1
  for (int k = 0; k < K_TOP; ++k) {
    float bp = myp; int bi = lane;
    for (int off = 32; off > 0; off >>= 1) {
      float op = __shfl_xor(bp, off); int oi = __shfl_xor(bi, off);
      if (op > bp || (op == bp && oi < bi)) { bp = op; bi = oi; }
    }
    gsum += bp;
    if (lane == k) { myg = bp; myi = bi; }
    if (lane == bi) myp = -1.f;
  }
  if (lane < K_TOP) {
    topk_i[n * K_TOP + lane] = myi;
    topk_p[n * K_TOP + lane] = myg / (gsum + 1e-9f);
  }
}

__global__ void __launch_bounds__(256) router_topk2(
    const float* __restrict__ x, const float* __restrict__ rwt,
    const float* __restrict__ bias, int* __restrict__ topk_i,
    float* __restrict__ topk_p) {
  const int wave = threadIdx.x >> 6;
  const int lane = threadIdx.x & 63;
  const int n0 = blockIdx.x * 32 + wave * 8;

  float acc[8];
  #pragma unroll
  for (int t = 0; t < 8; ++t) acc[t] = 0.f;

  const float4* wv4 = (const float4*)rwt;
  #pragma unroll 2
  for (int k4 = 0; k4 < 128; ++k4) {
    float4 w = wv4[k4 * 64 + lane];
    #pragma unroll
    for (int t = 0; t < 8; ++t) {
      float4 xv = *(const float4*)(x + (size_t)(n0 + t) * D_DIM + k4 * 4);
      acc[t] += xv.x * w.x + xv.y * w.y + xv.z * w.z + xv.w * w.w;
    }
  }
  float b = bias[lane];
  #pragma unroll 1
  for (int t = 0; t < 8; ++t)
    softmax_topk_write(acc[t] + b, n0 + t, lane, topk_i, topk_p);
}

// ---------------- per-chunk expert histogram ----------------
__global__ void hist_kernel(const int* __restrict__ topk_i, int* __restrict__ chunk_hist) {
  __shared__ int h[E_NUM];
  const int tid = threadIdx.x;
  if (tid < E_NUM) h[tid] = 0;
  __syncthreads();
  int e = topk_i[blockIdx.x * 256 + tid];
  atomicAdd(&h[e], 1);
  __syncthreads();
  if (tid < E_NUM) chunk_hist[blockIdx.x * E_NUM + tid] = h[tid];
}

// ---------------- exclusive scan over chunks, per expert ----------------
__global__ void scan_kernel(const int* __restrict__ chunk_hist, int* __restrict__ chunk_base) {
  const int e = threadIdx.x;
  int run = 0;
  for (int c = 0; c < NCHUNK; ++c) {
    chunk_base[c * E_NUM + e] = run;
    run += chunk_hist[c * E_NUM + e];
  }
}

// ---------------- dispatch: slot = global stable rank within expert ----------------
__global__ void dispatch_kernel(const int* __restrict__ topk_i, const float* __restrict__ topk_p,
                                const int* __restrict__ chunk_base,
                                int* __restrict__ expert_tok, float* __restrict__ expert_gate,
                                int* __restrict__ entry_row) {
  __shared__ int eid[256];
  const int tid = threadIdx.x;
  const int m = blockIdx.x * 256 + tid;
  const int e = topk_i[m];
  eid[tid] = e;
  __syncthreads();
  int rank = 0;
  for (int t = 0; t < tid; ++t) rank += (eid[t] == e);
  int slot = chunk_base[blockIdx.x * E_NUM + e] + rank;
  int row = -1;
  if (slot < CAP) {
    expert_tok[e * CAP + slot] = m / K_TOP;
    expert_gate[e * CAP + slot] = topk_p[m];
    row = e * CAP + slot;
  }
  if (entry_row) entry_row[m] = row;
}

// ================= FAST PATH =================

// merged: x fp32->bf16 (blocks 0..2047), transpose_rw (2048..2079), init_shared (2080..2143)
__global__ void convert_x_misc(const float* __restrict__ x, ushort* __restrict__ xb,
                               const float* __restrict__ rw, float* __restrict__ rwt,
                               int* __restrict__ tok_all, float* __restrict__ gate_all) {
  int b = blockIdx.x;
  if (b < 2048) {
    size_t idx = (size_t)b * 256 + threadIdx.x;
    const float4* s4 = (const float4*)(x + idx * 8);
    float4 v0 = s4[0], v1 = s4[1];
    short8 o;
    o[0] = f2bf(v0.x); o[1] = f2bf(v0.y); o[2] = f2bf(v0.z); o[3] = f2bf(v0.w);
    o[4] = f2bf(v1.x); o[5] = f2bf(v1.y); o[6] = f2bf(v1.z); o[7] = f2bf(v1.w);
    *(short8*)(xb + idx * 8) = o;
  } else if (b < 2080) {
    int idx = (b - 2048) * 256 + threadIdx.x;   // 0..8191 exactly
    int e = idx >> 7, k4 = idx & 127;
    float4 v = *(const float4*)(rw + (size_t)e * D_DIM + k4 * 4);
    *(float4*)(rwt + ((size_t)k4 * 64 + e) * 4) = v;
  } else {
    int i = (b - 2080) * 256 + threadIdx.x;     // 0..16383 exactly
    tok_all[TOK_ROUTED + i] = i & (N_TOK - 1);
    gate_all[TOK_ROUTED + i] = 0.5f;
  }
}

// weights fp32 -> bf16, pre-tiled fragment layout; dest-linear writes.
__global__ void convert_w(const float* __restrict__ wg_, const float* __restrict__ wu_,
                          const float* __restrict__ wd_, const float* __restrict__ swg,
                          const float* __restrict__ swu, const float* __restrict__ swd,
                          ushort* __restrict__ Wt) {
  int e = blockIdx.x / 12;
  int rem = blockIdx.x - e * 12;
  int p = rem >> 2, q = rem & 3;
  const float* src;
  if (p == 0)      src = (e < E_NUM) ? wg_ + (size_t)e * 131072 : swg + (size_t)(e - E_NUM) * 131072;
  else if (p == 1) src = (e < E_NUM) ? wu_ + (size_t)e * 131072 : swu + (size_t)(e - E_NUM) * 131072;
  else             src = (e < E_NUM) ? wd_ + (size_t)e * 131072 : swd + (size_t)(e - E_NUM) * 131072;
  ushort* dst = Wt + (size_t)e * EW_STRIDE + (size_t)p * 131072;
  #pragma unroll
  for (int i = 0; i < 16; ++i) {
    int d = q * 32768 + i * 2048 + threadIdx.x * 8;
    int ci = d >> 13;
    int r  = d & 8191;
    int nt = r >> 9;
    int rr = r & 511;
    int k8 = rr >> 7;
    int n  = nt * 16 + ((rr >> 3) & 15);
    size_t srcidx;
    if (p < 2) {
      srcidx = (size_t)n * 512 + ci * 32 + k8 * 8;
    } else {
      int np = ci >> 3, kc = ci & 7;
      srcidx = (size_t)(np * 256 + n) * 256 + kc * 32 + k8 * 8;
    }
    const float4* s4 = (const float4*)(src + srcidx);
    float4 v0 = s4[0], v1 = s4[1];
    short8 o;
    o[0] = f2bf(v0.x); o[1] = f2bf(v0.y); o[2] = f2bf(v0.z); o[3] = f2bf(v0.w);
    o[4] = f2bf(v1.x); o[5] = f2bf(v1.y); o[6] = f2bf(v1.z); o[7] = f2bf(v1.w);
    *(short8*)(dst + d) = o;
  }
}

// Unified FFN v3: 128-token tile x one expert, 512 threads (8 waves, 2r x 4c; each
// wave owns 64x64 of gate/up and 64x128 of down). Fused gate+up, 2-slot ring with
// distance-1 counted vmcnt (uniform 5 loads/wave/step gate-up, 4 down).
// XCD-aware decode; grid MUST be 896 = 8 * 112.
template <bool GATHER>
__global__ void __launch_bounds__(512, 1) ffn_mfma(
    const ushort* __restrict__ xb, const ushort* __restrict__ Wt,
    const int* __restrict__ tok_all, const float* __restrict__ gate_all,
    float* __restrict__ out, ushort* __restrict__ expert_out) {
  int e, tbase;
  {
    int xcd = blockIdx.x & 7;
    int j = blockIdx.x >> 3;          // 0..111
    if (j < 96) {                     // routed: 8 experts x 12 tiles per class
      int ec = j / 12;
      int mt = j - ec * 12;
      e = ec * 8 + xcd;
      tbase = e * CAP + mt * 128;
      if (tok_all[tbase] < 0) return;
    } else {                          // shared: 16 tiles per class (128 total)
      int s = xcd * 16 + (j - 96);    // 0..127
      int sh = s & 1, mt = s >> 1;    // mt 0..63
      e = E_NUM + sh;
      tbase = TOK_ROUTED + sh * N_TOK + mt * 128;
    }
  }
  const ushort* wbase = Wt + (size_t)e * EW_STRIDE;

  __shared__ ushort RING[2 * SLOT];   // 80 KB
  __shared__ ushort Act[32768];       // 64 KB: subtile st = rt*8+kc, 512 shorts each
  __shared__ int   toks[128];
  __shared__ float gts[128];

  const int tid = threadIdx.x;
  const int lane = tid & 63;
  const int wid = tid >> 6;        // 0..7
  const int wr = wid >> 2;         // 0..1 (row half: 64 tokens)
  const int wc = wid & 3;          // 0..3
  const int rl = lane & 15;
  const int hi = lane >> 4;

  if (tid < 128) {
    int t = tok_all[tbase + tid];
    toks[tid] = t;
    gts[tid] = (t >= 0) ? gate_all[tbase + tid] : 0.f;
  }
  __syncthreads();

  int t0 = toks[wid * 16 + rl];
  const ushort* xsrc = xb + (size_t)(t0 < 0 ? 0 : t0) * D_DIM + hi * 8;

  auto stage_gu = [&](int sl, int kc) {   // 5 loads / wave
    ushort* dst = RING + sl * SLOT;
    gload16(xsrc + kc * 32, dst + wid * 512);                 // X subtile wid
    #pragma unroll
    for (int i = 0; i < 2; ++i) {
      int s = wid * 2 + i;
      gload16(wbase + kc * 8192 + s * 512 + lane * 8, dst + 4096 + s * 512);
      gload16(wbase + 131072 + kc * 8192 + s * 512 + lane * 8, dst + 12288 + s * 512);
    }
  };
  auto stage_dn = [&](int sl, int kc) {   // 4 loads / wave
    ushort* dst = RING + sl * SLOT;
    #pragma unroll
    for (int i = 0; i < 4; ++i) {
      int s = wid * 4 + i;                // np = s>>4, nt = s&15
      gload16(wbase + 262144 + (s >> 4) * 65536 + kc * 8192 + (s & 15) * 512 + lane * 8,
              dst + s * 512);
    }
  };

  const f32x4 fzero = {0.f, 0.f, 0.f, 0.f};
  f32x4 accg[4][4], accu[4][4];           // [ri][bi]
  #pragma unroll
  for (int ri = 0; ri < 4; ++ri)
    #pragma unroll
    for (int bi = 0; bi < 4; ++bi) { accg[ri][bi] = fzero; accu[ri][bi] = fzero; }

  // ---- fused gate+up: 16 K-steps of 32 ----
  stage_gu(0, 0);
  {
    int sl = 0;
    #pragma unroll 1
    for (int kc = 0; kc < 16; ++kc) {
      if (kc < 15) { stage_gu(sl ^ 1, kc + 1); VMCNT(5); }
      else         VMCNT(0);
      __builtin_amdgcn_s_barrier();
      __builtin_amdgcn_sched_barrier(0);
      {
        const ushort* base = RING + sl * SLOT;
        bf16x8 a[4];
        #pragma unroll
        for (int ri = 0; ri < 4; ++ri)
          a[ri] = *(const bf16x8*)(base + (wr * 4 + ri) * 512 + lane * 8);
        __builtin_amdgcn_s_setprio(1);
        #pragma unroll
        for (int bi = 0; bi < 4; ++bi) {
          bf16x8 bg = *(const bf16x8*)(base + 4096 + (wc * 4 + bi) * 512 + lane * 8);
          bf16x8 bu = *(const bf16x8*)(base + 12288 + (wc * 4 + bi) * 512 + lane * 8);
          #pragma unroll
          for (int ri = 0; ri < 4; ++ri) {
            accg[ri][bi] = __builtin_amdgcn_mfma_f32_16x16x32_bf16(a[ri], bg, accg[ri][bi], 0, 0, 0);
            accu[ri][bi] = __builtin_amdgcn_mfma_f32_16x16x32_bf16(a[ri], bu, accu[ri][bi], 0, 0, 0);
          }
        }
        __builtin_amdgcn_s_setprio(0);
      }
      sl ^= 1;
      __builtin_amdgcn_s_barrier();
    }
  }

  // ---- silu(g)*u in-register -> Act (fragment-tiled bf16) ----
  #pragma unroll
  for (int ri = 0; ri < 4; ++ri)
    #pragma unroll
    for (int bi = 0; bi < 4; ++bi) {
      int st = (wr * 4 + ri) * 8 + wc * 2 + (bi >> 1);
      int base = st * 512 + ((bi & 1) * 2 + (rl >> 3)) * 128 + (rl & 7);
      #pragma unroll
      for (int j = 0; j < 4; ++j) {
        float g = accg[ri][bi][j], u = accu[ri][bi][j];
        Act[base + (hi * 4 + j) * 8] = f2bf(g / (1.f + __expf(-g)) * u);
      }
    }
  stage_dn(0, 0);
  __syncthreads();

  // ---- down: out[128 x 512], 8 K-steps of 32 over F ----
  f32x4 accd[4][8];
  #pragma unroll
  for (int ri = 0; ri < 4; ++ri)
    #pragma unroll
    for (int bj = 0; bj < 8; ++bj) accd[ri][bj] = fzero;

  {
    int sl = 0;
    #pragma unroll 1
    for (int kc = 0; kc < 8; ++kc) {
      if (kc < 7) { stage_dn(sl ^ 1, kc + 1); VMCNT(4); }
      else        VMCNT(0);
      __builtin_amdgcn_s_barrier();
      __builtin_amdgcn_sched_barrier(0);
      {
        const ushort* base = RING + sl * SLOT;
        bf16x8 a[4];
        #pragma unroll
        for (int ri = 0; ri < 4; ++ri)
          a[ri] = *(const bf16x8*)(Act + ((wr * 4 + ri) * 8 + kc) * 512 + lane * 8);
        __builtin_amdgcn_s_setprio(1);
        #pragma unroll
        for (int bj = 0; bj < 8; ++bj) {
          bf16x8 b = *(const bf16x8*)(base + (wc >> 1) * 8192 + ((wc & 1) * 8 + bj) * 512 + lane * 8);
          #pragma unroll
          for (int ri = 0; ri < 4; ++ri)
            accd[ri][bj] = __builtin_amdgcn_mfma_f32_16x16x32_bf16(a[ri], b, accd[ri][bj], 0, 0, 0);
        }
        __builtin_amdgcn_s_setprio(0);
      }
      sl ^= 1;
      __builtin_amdgcn_s_barrier();
    }
  }

  // ---- epilogue ----
  if (GATHER) {
    #pragma unroll
    for (int ri = 0; ri < 4; ++ri)
      #pragma unroll
      for (int j = 0; j < 4; ++j) {
        int r = wr * 64 + ri * 16 + hi * 4 + j;
        if (toks[r] < 0) continue;
        ushort* erow = expert_out + (size_t)(tbase + r) * D_DIM + wc * 128 + rl;
        #pragma unroll
        for (int bj = 0; bj < 8; ++bj)
          erow[bj * 16] = f2bf(accd[ri][bj][j]);
      }
  } else {
    #pragma unroll
    for (int ri = 0; ri < 4; ++ri)
      #pragma unroll
      for (int j = 0; j < 4; ++j) {
        int r = wr * 64 + ri * 16 + hi * 4 + j;
        int t = toks[r];
        if (t < 0) continue;
        float gt = gts[r];
        float* orow = out + (size_t)t * D_DIM + wc * 128 + rl;
        #pragma unroll
        for (int bj = 0; bj < 8; ++bj)
          atomicAdd(orow + bj * 16, gt * accd[ri][bj][j]);
      }
  }
}

// ---------------- gather combine: one wave per token ----------------
__global__ void __launch_bounds__(256) gather_out(
    const ushort* __restrict__ eo, const int* __restrict__ entry_row,
    const float* __restrict__ topk_p, float* __restrict__ out) {
  const int t = blockIdx.x * 4 + (threadIdx.x >> 6);
  const int lane = threadIdx.x & 63;
  const int base = t * K_TOP;

  float acc[8];
  #pragma unroll
  for (int j = 0; j < 8; ++j) acc[j] = 0.f;

  #pragma unroll
  for (int k = 0; k < K_TOP; ++k) {
    int row = entry_row[base + k];
    if (row >= 0) {
      float g = topk_p[base + k];
      bf16x8 v = *(const bf16x8*)(eo + (size_t)row * D_DIM + lane * 8);
      #pragma unroll
      for (int j = 0; j < 8; ++j) acc[j] += g * bf2f((ushort)v[j]);
    }
  }
  #pragma unroll
  for (int sh = 0; sh < SH_NUM; ++sh) {
    int row = TOK_ROUTED + sh * N_TOK + t;
    bf16x8 v = *(const bf16x8*)(eo + (size_t)row * D_DIM + lane * 8);
    #pragma unroll
    for (int j = 0; j < 8; ++j) acc[j] += 0.5f * bf2f((ushort)v[j]);
  }
  float4* o = (float4*)(out + (size_t)t * D_DIM + lane * 8);
  o[0] = make_float4(acc[0], acc[1], acc[2], acc[3]);
  o[1] = make_float4(acc[4], acc[5], acc[6], acc[7]);
}

// ================= LEGACY PATH (round-2, used when ws tiny) =================

__global__ void __launch_bounds__(256, 2) expert_ffn_mfma(
    const float* __restrict__ x, const float* __restrict__ wg_,
    const float* __restrict__ wu_, const float* __restrict__ wd_,
    const int* __restrict__ expert_tok, const float* __restrict__ expert_gate,
    float* __restrict__ out) {
  const int e = blockIdx.x & (E_NUM - 1);
  const int mt = blockIdx.x >> 6;
  const int s0 = mt * 64;
  if (expert_tok[e * CAP + s0] < 0) return;

  __shared__ ushort Xs[64][72];
  __shared__ ushort Ws[256][72];
  __shared__ ushort Act[64][264];
  __shared__ int   toks[64];
  __shared__ float gts[64];

  const int tid = threadIdx.x;
  const int lane = tid & 63;
  const int wid = tid >> 6;
  const int rl = lane & 15;
  const int ko = (lane >> 4) * 8;
  const int rquad = (lane >> 4) * 4;

  if (tid < 64) {
    int t = expert_tok[e * CAP + s0 + tid];
    toks[tid] = t;
    gts[tid] = (t >= 0) ? expert_gate[e * CAP + s0 + tid] : 0.f;
  }
  __syncthreads();

  float4 px[4], pw[16];

  auto loadX = [&](int kb) {
    #pragma unroll
    for (int it = 0; it < 4; ++it) {
      int idx = tid + it * 256;
      int row = idx >> 4, c4 = (idx & 15) << 2;
      int t = toks[row];
      px[it] = (t >= 0) ? *(const float4*)(x + (size_t)t * D_DIM + kb * 64 + c4)
                        : make_float4(0.f, 0.f, 0.f, 0.f);
    }
  };
  auto writeX = [&]() {
    #pragma unroll
    for (int it = 0; it < 4; ++it) {
      int idx = tid + it * 256;
      int row = idx >> 4, c4 = (idx & 15) << 2;
      ushort4 h; h.x = f2bf(px[it].x); h.y = f2bf(px[it].y);
      h.z = f2bf(px[it].z); h.w = f2bf(px[it].w);
      *(ushort4*)&Xs[row][c4] = h;
    }
  };
  auto loadW = [&](const float* src, int ldk, int kb) {
    #pragma unroll
    for (int it = 0; it < 16; ++it) {
      int idx = tid + it * 256;
      int row = idx >> 4, c4 = (idx & 15) << 2;
      pw[it] = *(const float4*)(src + (size_t)row * ldk + kb * 64 + c4);
    }
  };
  auto writeW = [&]() {
    #pragma unroll
    for (int it = 0; it < 16; ++it) {
      int idx = tid + it * 256;
      int row = idx >> 4, c4 = (idx & 15) << 2;
      ushort4 h; h.x = f2bf(pw[it].x); h.y = f2bf(pw[it].y);
      h.z = f2bf(pw[it].z); h.w = f2bf(pw[it].w);
      *(ushort4*)&Ws[row][c4] = h;
    }
  };
  auto compute = [&](const ushort* Ab, int lda, f32x4 (&acc)[4][4]) {
    #pragma unroll
    for (int kk = 0; kk < 2; ++kk) {
      bf16x8 a[4], b[4];
      #pragma unroll
      for (int ri = 0; ri < 4; ++ri)
        a[ri] = *(const bf16x8*)(Ab + (size_t)(ri * 16 + rl) * lda + kk * 32 + ko);
      #pragma unroll
      for (int bi = 0; bi < 4; ++bi)
        b[bi] = *(const bf16x8*)(&Ws[wid * 64 + bi * 16 + rl][kk * 32 + ko]);
      #pragma unroll
      for (int ri = 0; ri < 4; ++ri)
        #pragma unroll
        for (int bi = 0; bi < 4; ++bi)
          acc[ri][bi] = __builtin_amdgcn_mfma_f32_16x16x32_bf16(a[ri], b[bi], acc[ri][bi], 0, 0, 0);
    }
  };

  const f32x4 fzero = {0.f, 0.f, 0.f, 0.f};

  #pragma unroll 1
  for (int which = 0; which < 2; ++which) {
    const float* wsrc = (which == 0 ? wg_ : wu_) + (size_t)e * F_DIM * D_DIM;
    f32x4 acc[4][4];
    #pragma unroll
    for (int ri = 0; ri < 4; ++ri)
      #pragma unroll
      for (int bi = 0; bi < 4; ++bi) acc[ri][bi] = fzero;

    loadX(0); loadW(wsrc, D_DIM, 0);
    writeX(); writeW();
    __syncthreads();
    for (int kb = 0; kb < 8; ++kb) {
      if (kb < 7) { loadX(kb + 1); loadW(wsrc, D_DIM, kb + 1); }
      compute(&Xs[0][0], 72, acc);
      __syncthreads();
      if (kb < 7) { writeX(); writeW(); __syncthreads(); }
    }
    #pragma unroll
    for (int ri = 0; ri < 4; ++ri)
      #pragma unroll
      for (int bi = 0; bi < 4; ++bi)
        #pragma unroll
        for (int j = 0; j < 4; ++j) {
          int r = ri * 16 + rquad + j;
          int c = wid * 64 + bi * 16 + rl;
          if (which == 0) {
            Act[r][c] = f2bf(acc[ri][bi][j]);
          } else {
            float hg = bf2f(Act[r][c]);
            float a = hg / (1.f + __expf(-hg)) * acc[ri][bi][j];
            Act[r][c] = f2bf(a);
          }
        }
    __syncthreads();
  }

  #pragma unroll 1
  for (int np = 0; np < 2; ++np) {
    const float* wsrc = wd_ + ((size_t)e * D_DIM + np * 256) * F_DIM;
    f32x4 acc[4][4];
    #pragma unroll
    for (int ri = 0; ri < 4; ++ri)
      #pragma unroll
      for (int bi = 0; bi < 4; ++bi) acc[ri][bi] = fzero;

    loadW(wsrc, F_DIM, 0); writeW();
    __syncthreads();
    for (int kb = 0; kb < 4; ++kb) {
      if (kb < 3) loadW(wsrc, F_DIM, kb + 1);
      compute(&Act[0][kb * 64], 264, acc);
      __syncthreads();
      if (kb < 3) { writeW(); __syncthreads(); }
    }
    #pragma unroll
    for (int ri = 0; ri < 4; ++ri)
      #pragma unroll
      for (int bi = 0; bi < 4; ++bi)
        #pragma unroll
        for (int j = 0; j < 4; ++j) {
          int r = ri * 16 + rquad + j;
          int t = toks[r];
          if (t >= 0) {
            int c = np * 256 + wid * 64 + bi * 16 + rl;
            atomicAdd(out + (size_t)t * D_DIM + c, gts[r] * acc[ri][bi][j]);
          }
        }
  }
}

__global__ void __launch_bounds__(256, 2) shared_ffn_mfma(
    const float* __restrict__ x, const float* __restrict__ swg,
    const float* __restrict__ swu, const float* __restrict__ swd,
    float* __restrict__ out) {
  const int row0 = blockIdx.x * 32;

  __shared__ ushort Xs[32][72];
  __shared__ ushort Ws[256][72];
  __shared__ ushort Act[32][264];

  const int tid = threadIdx.x;
  const int lane = tid & 63;
  const int wid = tid >> 6;
  const int rl = lane & 15;
  const int ko = (lane >> 4) * 8;
  const int rquad = (lane >> 4) * 4;

  float4 px[2], pw[16];

  auto loadX = [&](int kb) {
    #pragma unroll
    for (int it = 0; it < 2; ++it) {
      int idx = tid + it * 256;
      int row = idx >> 4, c4 = (idx & 15) << 2;
      px[it] = *(const float4*)(x + (size_t)(row0 + row) * D_DIM + kb * 64 + c4);
    }
  };
  auto writeX = [&]() {
    #pragma unroll
    for (int it = 0; it < 2; ++it) {
      int idx = tid + it * 256;
      int row = idx >> 4, c4 = (idx & 15) << 2;
      ushort4 h; h.x = f2bf(px[it].x); h.y = f2bf(px[it].y);
      h.z = f2bf(px[it].z); h.w = f2bf(px[it].w);
      *(ushort4*)&Xs[row][c4] = h;
    }
  };
  auto loadW = [&](const float* src, int ldk, int kb) {
    #pragma unroll
    for (int it = 0; it < 16; ++it) {
      int idx = tid + it * 256;
      int row = idx >> 4, c4 = (idx & 15) << 2;
      pw[it] = *(const float4*)(src + (size_t)row * ldk + kb * 64 + c4);
    }
  };
  auto writeW = [&]() {
    #pragma unroll
    for (int it = 0; it < 16; ++it) {
      int idx = tid + it * 256;
      int row = idx >> 4, c4 = (idx & 15) << 2;
      ushort4 h; h.x = f2bf(pw[it].x); h.y = f2bf(pw[it].y);
      h.z = f2bf(pw[it].z); h.w = f2bf(pw[it].w);
      *(ushort4*)&Ws[row][c4] = h;
    }
  };
  auto compute = [&](const ushort* Ab, int lda, f32x4 (&acc)[2][4]) {
    #pragma unroll
    for (int kk = 0; kk < 2; ++kk) {
      bf16x8 a[2], b[4];
      #pragma unroll
      for (int ri = 0; ri < 2; ++ri)
        a[ri] = *(const bf16x8*)(Ab + (size_t)(ri * 16 + rl) * lda + kk * 32 + ko);
      #pragma unroll
      for (int bi = 0; bi < 4; ++bi)
        b[bi] = *(const bf16x8*)(&Ws[wid * 64 + bi * 16 + rl][kk * 32 + ko]);
      #pragma unroll
      for (int ri = 0; ri < 2; ++ri)
        #pragma unroll
        for (int bi = 0; bi < 4; ++bi)
          acc[ri][bi] = __builtin_amdgcn_mfma_f32_16x16x32_bf16(a[ri], b[bi], acc[ri][bi], 0, 0, 0);
    }
  };

  const f32x4 fzero = {0.f, 0.f, 0.f, 0.f};
  f32x4 accd[2][2][4];
  #pragma unroll
  for (int np = 0; np < 2; ++np)
    #pragma unroll
    for (int ri = 0; ri < 2; ++ri)
      #pragma unroll
      for (int bi = 0; bi < 4; ++bi) accd[np][ri][bi] = fzero;

  #pragma unroll 1
  for (int sh = 0; sh < SH_NUM; ++sh) {
    #pragma unroll 1
    for (int which = 0; which < 2; ++which) {
      const float* wsrc = (which == 0 ? swg : swu) + (size_t)sh * F_DIM * D_DIM;
      f32x4 acc[2][4];
      #pragma unroll
      for (int ri = 0; ri < 2; ++ri)
        #pragma unroll
        for (int bi = 0; bi < 4; ++bi) acc[ri][bi] = fzero;

      loadX(0); loadW(wsrc, D_DIM, 0);
      writeX(); writeW();
      __syncthreads();
      for (int kb = 0; kb < 8; ++kb) {
        if (kb < 7) { loadX(kb + 1); loadW(wsrc, D_DIM, kb + 1); }
        compute(&Xs[0][0], 72, acc);
        __syncthreads();
        if (kb < 7) { writeX(); writeW(); __syncthreads(); }
      }
      #pragma unroll
      for (int ri = 0; ri < 2; ++ri)
        #pragma unroll
        for (int bi = 0; bi < 4; ++bi)
          #pragma unroll
          for (int j = 0; j < 4; ++j) {
            int r = ri * 16 + rquad + j;
            int c = wid * 64 + bi * 16 + rl;
            if (which == 0) {
              Act[r][c] = f2bf(acc[ri][bi][j]);
            } else {
              float hg = bf2f(Act[r][c]);
              float a = hg / (1.f + __expf(-hg)) * acc[ri][bi][j];
              Act[r][c] = f2bf(a);
            }
          }
      __syncthreads();
    }
    #pragma unroll
    for (int np = 0; np < 2; ++np) {
      const float* wsrc = swd + ((size_t)sh * D_DIM + np * 256) * F_DIM;
      loadW(wsrc, F_DIM, 0); writeW();
      __syncthreads();
      for (int kb = 0; kb < 4; ++kb) {
        if (kb < 3) loadW(wsrc, F_DIM, kb + 1);
        compute(&Act[0][kb * 64], 264, accd[np]);
        __syncthreads();
        if (kb < 3) { writeW(); __syncthreads(); }
      }
    }
  }

  #pragma unroll
  for (int np = 0; np < 2; ++np)
    #pragma unroll
    for (int ri = 0; ri < 2; ++ri)
      #pragma unroll
      for (int bi = 0; bi < 4; ++bi)
        #pragma unroll
        for (int j = 0; j < 4; ++j) {
          int r = ri * 16 + rquad + j;
          int c = np * 256 + wid * 64 + bi * 16 + rl;
          out[(size_t)(row0 + r) * D_DIM + c] = 0.5f * accd[np][ri][bi][j];
        }
}

extern "C" void kernel_launch(void* const* d_in, const int* in_sizes, int n_in,
                              void* d_out, int out_size, void* d_ws, size_t ws_size,
                              hipStream_t stream) {
  const float* x    = (const float*)d_in[0];
  const float* rw   = (const float*)d_in[1];
  const float* bias = (const float*)d_in[2];
  const float* swg  = (const float*)d_in[3];
  const float* swu  = (const float*)d_in[4];
  const float* swd  = (const float*)d_in[5];
  const float* wg   = (const float*)d_in[6];
  const float* wu   = (const float*)d_in[7];
  const float* wd   = (const float*)d_in[8];
  float* out = (float*)d_out;

  const size_t small = 2 * (size_t)M_ENT * 4 + (size_t)M_ENT * 4 +
                       2 * (size_t)NCHUNK * E_NUM * 4 + 2 * (size_t)TOK_TOTAL * 4 +
                       RWT_BYTES;
  const size_t need_mid = X_BF_BYTES + WT_BYTES + small;
  const size_t need_big = need_mid + EO_BYTES;

  if (ws_size >= need_mid) {
    const bool gather = (ws_size >= need_big);
    char* ws = (char*)d_ws;
    ushort* x_bf     = (ushort*)ws; ws += X_BF_BYTES;
    ushort* Wt       = (ushort*)ws; ws += WT_BYTES;
    int*   topk_i    = (int*)ws;    ws += (size_t)M_ENT * 4;
    float* topk_p    = (float*)ws;  ws += (size_t)M_ENT * 4;
    int*   entry_row = (int*)ws;    ws += (size_t)M_ENT * 4;
    int*   chunk_hist= (int*)ws;    ws += (size_t)NCHUNK * E_NUM * 4;
    int*   chunk_base= (int*)ws;    ws += (size_t)NCHUNK * E_NUM * 4;
    int*   tok_all   = (int*)ws;    ws += (size_t)TOK_TOTAL * 4;
    float* gate_all  = (float*)ws;  ws += (size_t)TOK_TOTAL * 4;
    float* rwt       = (float*)ws;  ws += RWT_BYTES;
    ushort* eo       = (ushort*)ws; // only valid if gather

    convert_x_misc<<<2144, 256, 0, stream>>>(x, x_bf, rw, rwt, tok_all, gate_all);
    convert_w<<<E_TOT * 12, 256, 0, stream>>>(wg, wu, wd, swg, swu, swd, Wt);
    router_topk2<<<256, 256, 0, stream>>>(x, rwt, bias, topk_i, topk_p);
    hipMemsetAsync(tok_all, 0xFF, (size_t)TOK_ROUTED * 4, stream);
    if (!gather) hipMemsetAsync(out, 0, (size_t)out_size * 4, stream);
    hist_kernel<<<NCHUNK, 256, 0, stream>>>(topk_i, chunk_hist);
    scan_kernel<<<1, 64, 0, stream>>>(chunk_hist, chunk_base);
    dispatch_kernel<<<NCHUNK, 256, 0, stream>>>(topk_i, topk_p, chunk_base, tok_all,
                                                gate_all, entry_row);
    const int nblk = (CAP / 128) * E_NUM + 2 * (N_TOK / 128);   // 768 + 128 = 896 = 8*112
    if (gather) {
      ffn_mfma<true><<<nblk, 512, 0, stream>>>(x_bf, Wt, tok_all, gate_all, out, eo);
      gather_out<<<N_TOK / 4, 256, 0, stream>>>(eo, entry_row, topk_p, out);
    } else {
      ffn_mfma<false><<<nblk, 512, 0, stream>>>(x_bf, Wt, tok_all, gate_all, out, nullptr);
    }
  } else {
    char* ws = (char*)d_ws;
    int*   topk_i      = (int*)ws;   ws += (size_t)M_ENT * 4;
    float* topk_p      = (float*)ws; ws += (size_t)M_ENT * 4;
    int*   chunk_hist  = (int*)ws;   ws += (size_t)NCHUNK * E_NUM * 4;
    int*   chunk_base  = (int*)ws;   ws += (size_t)NCHUNK * E_NUM * 4;
    int*   expert_tok  = (int*)ws;   ws += (size_t)E_NUM * CAP * 4;
    float* expert_gate = (float*)ws; ws += (size_t)E_NUM * CAP * 4;

    router_topk<<<N_TOK / 4, 256, 0, stream>>>(x, rw, bias, topk_i, topk_p);
    hipMemsetAsync(expert_tok, 0xFF, (size_t)E_NUM * CAP * 4, stream);
    hist_kernel<<<NCHUNK, 256, 0, stream>>>(topk_i, chunk_hist);
    scan_kernel<<<1, 64, 0, stream>>>(chunk_hist, chunk_base);
    dispatch_kernel<<<NCHUNK, 256, 0, stream>>>(topk_i, topk_p, chunk_base, expert_tok,
                                                expert_gate, nullptr);
    shared_ffn_mfma<<<N_TOK / 32, 256, 0, stream>>>(x, swg, swu, swd, out);
    expert_ffn_mfma<<<(CAP / 64) * E_NUM, 256, 0, stream>>>(x, wg, wu, wd, expert_tok,
                                                            expert_gate, out);
  }
}

// Round 11
// 254.320 us; speedup vs baseline: 8.0048x; 1.0306x over previous
//
#include <hip/hip_runtime.h>
#include <hip/hip_bf16.h>
#include <math.h>

#define N_TOK 8192
#define D_DIM 512
#define F_DIM 256
#define E_NUM 64
#define SH_NUM 2
#define K_TOP 6
#define CAP   1536
#define M_ENT (N_TOK * K_TOP)   // 49152
#define NCHUNK (M_ENT / 256)    // 192

#define EW_STRIDE 393216            // shorts per expert blob (48 chunks x 8192)
#define E_TOT (E_NUM + SH_NUM)      // 66
#define X_BF_BYTES   (8388608ull)
#define WT_BYTES     ((size_t)E_TOT * EW_STRIDE * 2)
#define TOK_ROUTED   (E_NUM * CAP)                   // 98304
#define TOK_TOTAL    (TOK_ROUTED + SH_NUM * N_TOK)   // 114688
#define EO_BYTES     ((size_t)TOK_TOTAL * D_DIM * 2)
#define RWT_BYTES    131072ull

typedef __attribute__((ext_vector_type(8))) short bf16x8;
typedef __attribute__((ext_vector_type(8))) short short8;
typedef __attribute__((ext_vector_type(4))) float f32x4;

#define VMCNT(n) asm volatile("s_waitcnt vmcnt(" #n ")" ::: "memory")

__device__ __forceinline__ ushort f2bf(float f) {
  union { float f; unsigned u; } c; c.f = f;
  return (ushort)((c.u + 0x7FFFu + ((c.u >> 16) & 1u)) >> 16);
}
__device__ __forceinline__ float bf2f(ushort h) {
  union { unsigned u; float f; } c; c.u = ((unsigned)h) << 16;
  return c.f;
}
__device__ __forceinline__ void gload16(const void* g, void* l) {
  __builtin_amdgcn_global_load_lds(
      (const __attribute__((address_space(1))) void*)g,
      (__attribute__((address_space(3))) void*)l, 16, 0, 0);
}

// ---------------- legacy router (small-ws path) ----------------
__global__ void router_topk(const float* __restrict__ x, const float* __restrict__ rw,
                            const float* __restrict__ bias, int* __restrict__ topk_i,
                            float* __restrict__ topk_p) {
  const int wave = threadIdx.x >> 6;
  const int lane = threadIdx.x & 63;
  const int n = blockIdx.x * 4 + wave;
  if (n >= N_TOK) return;

  const float4* xr = (const float4*)(x + (size_t)n * D_DIM);
  const float4* wr = (const float4*)(rw + (size_t)lane * D_DIM);
  float acc = 0.f;
  #pragma unroll 4
  for (int d4 = 0; d4 < D_DIM / 4; ++d4) {
    float4 xv = xr[d4]; float4 wv = wr[d4];
    acc += xv.x * wv.x + xv.y * wv.y + xv.z * wv.z + xv.w * wv.w;
  }
  float logit = acc + bias[lane];

  float m = logit;
  for (int off = 32; off > 0; off >>= 1) m = fmaxf(m, __shfl_xor(m, off));
  float p = expf(logit - m);
  float s = p;
  for (int off = 32; off > 0; off >>= 1) s += __shfl_xor(s, off);
  float prob = p / s;

  float myp = prob;
  float gsum = 0.f;
  float myg = 0.f; int myi = -1;
  for (int k = 0; k < K_TOP; ++k) {
    float bp = myp; int bi = lane;
    for (int off = 32; off > 0; off >>= 1) {
      float op = __shfl_xor(bp, off); int oi = __shfl_xor(bi, off);
      if (op > bp || (op == bp && oi < bi)) { bp = op; bi = oi; }
    }
    gsum += bp;
    if (lane == k) { myg = bp; myi = bi; }
    if (lane == bi) myp = -1.f;
  }
  if (lane < K_TOP) {
    topk_i[n * K_TOP + lane] = myi;
    topk_p[n * K_TOP + lane] = myg / (gsum + 1e-9f);
  }
}

__device__ __forceinline__ void softmax_topk_write(float logit, int n, int lane,
                                                   int* __restrict__ topk_i,
                                                   float* __restrict__ topk_p) {
  float m = logit;
  for (int off = 32; off > 0; off >>= 1) m = fmaxf(m, __shfl_xor(m, off));
  float p = expf(logit - m);
  float s = p;
  for (int off = 32; off > 0; off >>= 1) s += __shfl_xor(s, off);
  float prob = p / s;

  float myp = prob;
  float gsum = 0.f;
  float myg = 0.f; int myi = -1;
  #pragma unroll 1
  for (int k = 0; k < K_TOP; ++k) {
    float bp = myp; int bi = lane;
    for (int off = 32; off > 0; off >>= 1) {
      float op = __shfl_xor(bp, off); int oi = __shfl_xor(bi, off);
      if (op > bp || (op == bp && oi < bi)) { bp = op; bi = oi; }
    }
    gsum += bp;
    if (lane == k) { myg = bp; myi = bi; }
    if (lane == bi) myp = -1.f;
  }
  if (lane < K_TOP) {
    topk_i[n * K_TOP + lane] = myi;
    topk_p[n * K_TOP + lane] = myg / (gsum + 1e-9f);
  }
}

__global__ void __launch_bounds__(256) router_topk2(
    const float* __restrict__ x, const float* __restrict__ rwt,
    const float* __restrict__ bias, int* __restrict__ topk_i,
    float* __restrict__ topk_p) {
  const int wave = threadIdx.x >> 6;
  const int lane = threadIdx.x & 63;
  const int n0 = blockIdx.x * 32 + wave * 8;

  float acc[8];
  #pragma unroll
  for (int t = 0; t < 8; ++t) acc[t] = 0.f;

  const float4* wv4 = (const float4*)rwt;
  #pragma unroll 2
  for (int k4 = 0; k4 < 128; ++k4) {
    float4 w = wv4[k4 * 64 + lane];
    #pragma unroll
    for (int t = 0; t < 8; ++t) {
      float4 xv = *(const float4*)(x + (size_t)(n0 + t) * D_DIM + k4 * 4);
      acc[t] += xv.x * w.x + xv.y * w.y + xv.z * w.z + xv.w * w.w;
    }
  }
  float b = bias[lane];
  #pragma unroll 1
  for (int t = 0; t < 8; ++t)
    softmax_topk_write(acc[t] + b, n0 + t, lane, topk_i, topk_p);
}

// ---------------- per-chunk expert histogram ----------------
__global__ void hist_kernel(const int* __restrict__ topk_i, int* __restrict__ chunk_hist) {
  __shared__ int h[E_NUM];
  const int tid = threadIdx.x;
  if (tid < E_NUM) h[tid] = 0;
  __syncthreads();
  int e = topk_i[blockIdx.x * 256 + tid];
  atomicAdd(&h[e], 1);
  __syncthreads();
  if (tid < E_NUM) chunk_hist[blockIdx.x * E_NUM + tid] = h[tid];
}

// ---------------- exclusive scan over chunks, per expert ----------------
__global__ void scan_kernel(const int* __restrict__ chunk_hist, int* __restrict__ chunk_base) {
  const int e = threadIdx.x;
  int run = 0;
  for (int c = 0; c < NCHUNK; ++c) {
    chunk_base[c * E_NUM + e] = run;
    run += chunk_hist[c * E_NUM + e];
  }
}

// ---------------- dispatch: slot = global stable rank within expert ----------------
__global__ void dispatch_kernel(const int* __restrict__ topk_i, const float* __restrict__ topk_p,
                                const int* __restrict__ chunk_base,
                                int* __restrict__ expert_tok, float* __restrict__ expert_gate,
                                int* __restrict__ entry_row) {
  __shared__ int eid[256];
  const int tid = threadIdx.x;
  const int m = blockIdx.x * 256 + tid;
  const int e = topk_i[m];
  eid[tid] = e;
  __syncthreads();
  int rank = 0;
  for (int t = 0; t < tid; ++t) rank += (eid[t] == e);
  int slot = chunk_base[blockIdx.x * E_NUM + e] + rank;
  int row = -1;
  if (slot < CAP) {
    expert_tok[e * CAP + slot] = m / K_TOP;
    expert_gate[e * CAP + slot] = topk_p[m];
    row = e * CAP + slot;
  }
  if (entry_row) entry_row[m] = row;
}

// ================= FAST PATH =================

// merged: x fp32->bf16 (blocks 0..2047), transpose_rw (2048..2079), init_shared (2080..2143)
__global__ void convert_x_misc(const float* __restrict__ x, ushort* __restrict__ xb,
                               const float* __restrict__ rw, float* __restrict__ rwt,
                               int* __restrict__ tok_all, float* __restrict__ gate_all) {
  int b = blockIdx.x;
  if (b < 2048) {
    size_t idx = (size_t)b * 256 + threadIdx.x;
    const float4* s4 = (const float4*)(x + idx * 8);
    float4 v0 = s4[0], v1 = s4[1];
    short8 o;
    o[0] = f2bf(v0.x); o[1] = f2bf(v0.y); o[2] = f2bf(v0.z); o[3] = f2bf(v0.w);
    o[4] = f2bf(v1.x); o[5] = f2bf(v1.y); o[6] = f2bf(v1.z); o[7] = f2bf(v1.w);
    *(short8*)(xb + idx * 8) = o;
  } else if (b < 2080) {
    int idx = (b - 2048) * 256 + threadIdx.x;   // 0..8191 exactly
    int e = idx >> 7, k4 = idx & 127;
    float4 v = *(const float4*)(rw + (size_t)e * D_DIM + k4 * 4);
    *(float4*)(rwt + ((size_t)k4 * 64 + e) * 4) = v;
  } else {
    int i = (b - 2080) * 256 + threadIdx.x;     // 0..16383 exactly
    tok_all[TOK_ROUTED + i] = i & (N_TOK - 1);
    gate_all[TOK_ROUTED + i] = 0.5f;
  }
}

// weights fp32 -> bf16, pre-tiled fragment layout; dest-linear writes.
__global__ void convert_w(const float* __restrict__ wg_, const float* __restrict__ wu_,
                          const float* __restrict__ wd_, const float* __restrict__ swg,
                          const float* __restrict__ swu, const float* __restrict__ swd,
                          ushort* __restrict__ Wt) {
  int e = blockIdx.x / 12;
  int rem = blockIdx.x - e * 12;
  int p = rem >> 2, q = rem & 3;
  const float* src;
  if (p == 0)      src = (e < E_NUM) ? wg_ + (size_t)e * 131072 : swg + (size_t)(e - E_NUM) * 131072;
  else if (p == 1) src = (e < E_NUM) ? wu_ + (size_t)e * 131072 : swu + (size_t)(e - E_NUM) * 131072;
  else             src = (e < E_NUM) ? wd_ + (size_t)e * 131072 : swd + (size_t)(e - E_NUM) * 131072;
  ushort* dst = Wt + (size_t)e * EW_STRIDE + (size_t)p * 131072;
  #pragma unroll
  for (int i = 0; i < 16; ++i) {
    int d = q * 32768 + i * 2048 + threadIdx.x * 8;
    int ci = d >> 13;
    int r  = d & 8191;
    int nt = r >> 9;
    int rr = r & 511;
    int k8 = rr >> 7;
    int n  = nt * 16 + ((rr >> 3) & 15);
    size_t srcidx;
    if (p < 2) {
      srcidx = (size_t)n * 512 + ci * 32 + k8 * 8;
    } else {
      int np = ci >> 3, kc = ci & 7;
      srcidx = (size_t)(np * 256 + n) * 256 + kc * 32 + k8 * 8;
    }
    const float4* s4 = (const float4*)(src + srcidx);
    float4 v0 = s4[0], v1 = s4[1];
    short8 o;
    o[0] = f2bf(v0.x); o[1] = f2bf(v0.y); o[2] = f2bf(v0.z); o[3] = f2bf(v0.w);
    o[4] = f2bf(v1.x); o[5] = f2bf(v1.y); o[6] = f2bf(v1.z); o[7] = f2bf(v1.w);
    *(short8*)(dst + d) = o;
  }
}

// Unified FFN v4: 128-token tile, 512 threads (8 waves, 2r x 4c).
// W operands loaded GLOBAL->REG (pre-tiled layout == fragment layout), register
// double-buffered; only X goes through a 2-slot LDS ring (1 gload_lds/wave/step).
// vmcnt discipline: issue order W(k+1) then X(k+1); VMCNT(9) drains {W(k),X(k)}.
// Down pass: Act in LDS (static after one sync) + reg-W -> NO barriers.
// XCD-aware decode; grid MUST be 896 = 8 * 112.
template <bool GATHER>
__global__ void __launch_bounds__(512, 1) ffn_mfma(
    const ushort* __restrict__ xb, const ushort* __restrict__ Wt,
    const int* __restrict__ tok_all, const float* __restrict__ gate_all,
    float* __restrict__ out, ushort* __restrict__ expert_out) {
  int e, tbase;
  {
    int xcd = blockIdx.x & 7;
    int j = blockIdx.x >> 3;          // 0..111
    if (j < 96) {                     // routed: 8 experts x 12 tiles per class
      int ec = j / 12;
      int mt = j - ec * 12;
      e = ec * 8 + xcd;
      tbase = e * CAP + mt * 128;
      if (tok_all[tbase] < 0) return;
    } else {                          // shared: 16 tiles per class (128 total)
      int s = xcd * 16 + (j - 96);
      int sh = s & 1, mt = s >> 1;
      e = E_NUM + sh;
      tbase = TOK_ROUTED + sh * N_TOK + mt * 128;
    }
  }
  const ushort* wbase = Wt + (size_t)e * EW_STRIDE;

  __shared__ ushort XR[2][4096];      // 16 KB: 2-slot X ring (128 tok x 32 k)
  __shared__ ushort Act[32768];       // 64 KB
  __shared__ int   toks[128];
  __shared__ float gts[128];

  const int tid = threadIdx.x;
  const int lane = tid & 63;
  const int wid = tid >> 6;        // 0..7
  const int wr = wid >> 2;         // 0..1
  const int wc = wid & 3;          // 0..3
  const int rl = lane & 15;
  const int hi = lane >> 4;

  if (tid < 128) {
    int t = tok_all[tbase + tid];
    toks[tid] = t;
    gts[tid] = (t >= 0) ? gate_all[tbase + tid] : 0.f;
  }
  __syncthreads();

  int t0 = toks[wid * 16 + rl];
  const ushort* xsrc = xb + (size_t)(t0 < 0 ? 0 : t0) * D_DIM + hi * 8;

  auto stageX = [&](int sl, int kc) {
    gload16(xsrc + kc * 32, &XR[sl][wid * 512]);
  };
  auto loadW = [&](int kc, bf16x8 (&g)[4], bf16x8 (&u)[4]) {
    #pragma unroll
    for (int bi = 0; bi < 4; ++bi) {
      const ushort* p = wbase + kc * 8192 + (wc * 4 + bi) * 512 + lane * 8;
      g[bi] = *(const bf16x8*)p;
      u[bi] = *(const bf16x8*)(p + 131072);
    }
  };

  const f32x4 fzero = {0.f, 0.f, 0.f, 0.f};
  f32x4 accg[4][4], accu[4][4];
  #pragma unroll
  for (int ri = 0; ri < 4; ++ri)
    #pragma unroll
    for (int bi = 0; bi < 4; ++bi) { accg[ri][bi] = fzero; accu[ri][bi] = fzero; }

  bf16x8 gA[4], uA[4], gB[4], uB[4];

  auto guMFMA = [&](int sl, bf16x8 (&g)[4], bf16x8 (&u)[4]) {
    bf16x8 a[4];
    #pragma unroll
    for (int ri = 0; ri < 4; ++ri)
      a[ri] = *(const bf16x8*)(&XR[sl][(wr * 4 + ri) * 512 + lane * 8]);
    __builtin_amdgcn_s_setprio(1);
    #pragma unroll
    for (int bi = 0; bi < 4; ++bi)
      #pragma unroll
      for (int ri = 0; ri < 4; ++ri) {
        accg[ri][bi] = __builtin_amdgcn_mfma_f32_16x16x32_bf16(a[ri], g[bi], accg[ri][bi], 0, 0, 0);
        accu[ri][bi] = __builtin_amdgcn_mfma_f32_16x16x32_bf16(a[ri], u[bi], accu[ri][bi], 0, 0, 0);
      }
    __builtin_amdgcn_s_setprio(0);
  };

  // ---- fused gate+up: 16 K-steps of 32 ----
  loadW(0, gA, uA); stageX(0, 0);
  __builtin_amdgcn_sched_barrier(0);
  VMCNT(0);
  __builtin_amdgcn_s_barrier();

  #pragma unroll 1
  for (int k2 = 0; k2 < 16; k2 += 2) {
    // body even k = k2 (slot 0, cur = A, nxt = B)
    {
      const int k = k2;
      if (k < 15) {
        loadW(k + 1, gB, uB); stageX((k + 1) & 1, k + 1);
        __builtin_amdgcn_sched_barrier(0);
        VMCNT(9);
      } else { __builtin_amdgcn_sched_barrier(0); VMCNT(0); }
      __builtin_amdgcn_s_barrier();
      __builtin_amdgcn_sched_barrier(0);
      guMFMA(0, gA, uA);
      __builtin_amdgcn_s_barrier();
    }
    // body odd k = k2+1 (slot 1, cur = B, nxt = A)
    {
      const int k = k2 + 1;
      if (k < 15) {
        loadW(k + 1, gA, uA); stageX((k + 1) & 1, k + 1);
        __builtin_amdgcn_sched_barrier(0);
        VMCNT(9);
      } else { __builtin_amdgcn_sched_barrier(0); VMCNT(0); }
      __builtin_amdgcn_s_barrier();
      __builtin_amdgcn_sched_barrier(0);
      guMFMA(1, gB, uB);
      __builtin_amdgcn_s_barrier();
    }
  }

  // ---- silu(g)*u in-register -> Act (fragment-tiled bf16) ----
  #pragma unroll
  for (int ri = 0; ri < 4; ++ri)
    #pragma unroll
    for (int bi = 0; bi < 4; ++bi) {
      int st = (wr * 4 + ri) * 8 + wc * 2 + (bi >> 1);
      int base = st * 512 + ((bi & 1) * 2 + (rl >> 3)) * 128 + (rl & 7);
      #pragma unroll
      for (int j = 0; j < 4; ++j) {
        float g = accg[ri][bi][j], u = accu[ri][bi][j];
        Act[base + (hi * 4 + j) * 8] = f2bf(g / (1.f + __expf(-g)) * u);
      }
    }

  // ---- down: out[128 x 512], 8 K-steps of 32 over F; NO barriers ----
  const ushort* wdbase = wbase + 262144 + (wc >> 1) * 65536 + ((wc & 1) * 8) * 512 + lane * 8;
  auto loadWd = [&](int kc, bf16x8 (&d)[8]) {
    #pragma unroll
    for (int bj = 0; bj < 8; ++bj)
      d[bj] = *(const bf16x8*)(wdbase + kc * 8192 + bj * 512);
  };

  f32x4 accd[4][8];
  #pragma unroll
  for (int ri = 0; ri < 4; ++ri)
    #pragma unroll
    for (int bj = 0; bj < 8; ++bj) accd[ri][bj] = fzero;

  bf16x8 dA[8], dB[8];
  loadWd(0, dA);
  __syncthreads();   // Act ready

  auto dnMFMA = [&](int kc, bf16x8 (&d)[8]) {
    bf16x8 a[4];
    #pragma unroll
    for (int ri = 0; ri < 4; ++ri)
      a[ri] = *(const bf16x8*)(&Act[((wr * 4 + ri) * 8 + kc) * 512 + lane * 8]);
    __builtin_amdgcn_s_setprio(1);
    #pragma unroll
    for (int bj = 0; bj < 8; ++bj)
      #pragma unroll
      for (int ri = 0; ri < 4; ++ri)
        accd[ri][bj] = __builtin_amdgcn_mfma_f32_16x16x32_bf16(a[ri], d[bj], accd[ri][bj], 0, 0, 0);
    __builtin_amdgcn_s_setprio(0);
  };

  #pragma unroll 1
  for (int k2 = 0; k2 < 8; k2 += 2) {
    loadWd(k2 + 1, dB);
    dnMFMA(k2, dA);
    if (k2 + 2 < 8) loadWd(k2 + 2, dA);
    dnMFMA(k2 + 1, dB);
  }

  // ---- epilogue ----
  if (GATHER) {
    #pragma unroll
    for (int ri = 0; ri < 4; ++ri)
      #pragma unroll
      for (int j = 0; j < 4; ++j) {
        int r = wr * 64 + ri * 16 + hi * 4 + j;
        if (toks[r] < 0) continue;
        ushort* erow = expert_out + (size_t)(tbase + r) * D_DIM + wc * 128 + rl;
        #pragma unroll
        for (int bj = 0; bj < 8; ++bj)
          erow[bj * 16] = f2bf(accd[ri][bj][j]);
      }
  } else {
    #pragma unroll
    for (int ri = 0; ri < 4; ++ri)
      #pragma unroll
      for (int j = 0; j < 4; ++j) {
        int r = wr * 64 + ri * 16 + hi * 4 + j;
        int t = toks[r];
        if (t < 0) continue;
        float gt = gts[r];
        float* orow = out + (size_t)t * D_DIM + wc * 128 + rl;
        #pragma unroll
        for (int bj = 0; bj < 8; ++bj)
          atomicAdd(orow + bj * 16, gt * accd[ri][bj][j]);
      }
  }
}

// ---------------- gather combine: one wave per token ----------------
__global__ void __launch_bounds__(256) gather_out(
    const ushort* __restrict__ eo, const int* __restrict__ entry_row,
    const float* __restrict__ topk_p, float* __restrict__ out) {
  const int t = blockIdx.x * 4 + (threadIdx.x >> 6);
  const int lane = threadIdx.x & 63;
  const int base = t * K_TOP;

  float acc[8];
  #pragma unroll
  for (int j = 0; j < 8; ++j) acc[j] = 0.f;

  #pragma unroll
  for (int k = 0; k < K_TOP; ++k) {
    int row = entry_row[base + k];
    if (row >= 0) {
      float g = topk_p[base + k];
      bf16x8 v = *(const bf16x8*)(eo + (size_t)row * D_DIM + lane * 8);
      #pragma unroll
      for (int j = 0; j < 8; ++j) acc[j] += g * bf2f((ushort)v[j]);
    }
  }
  #pragma unroll
  for (int sh = 0; sh < SH_NUM; ++sh) {
    int row = TOK_ROUTED + sh * N_TOK + t;
    bf16x8 v = *(const bf16x8*)(eo + (size_t)row * D_DIM + lane * 8);
    #pragma unroll
    for (int j = 0; j < 8; ++j) acc[j] += 0.5f * bf2f((ushort)v[j]);
  }
  float4* o = (float4*)(out + (size_t)t * D_DIM + lane * 8);
  o[0] = make_float4(acc[0], acc[1], acc[2], acc[3]);
  o[1] = make_float4(acc[4], acc[5], acc[6], acc[7]);
}

// ================= LEGACY PATH (round-2, used when ws tiny) =================

__global__ void __launch_bounds__(256, 2) expert_ffn_mfma(
    const float* __restrict__ x, const float* __restrict__ wg_,
    const float* __restrict__ wu_, const float* __restrict__ wd_,
    const int* __restrict__ expert_tok, const float* __restrict__ expert_gate,
    float* __restrict__ out) {
  const int e = blockIdx.x & (E_NUM - 1);
  const int mt = blockIdx.x >> 6;
  const int s0 = mt * 64;
  if (expert_tok[e * CAP + s0] < 0) return;

  __shared__ ushort Xs[64][72];
  __shared__ ushort Ws[256][72];
  __shared__ ushort Act[64][264];
  __shared__ int   toks[64];
  __shared__ float gts[64];

  const int tid = threadIdx.x;
  const int lane = tid & 63;
  const int wid = tid >> 6;
  const int rl = lane & 15;
  const int ko = (lane >> 4) * 8;
  const int rquad = (lane >> 4) * 4;

  if (tid < 64) {
    int t = expert_tok[e * CAP + s0 + tid];
    toks[tid] = t;
    gts[tid] = (t >= 0) ? expert_gate[e * CAP + s0 + tid] : 0.f;
  }
  __syncthreads();

  float4 px[4], pw[16];

  auto loadX = [&](int kb) {
    #pragma unroll
    for (int it = 0; it < 4; ++it) {
      int idx = tid + it * 256;
      int row = idx >> 4, c4 = (idx & 15) << 2;
      int t = toks[row];
      px[it] = (t >= 0) ? *(const float4*)(x + (size_t)t * D_DIM + kb * 64 + c4)
                        : make_float4(0.f, 0.f, 0.f, 0.f);
    }
  };
  auto writeX = [&]() {
    #pragma unroll
    for (int it = 0; it < 4; ++it) {
      int idx = tid + it * 256;
      int row = idx >> 4, c4 = (idx & 15) << 2;
      ushort4 h; h.x = f2bf(px[it].x); h.y = f2bf(px[it].y);
      h.z = f2bf(px[it].z); h.w = f2bf(px[it].w);
      *(ushort4*)&Xs[row][c4] = h;
    }
  };
  auto loadW = [&](const float* src, int ldk, int kb) {
    #pragma unroll
    for (int it = 0; it < 16; ++it) {
      int idx = tid + it * 256;
      int row = idx >> 4, c4 = (idx & 15) << 2;
      pw[it] = *(const float4*)(src + (size_t)row * ldk + kb * 64 + c4);
    }
  };
  auto writeW = [&]() {
    #pragma unroll
    for (int it = 0; it < 16; ++it) {
      int idx = tid + it * 256;
      int row = idx >> 4, c4 = (idx & 15) << 2;
      ushort4 h; h.x = f2bf(pw[it].x); h.y = f2bf(pw[it].y);
      h.z = f2bf(pw[it].z); h.w = f2bf(pw[it].w);
      *(ushort4*)&Ws[row][c4] = h;
    }
  };
  auto compute = [&](const ushort* Ab, int lda, f32x4 (&acc)[4][4]) {
    #pragma unroll
    for (int kk = 0; kk < 2; ++kk) {
      bf16x8 a[4], b[4];
      #pragma unroll
      for (int ri = 0; ri < 4; ++ri)
        a[ri] = *(const bf16x8*)(Ab + (size_t)(ri * 16 + rl) * lda + kk * 32 + ko);
      #pragma unroll
      for (int bi = 0; bi < 4; ++bi)
        b[bi] = *(const bf16x8*)(&Ws[wid * 64 + bi * 16 + rl][kk * 32 + ko]);
      #pragma unroll
      for (int ri = 0; ri < 4; ++ri)
        #pragma unroll
        for (int bi = 0; bi < 4; ++bi)
          acc[ri][bi] = __builtin_amdgcn_mfma_f32_16x16x32_bf16(a[ri], b[bi], acc[ri][bi], 0, 0, 0);
    }
  };

  const f32x4 fzero = {0.f, 0.f, 0.f, 0.f};

  #pragma unroll 1
  for (int which = 0; which < 2; ++which) {
    const float* wsrc = (which == 0 ? wg_ : wu_) + (size_t)e * F_DIM * D_DIM;
    f32x4 acc[4][4];
    #pragma unroll
    for (int ri = 0; ri < 4; ++ri)
      #pragma unroll
      for (int bi = 0; bi < 4; ++bi) acc[ri][bi] = fzero;

    loadX(0); loadW(wsrc, D_DIM, 0);
    writeX(); writeW();
    __syncthreads();
    for (int kb = 0; kb < 8; ++kb) {
      if (kb < 7) { loadX(kb + 1); loadW(wsrc, D_DIM, kb + 1); }
      compute(&Xs[0][0], 72, acc);
      __syncthreads();
      if (kb < 7) { writeX(); writeW(); __syncthreads(); }
    }
    #pragma unroll
    for (int ri = 0; ri < 4; ++ri)
      #pragma unroll
      for (int bi = 0; bi < 4; ++bi)
        #pragma unroll
        for (int j = 0; j < 4; ++j) {
          int r = ri * 16 + rquad + j;
          int c = wid * 64 + bi * 16 + rl;
          if (which == 0) {
            Act[r][c] = f2bf(acc[ri][bi][j]);
          } else {
            float hg = bf2f(Act[r][c]);
            float a = hg / (1.f + __expf(-hg)) * acc[ri][bi][j];
            Act[r][c] = f2bf(a);
          }
        }
    __syncthreads();
  }

  #pragma unroll 1
  for (int np = 0; np < 2; ++np) {
    const float* wsrc = wd_ + ((size_t)e * D_DIM + np * 256) * F_DIM;
    f32x4 acc[4][4];
    #pragma unroll
    for (int ri = 0; ri < 4; ++ri)
      #pragma unroll
      for (int bi = 0; bi < 4; ++bi) acc[ri][bi] = fzero;

    loadW(wsrc, F_DIM, 0); writeW();
    __syncthreads();
    for (int kb = 0; kb < 4; ++kb) {
      if (kb < 3) loadW(wsrc, F_DIM, kb + 1);
      compute(&Act[0][kb * 64], 264, acc);
      __syncthreads();
      if (kb < 3) { writeW(); __syncthreads(); }
    }
    #pragma unroll
    for (int ri = 0; ri < 4; ++ri)
      #pragma unroll
      for (int bi = 0; bi < 4; ++bi)
        #pragma unroll
        for (int j = 0; j < 4; ++j) {
          int r = ri * 16 + rquad + j;
          int t = toks[r];
          if (t >= 0) {
            int c = np * 256 + wid * 64 + bi * 16 + rl;
            atomicAdd(out + (size_t)t * D_DIM + c, gts[r] * acc[ri][bi][j]);
          }
        }
  }
}

__global__ void __launch_bounds__(256, 2) shared_ffn_mfma(
    const float* __restrict__ x, const float* __restrict__ swg,
    const float* __restrict__ swu, const float* __restrict__ swd,
    float* __restrict__ out) {
  const int row0 = blockIdx.x * 32;

  __shared__ ushort Xs[32][72];
  __shared__ ushort Ws[256][72];
  __shared__ ushort Act[32][264];

  const int tid = threadIdx.x;
  const int lane = tid & 63;
  const int wid = tid >> 6;
  const int rl = lane & 15;
  const int ko = (lane >> 4) * 8;
  const int rquad = (lane >> 4) * 4;

  float4 px[2], pw[16];

  auto loadX = [&](int kb) {
    #pragma unroll
    for (int it = 0; it < 2; ++it) {
      int idx = tid + it * 256;
      int row = idx >> 4, c4 = (idx & 15) << 2;
      px[it] = *(const float4*)(x + (size_t)(row0 + row) * D_DIM + kb * 64 + c4);
    }
  };
  auto writeX = [&]() {
    #pragma unroll
    for (int it = 0; it < 2; ++it) {
      int idx = tid + it * 256;
      int row = idx >> 4, c4 = (idx & 15) << 2;
      ushort4 h; h.x = f2bf(px[it].x); h.y = f2bf(px[it].y);
      h.z = f2bf(px[it].z); h.w = f2bf(px[it].w);
      *(ushort4*)&Xs[row][c4] = h;
    }
  };
  auto loadW = [&](const float* src, int ldk, int kb) {
    #pragma unroll
    for (int it = 0; it < 16; ++it) {
      int idx = tid + it * 256;
      int row = idx >> 4, c4 = (idx & 15) << 2;
      pw[it] = *(const float4*)(src + (size_t)row * ldk + kb * 64 + c4);
    }
  };
  auto writeW = [&]() {
    #pragma unroll
    for (int it = 0; it < 16; ++it) {
      int idx = tid + it * 256;
      int row = idx >> 4, c4 = (idx & 15) << 2;
      ushort4 h; h.x = f2bf(pw[it].x); h.y = f2bf(pw[it].y);
      h.z = f2bf(pw[it].z); h.w = f2bf(pw[it].w);
      *(ushort4*)&Ws[row][c4] = h;
    }
  };
  auto compute = [&](const ushort* Ab, int lda, f32x4 (&acc)[2][4]) {
    #pragma unroll
    for (int kk = 0; kk < 2; ++kk) {
      bf16x8 a[2], b[4];
      #pragma unroll
      for (int ri = 0; ri < 2; ++ri)
        a[ri] = *(const bf16x8*)(Ab + (size_t)(ri * 16 + rl) * lda + kk * 32 + ko);
      #pragma unroll
      for (int bi = 0; bi < 4; ++bi)
        b[bi] = *(const bf16x8*)(&Ws[wid * 64 + bi * 16 + rl][kk * 32 + ko]);
      #pragma unroll
      for (int ri = 0; ri < 2; ++ri)
        #pragma unroll
        for (int bi = 0; bi < 4; ++bi)
          acc[ri][bi] = __builtin_amdgcn_mfma_f32_16x16x32_bf16(a[ri], b[bi], acc[ri][bi], 0, 0, 0);
    }
  };

  const f32x4 fzero = {0.f, 0.f, 0.f, 0.f};
  f32x4 accd[2][2][4];
  #pragma unroll
  for (int np = 0; np < 2; ++np)
    #pragma unroll
    for (int ri = 0; ri < 2; ++ri)
      #pragma unroll
      for (int bi = 0; bi < 4; ++bi) accd[np][ri][bi] = fzero;

  #pragma unroll 1
  for (int sh = 0; sh < SH_NUM; ++sh) {
    #pragma unroll 1
    for (int which = 0; which < 2; ++which) {
      const float* wsrc = (which == 0 ? swg : swu) + (size_t)sh * F_DIM * D_DIM;
      f32x4 acc[2][4];
      #pragma unroll
      for (int ri = 0; ri < 2; ++ri)
        #pragma unroll
        for (int bi = 0; bi < 4; ++bi) acc[ri][bi] = fzero;

      loadX(0); loadW(wsrc, D_DIM, 0);
      writeX(); writeW();
      __syncthreads();
      for (int kb = 0; kb < 8; ++kb) {
        if (kb < 7) { loadX(kb + 1); loadW(wsrc, D_DIM, kb + 1); }
        compute(&Xs[0][0], 72, acc);
        __syncthreads();
        if (kb < 7) { writeX(); writeW(); __syncthreads(); }
      }
      #pragma unroll
      for (int ri = 0; ri < 2; ++ri)
        #pragma unroll
        for (int bi = 0; bi < 4; ++bi)
          #pragma unroll
          for (int j = 0; j < 4; ++j) {
            int r = ri * 16 + rquad + j;
            int c = wid * 64 + bi * 16 + rl;
            if (which == 0) {
              Act[r][c] = f2bf(acc[ri][bi][j]);
            } else {
              float hg = bf2f(Act[r][c]);
              float a = hg / (1.f + __expf(-hg)) * acc[ri][bi][j];
              Act[r][c] = f2bf(a);
            }
          }
      __syncthreads();
    }
    #pragma unroll
    for (int np = 0; np < 2; ++np) {
      const float* wsrc = swd + ((size_t)sh * D_DIM + np * 256) * F_DIM;
      loadW(wsrc, F_DIM, 0); writeW();
      __syncthreads();
      for (int kb = 0; kb < 4; ++kb) {
        if (kb < 3) loadW(wsrc, F_DIM, kb + 1);
        compute(&Act[0][kb * 64], 264, accd[np]);
        __syncthreads();
        if (kb < 3) { writeW(); __syncthreads(); }
      }
    }
  }

  #pragma unroll
  for (int np = 0; np < 2; ++np)
    #pragma unroll
    for (int ri = 0; ri < 2; ++ri)
      #pragma unroll
      for (int bi = 0; bi < 4; ++bi)
        #pragma unroll
        for (int j = 0; j < 4; ++j) {
          int r = ri * 16 + rquad + j;
          int c = np * 256 + wid * 64 + bi * 16 + rl;
          out[(size_t)(row0 + r) * D_DIM + c] = 0.5f * accd[np][ri][bi][j];
        }
}

extern "C" void kernel_launch(void* const* d_in, const int* in_sizes, int n_in,
                              void* d_out, int out_size, void* d_ws, size_t ws_size,
                              hipStream_t stream) {
  const float* x    = (const float*)d_in[0];
  const float* rw   = (const float*)d_in[1];
  const float* bias = (const float*)d_in[2];
  const float* swg  = (const float*)d_in[3];
  const float* swu  = (const float*)d_in[4];
  const float* swd  = (const float*)d_in[5];
  const float* wg   = (const float*)d_in[6];
  const float* wu   = (const float*)d_in[7];
  const float* wd   = (const float*)d_in[8];
  float* out = (float*)d_out;

  const size_t small = 2 * (size_t)M_ENT * 4 + (size_t)M_ENT * 4 +
                       2 * (size_t)NCHUNK * E_NUM * 4 + 2 * (size_t)TOK_TOTAL * 4 +
                       RWT_BYTES;
  const size_t need_mid = X_BF_BYTES + WT_BYTES + small;
  const size_t need_big = need_mid + EO_BYTES;

  if (ws_size >= need_mid) {
    const bool gather = (ws_size >= need_big);
    char* ws = (char*)d_ws;
    ushort* x_bf     = (ushort*)ws; ws += X_BF_BYTES;
    ushort* Wt       = (ushort*)ws; ws += WT_BYTES;
    int*   topk_i    = (int*)ws;    ws += (size_t)M_ENT * 4;
    float* topk_p    = (float*)ws;  ws += (size_t)M_ENT * 4;
    int*   entry_row = (int*)ws;    ws += (size_t)M_ENT * 4;
    int*   chunk_hist= (int*)ws;    ws += (size_t)NCHUNK * E_NUM * 4;
    int*   chunk_base= (int*)ws;    ws += (size_t)NCHUNK * E_NUM * 4;
    int*   tok_all   = (int*)ws;    ws += (size_t)TOK_TOTAL * 4;
    float* gate_all  = (float*)ws;  ws += (size_t)TOK_TOTAL * 4;
    float* rwt       = (float*)ws;  ws += RWT_BYTES;
    ushort* eo       = (ushort*)ws; // only valid if gather

    convert_x_misc<<<2144, 256, 0, stream>>>(x, x_bf, rw, rwt, tok_all, gate_all);
    convert_w<<<E_TOT * 12, 256, 0, stream>>>(wg, wu, wd, swg, swu, swd, Wt);
    router_topk2<<<256, 256, 0, stream>>>(x, rwt, bias, topk_i, topk_p);
    hipMemsetAsync(tok_all, 0xFF, (size_t)TOK_ROUTED * 4, stream);
    if (!gather) hipMemsetAsync(out, 0, (size_t)out_size * 4, stream);
    hist_kernel<<<NCHUNK, 256, 0, stream>>>(topk_i, chunk_hist);
    scan_kernel<<<1, 64, 0, stream>>>(chunk_hist, chunk_base);
    dispatch_kernel<<<NCHUNK, 256, 0, stream>>>(topk_i, topk_p, chunk_base, tok_all,
                                                gate_all, entry_row);
    const int nblk = (CAP / 128) * E_NUM + 2 * (N_TOK / 128);   // 768 + 128 = 896 = 8*112
    if (gather) {
      ffn_mfma<true><<<nblk, 512, 0, stream>>>(x_bf, Wt, tok_all, gate_all, out, eo);
      gather_out<<<N_TOK / 4, 256, 0, stream>>>(eo, entry_row, topk_p, out);
    } else {
      ffn_mfma<false><<<nblk, 512, 0, stream>>>(x_bf, Wt, tok_all, gate_all, out, nullptr);
    }
  } else {
    char* ws = (char*)d_ws;
    int*   topk_i      = (int*)ws;   ws += (size_t)M_ENT * 4;
    float* topk_p      = (float*)ws; ws += (size_t)M_ENT * 4;
    int*   chunk_hist  = (int*)ws;   ws += (size_t)NCHUNK * E_NUM * 4;
    int*   chunk_base  = (int*)ws;   ws += (size_t)NCHUNK * E_NUM * 4;
    int*   expert_tok  = (int*)ws;   ws += (size_t)E_NUM * CAP * 4;
    float* expert_gate = (float*)ws; ws += (size_t)E_NUM * CAP * 4;

    router_topk<<<N_TOK / 4, 256, 0, stream>>>(x, rw, bias, topk_i, topk_p);
    hipMemsetAsync(expert_tok, 0xFF, (size_t)E_NUM * CAP * 4, stream);
    hist_kernel<<<NCHUNK, 256, 0, stream>>>(topk_i, chunk_hist);
    scan_kernel<<<1, 64, 0, stream>>>(chunk_hist, chunk_base);
    dispatch_kernel<<<NCHUNK, 256, 0, stream>>>(topk_i, topk_p, chunk_base, expert_tok,
                                                expert_gate, nullptr);
    shared_ffn_mfma<<<N_TOK / 32, 256, 0, stream>>>(x, swg, swu, swd, out);
    expert_ffn_mfma<<<(CAP / 64) * E_NUM, 256, 0, stream>>>(x, wg, wu, wd, expert_tok,
                                                            expert_gate, out);
  }
}